// Round 2
// baseline (2415.824 us; speedup 1.0000x reference)
//
#include <hip/hip_runtime.h>
#include <math.h>

#define L_OR 6
#define N_BL 48   // B*L = 8*6

// Static device scratch: 3 x (196608*128) fp32 buffers + tail. ~310 MB BSS,
// allocated at module load (no runtime alloc -> graph-capture safe).
#define WS_FLOATS 77491456ull
__device__ float g_ws[WS_FLOATS];

// ---------------------------------------------------------------------------
// Laplacian gather: out[n][:] = alpha * sum_{incoming e} ea[e]*in[src(e)][:] - tpp[n][:]
// Edge blocks in ea: [x-fwd | x-bwd | y-fwd | y-bwd | ring-fwd | ring-bwd]
// NOTE: out and tpp may ALIAS (in-place recurrence): each element is read by
// exactly the thread that overwrites it. No __restrict__ on out/tpp.
// ---------------------------------------------------------------------------
template<int S>
__global__ __launch_bounds__(256)
void lap128_kernel(float* out, const float* __restrict__ in,
                   const float* tpp, const float* __restrict__ ea,
                   float alpha)
{
    const int NN = N_BL * S * S;
    int node = blockIdx.x * 8 + (threadIdx.x >> 5);
    int c4   = threadIdx.x & 31;           // float4 column 0..31 (128 floats)
    if (node >= NN) return;

    const int x = node % S;
    const int y = (node / S) % S;
    const int g = node / (S * S);          // b*6 + o
    const int o = g % L_OR;
    const int b = g / L_OR;
    const int szx = N_BL * S * (S - 1);

    const float4* in4 = (const float4*)in;
    float4 acc = make_float4(0.f, 0.f, 0.f, 0.f);

    auto gather = [&](int src, float w) {
        float4 v = in4[(size_t)src * 32 + c4];
        acc.x += w * v.x; acc.y += w * v.y; acc.z += w * v.z; acc.w += w * v.w;
    };

    const int basex = (g * S + y) * (S - 1);
    if (x > 0)     gather(node - 1, ea[basex + x - 1]);
    if (x < S - 1) gather(node + 1, ea[szx + basex + x]);
    if (y > 0)     gather(node - S, ea[2 * szx + (g * (S - 1) + y - 1) * S + x]);
    if (y < S - 1) gather(node + S, ea[3 * szx + (g * (S - 1) + y) * S + x]);
    {   // ring: from o-1
        int op = (o == 0) ? L_OR - 1 : o - 1;
        int sp = ((b * L_OR + op) * S + y) * S + x;
        gather(sp, ea[4 * szx + sp]);
    }
    {   // ring: from o+1
        int on = (o == L_OR - 1) ? 0 : o + 1;
        int sn = ((b * L_OR + on) * S + y) * S + x;
        gather(sn, ea[4 * szx + N_BL * S * S + node]);
    }

    float4 r;
    r.x = alpha * acc.x; r.y = alpha * acc.y; r.z = alpha * acc.z; r.w = alpha * acc.w;
    if (tpp) {
        float4 t = ((const float4*)tpp)[(size_t)node * 32 + c4];
        r.x -= t.x; r.y -= t.y; r.z -= t.z; r.w -= t.w;
    }
    ((float4*)out)[(size_t)node * 32 + c4] = r;
}

template<int S>
__global__ __launch_bounds__(256)
void lap3_kernel(float* __restrict__ out, const float* __restrict__ in,
                 const float* __restrict__ tpp, const float* __restrict__ ea,
                 float alpha)
{
    const int NN = N_BL * S * S;
    int n = blockIdx.x * 256 + threadIdx.x;
    if (n >= NN) return;
    const int x = n % S, y = (n / S) % S, g = n / (S * S);
    const int o = g % L_OR, b = g / L_OR;
    const int szx = N_BL * S * (S - 1);

    float a0 = 0.f, a1 = 0.f, a2 = 0.f;
    auto gather = [&](int src, float w) {
        a0 += w * in[src * 3 + 0];
        a1 += w * in[src * 3 + 1];
        a2 += w * in[src * 3 + 2];
    };
    const int basex = (g * S + y) * (S - 1);
    if (x > 0)     gather(n - 1, ea[basex + x - 1]);
    if (x < S - 1) gather(n + 1, ea[szx + basex + x]);
    if (y > 0)     gather(n - S, ea[2 * szx + (g * (S - 1) + y - 1) * S + x]);
    if (y < S - 1) gather(n + S, ea[3 * szx + (g * (S - 1) + y) * S + x]);
    { int op = (o == 0) ? L_OR - 1 : o - 1; int sp = ((b * L_OR + op) * S + y) * S + x;
      gather(sp, ea[4 * szx + sp]); }
    { int on = (o == L_OR - 1) ? 0 : o + 1; int sn = ((b * L_OR + on) * S + y) * S + x;
      gather(sn, ea[4 * szx + N_BL * S * S + n]); }

    float r0 = alpha * a0, r1 = alpha * a1, r2 = alpha * a2;
    if (tpp) { r0 -= tpp[n * 3 + 0]; r1 -= tpp[n * 3 + 1]; r2 -= tpp[n * 3 + 2]; }
    out[n * 3 + 0] = r0; out[n * 3 + 1] = r1; out[n * 3 + 2] = r2;
}

// ---------------------------------------------------------------------------
// GEMM: O[N,128] (+)= Ta[N,128]@Wa[128,128] + Tb[N,128]@Wb[128,128] (+bias)
// BM=64, BN=128, BK=32; 256 threads, each 8x4 outputs.
// ---------------------------------------------------------------------------
__global__ __launch_bounds__(256)
void gemm_pair128(float* __restrict__ O, const float* __restrict__ Ta,
                  const float* __restrict__ Wa, const float* __restrict__ Tb,
                  const float* __restrict__ Wb, const float* __restrict__ bias,
                  int first)
{
    __shared__ float As[64][33];
    __shared__ float Bs[32][128];
    const int tid  = threadIdx.x;
    const int m0   = blockIdx.x * 64;
    const int tcol = (tid & 31) * 4;     // 0..124
    const int trow = (tid >> 5) * 8;     // 0..56

    float acc[8][4];
#pragma unroll
    for (int i = 0; i < 8; ++i)
#pragma unroll
        for (int j = 0; j < 4; ++j) acc[i][j] = 0.f;

#pragma unroll 1
    for (int t = 0; t < 8; ++t) {
        const float* T = (t < 4) ? Ta : Tb;
        const float* W = (t < 4) ? Wa : Wb;
        const int k0 = (t & 3) * 32;

#pragma unroll
        for (int i = 0; i < 2; ++i) {
            int li = tid * 2 + i;                // 0..511
            int r  = li >> 3;                    // 0..63
            int kk = (li & 7) << 2;              // 0..28
            float4 v = *(const float4*)&T[(size_t)(m0 + r) * 128 + k0 + kk];
            As[r][kk + 0] = v.x; As[r][kk + 1] = v.y;
            As[r][kk + 2] = v.z; As[r][kk + 3] = v.w;
        }
#pragma unroll
        for (int i = 0; i < 4; ++i) {
            int li = tid * 4 + i;                // 0..1023
            int r  = li >> 5;                    // 0..31
            int cc = (li & 31) << 2;             // 0..124
            *(float4*)&Bs[r][cc] = *(const float4*)&W[(size_t)(k0 + r) * 128 + cc];
        }
        __syncthreads();

#pragma unroll
        for (int kk = 0; kk < 32; ++kk) {
            float4 b4 = *(const float4*)&Bs[kk][tcol];
            float a[8];
#pragma unroll
            for (int i = 0; i < 8; ++i) a[i] = As[trow + i][kk];
#pragma unroll
            for (int i = 0; i < 8; ++i) {
                acc[i][0] += a[i] * b4.x; acc[i][1] += a[i] * b4.y;
                acc[i][2] += a[i] * b4.z; acc[i][3] += a[i] * b4.w;
            }
        }
        __syncthreads();
    }

#pragma unroll
    for (int i = 0; i < 8; ++i) {
        size_t off = (size_t)(m0 + trow + i) * 128 + tcol;
        float4 v = make_float4(acc[i][0], acc[i][1], acc[i][2], acc[i][3]);
        if (first) {
            float4 bv = *(const float4*)&bias[tcol];
            v.x += bv.x; v.y += bv.y; v.z += bv.z; v.w += bv.w;
        } else {
            float4 ov = *(const float4*)&O[off];
            v.x += ov.x; v.y += ov.y; v.z += ov.z; v.w += ov.w;
        }
        *(float4*)&O[off] = v;
    }
}

// Layer-1 GEMM: K=3 per matrix. O[N,128] (+)= Ta[N,3]@Wa[3,128] + Tb[N,3]@Wb[3,128]
__global__ __launch_bounds__(256)
void gemm_k3pair(float* __restrict__ O, const float* __restrict__ Ta,
                 const float* __restrict__ Wa, const float* __restrict__ Tb,
                 const float* __restrict__ Wb, const float* __restrict__ bias,
                 int first)
{
    int tid = threadIdx.x;
    int col = tid & 127;
    int row = blockIdx.x * 2 + (tid >> 7);
    float ta0 = Ta[row * 3 + 0], ta1 = Ta[row * 3 + 1], ta2 = Ta[row * 3 + 2];
    float tb0 = Tb[row * 3 + 0], tb1 = Tb[row * 3 + 1], tb2 = Tb[row * 3 + 2];
    float acc = ta0 * Wa[col] + ta1 * Wa[128 + col] + ta2 * Wa[256 + col]
              + tb0 * Wb[col] + tb1 * Wb[128 + col] + tb2 * Wb[256 + col];
    size_t off = (size_t)row * 128 + col;
    acc += first ? bias[col] : O[off];
    O[off] = acc;
}

// Layer-6 GEMM: O[N,10] (+)= Ta[N,128]@Wa[128,10] + Tb[N,128]@Wb[128,10]
__global__ __launch_bounds__(256)
void gemm_pair_out10(float* __restrict__ O, const float* __restrict__ Ta,
                     const float* __restrict__ Wa, const float* __restrict__ Tb,
                     const float* __restrict__ Wb, const float* __restrict__ bias,
                     int N, int first)
{
    __shared__ float Ws[2][128][16];
    int tid = threadIdx.x;
    for (int i = tid; i < 2 * 128 * 16; i += 256) {
        int m = i / (128 * 16);
        int r = (i / 16) & 127;
        int c = i & 15;
        float v = 0.f;
        if (c < 10) v = m ? Wb[r * 10 + c] : Wa[r * 10 + c];
        Ws[m][r][c] = v;
    }
    __syncthreads();
    int col = tid & 15;
    int row = blockIdx.x * 16 + (tid >> 4);
    if (row < N && col < 10) {
        float acc = 0.f;
        for (int k = 0; k < 128; ++k) acc += Ta[(size_t)row * 128 + k] * Ws[0][k][col];
        for (int k = 0; k < 128; ++k) acc += Tb[(size_t)row * 128 + k] * Ws[1][k][col];
        size_t off = (size_t)row * 10 + col;
        acc += first ? bias[col] : O[off];
        O[off] = acc;
    }
}

// ---------------------------------------------------------------------------
// BatchNorm (training stats, biased var) — deterministic two-stage
// ---------------------------------------------------------------------------
__global__ __launch_bounds__(256)
void bn_stats(const float* __restrict__ X, float* __restrict__ partials, int N)
{
    int tid = threadIdx.x;
    int c = tid & 127;
    int h = tid >> 7;     // 0/1
    float s = 0.f, s2 = 0.f;
    for (int r = blockIdx.x * 2 + h; r < N; r += gridDim.x * 2) {
        float v = X[(size_t)r * 128 + c];
        s += v; s2 += v * v;
    }
    __shared__ float sh[256], sh2[256];
    sh[tid] = s; sh2[tid] = s2;
    __syncthreads();
    if (tid < 128) {
        partials[blockIdx.x * 256 + tid]       = sh[tid] + sh[tid + 128];
        partials[blockIdx.x * 256 + 128 + tid] = sh2[tid] + sh2[tid + 128];
    }
}

__global__ __launch_bounds__(128)
void bn_finalize(const float* __restrict__ partials, int nblk, int N,
                 float* __restrict__ meanb, float* __restrict__ invstd)
{
    int c = threadIdx.x;
    float S = 0.f, S2 = 0.f;
    for (int b = 0; b < nblk; ++b) {
        S  += partials[b * 256 + c];
        S2 += partials[b * 256 + 128 + c];
    }
    float inv_n = 1.f / (float)N;
    float mu = S * inv_n;
    float var = S2 * inv_n - mu * mu;
    meanb[c]  = mu;
    invstd[c] = rsqrtf(var + 1e-5f);
}

__global__ __launch_bounds__(256)
void bn_apply_relu(float* __restrict__ X, const float* __restrict__ meanb,
                   const float* __restrict__ invstd, const float* __restrict__ g,
                   const float* __restrict__ bt)
{
    size_t idx = (size_t)blockIdx.x * 256 + threadIdx.x;
    int c = idx & 127;
    float v = (X[idx] - meanb[c]) * invstd[c] * g[c] + bt[c];
    X[idx] = fmaxf(v, 0.f);
}

__global__ __launch_bounds__(256)
void relu_kernel(float* __restrict__ X, int n)
{
    int idx = blockIdx.x * 256 + threadIdx.x;
    if (idx < n) X[idx] = fmaxf(X[idx], 0.f);
}

// ---------------------------------------------------------------------------
// Pools
// ---------------------------------------------------------------------------
__global__ __launch_bounds__(256)
void pool_spatial(float* __restrict__ out, const float* __restrict__ in,
                  int s, int D, int Nout)
{
    int idx = blockIdx.x * 256 + threadIdx.x;
    if (idx >= Nout * D) return;
    int c  = idx % D;
    int n2 = idx / D;
    int h  = s >> 1;
    int x2 = n2 % h;
    int y2 = (n2 / h) % h;
    int g  = n2 / (h * h);
    int base = (g * s + 2 * y2) * s + 2 * x2;
    float m = in[(size_t)base * D + c];
    m = fmaxf(m, in[(size_t)(base + 1) * D + c]);
    m = fmaxf(m, in[(size_t)(base + s) * D + c]);
    m = fmaxf(m, in[(size_t)(base + s + 1) * D + c]);
    out[(size_t)n2 * D + c] = m;
}

// orientation pool: in [B*6*64][10] -> out [B*64][10]
__global__ __launch_bounds__(256)
void pool_orient(float* __restrict__ out, const float* __restrict__ in)
{
    int idx = blockIdx.x * 256 + threadIdx.x;
    if (idx >= 512 * 10) return;
    int c = idx % 10;
    int n = idx / 10;
    int x = n % 8, y = (n / 8) % 8, b = n / 64;
    float m = -INFINITY;
    for (int o = 0; o < L_OR; ++o)
        m = fmaxf(m, in[(size_t)((((b * L_OR + o) * 8 + y) * 8 + x)) * 10 + c]);
    out[idx] = m;
}

// global max pool over 64 spatial nodes per graph + log_softmax
__global__ __launch_bounds__(128)
void global_pool_logsoftmax(const float* __restrict__ in, float* __restrict__ out)
{
    __shared__ float G[8][10];
    __shared__ float rowm[8], rowl[8];
    int t = threadIdx.x;
    if (t < 80) {
        int b = t / 10, c = t % 10;
        float m = -INFINITY;
        for (int p = 0; p < 64; ++p)
            m = fmaxf(m, in[(size_t)(b * 64 + p) * 10 + c]);
        G[b][c] = m;
    }
    __syncthreads();
    if (t < 8) {
        float m = -INFINITY;
        for (int c = 0; c < 10; ++c) m = fmaxf(m, G[t][c]);
        float s = 0.f;
        for (int c = 0; c < 10; ++c) s += expf(G[t][c] - m);
        rowm[t] = m; rowl[t] = logf(s);
    }
    __syncthreads();
    if (t < 80) {
        int b = t / 10, c = t % 10;
        out[t] = G[b][c] - rowm[b] - rowl[b];
    }
}

// ---------------------------------------------------------------------------
// Host-side orchestration
// ---------------------------------------------------------------------------
static void launch_lap128(float* out, const float* in, const float* tpp,
                          const float* ea, int S, int N, float alpha, hipStream_t st)
{
    dim3 grid(N / 8), block(256);
    if (S == 64)      hipLaunchKernelGGL(lap128_kernel<64>, grid, block, 0, st, out, in, tpp, ea, alpha);
    else if (S == 32) hipLaunchKernelGGL(lap128_kernel<32>, grid, block, 0, st, out, in, tpp, ea, alpha);
    else              hipLaunchKernelGGL(lap128_kernel<16>, grid, block, 0, st, out, in, tpp, ea, alpha);
}

// Full K=6 Chebyshev conv, D=128 -> 128. 3 buffers: X (input, destroyed),
// T (temp), O (output). In-place recurrence: T_{k+1} overwrites T_{k-1}.
static void cheb128_layer(float* X, float* T, float* O,
                          const float* W, const float* bias, const float* ea,
                          int S, int N, hipStream_t st)
{
    launch_lap128(T, X, nullptr, ea, S, N, 1.f, st);                         // T=T1
    hipLaunchKernelGGL(gemm_pair128, dim3(N / 64), dim3(256), 0, st,
                       O, X, W, T, W + 16384, bias, 1);                      // T0,T1
    launch_lap128(X, T, X, ea, S, N, 2.f, st);                               // X=T2
    launch_lap128(T, X, T, ea, S, N, 2.f, st);                               // T=T3
    hipLaunchKernelGGL(gemm_pair128, dim3(N / 64), dim3(256), 0, st,
                       O, X, W + 2 * 16384, T, W + 3 * 16384, (const float*)nullptr, 0);
    launch_lap128(X, T, X, ea, S, N, 2.f, st);                               // X=T4
    launch_lap128(T, X, T, ea, S, N, 2.f, st);                               // T=T5
    hipLaunchKernelGGL(gemm_pair128, dim3(N / 64), dim3(256), 0, st,
                       O, X, W + 4 * 16384, T, W + 5 * 16384, (const float*)nullptr, 0);
}

// K=6 Chebyshev conv, D=128 -> 10 (layer 6). Destroys X and T.
static void cheb128_layer_out10(float* X, float* T, float* O,
                                const float* W, const float* bias, const float* ea,
                                int S, int N, hipStream_t st)
{
    launch_lap128(T, X, nullptr, ea, S, N, 1.f, st);
    hipLaunchKernelGGL(gemm_pair_out10, dim3(N / 16), dim3(256), 0, st,
                       O, X, W, T, W + 1280, bias, N, 1);
    launch_lap128(X, T, X, ea, S, N, 2.f, st);
    launch_lap128(T, X, T, ea, S, N, 2.f, st);
    hipLaunchKernelGGL(gemm_pair_out10, dim3(N / 16), dim3(256), 0, st,
                       O, X, W + 2 * 1280, T, W + 3 * 1280, (const float*)nullptr, N, 0);
    launch_lap128(X, T, X, ea, S, N, 2.f, st);
    launch_lap128(T, X, T, ea, S, N, 2.f, st);
    hipLaunchKernelGGL(gemm_pair_out10, dim3(N / 16), dim3(256), 0, st,
                       O, X, W + 4 * 1280, T, W + 5 * 1280, (const float*)nullptr, N, 0);
}

static void bn_relu(float* X, int N, const float* g, const float* bt,
                    float* part, float* meanb, float* invstd, hipStream_t st)
{
    hipLaunchKernelGGL(bn_stats, dim3(256), dim3(256), 0, st, X, part, N);
    hipLaunchKernelGGL(bn_finalize, dim3(1), dim3(128), 0, st, part, 256, N, meanb, invstd);
    hipLaunchKernelGGL(bn_apply_relu, dim3((N * 128) / 256), dim3(256), 0, st,
                       X, meanb, invstd, g, bt);
}

extern "C" void kernel_launch(void* const* d_in, const int* in_sizes, int n_in,
                              void* d_out, int out_size, void* d_ws, size_t ws_size,
                              hipStream_t stream)
{
    const float* x   = (const float*)d_in[0];
    const float* ea1 = (const float*)d_in[2];
    const float* ea2 = (const float*)d_in[4];
    const float* ea3 = (const float*)d_in[6];
    const float* W1  = (const float*)d_in[12];
    const float* b1  = (const float*)d_in[13];
    const float* W2  = (const float*)d_in[14];
    const float* b2  = (const float*)d_in[15];
    const float* W3  = (const float*)d_in[16];
    const float* b3  = (const float*)d_in[17];
    const float* W4  = (const float*)d_in[18];
    const float* b4  = (const float*)d_in[19];
    const float* W5  = (const float*)d_in[20];
    const float* b5  = (const float*)d_in[21];
    const float* W6  = (const float*)d_in[22];
    const float* b6  = (const float*)d_in[23];
    const float* g1  = (const float*)d_in[24];
    const float* be1 = (const float*)d_in[25];
    const float* g2  = (const float*)d_in[26];
    const float* be2 = (const float*)d_in[27];
    const float* g3  = (const float*)d_in[28];
    const float* be3 = (const float*)d_in[29];
    const float* g4  = (const float*)d_in[30];
    const float* be4 = (const float*)d_in[31];
    const float* g5  = (const float*)d_in[32];
    const float* be5 = (const float*)d_in[33];

    const int N1 = 196608, N2 = 49152, N3 = 12288;
    const size_t NB = (size_t)N1 * 128;   // 25,165,824 floats per big buffer

    // Static device workspace (ignore d_ws entirely; it was too small).
    float* ws = nullptr;
    if (hipGetSymbolAddress((void**)&ws, HIP_SYMBOL(g_ws)) != hipSuccess || !ws)
        return;

    float* B0 = ws;
    float* B1 = ws + NB;
    float* B2 = ws + 2 * NB;
    float* tail   = ws + 3 * NB;
    float* t0     = tail;                        // N1*3
    float* t1     = t0 + (size_t)N1 * 3;
    float* t2     = t1 + (size_t)N1 * 3;
    float* l6out  = t2 + (size_t)N1 * 3;         // N3*10
    float* p3buf  = l6out + (size_t)N3 * 10;     // 3072*10
    float* p4buf  = p3buf + 3072 * 10;           // 512*10
    float* part   = p4buf + 512 * 10;            // 256*256
    float* meanb  = part + 256 * 256;            // 128
    float* invstd = meanb + 128;                 // 128

    // ---------- Layer 1: cheb(x[N1,3], W1) -> B0 ----------
    {
        dim3 g1d((N1 + 255) / 256), blk(256);
        hipLaunchKernelGGL(lap3_kernel<64>, g1d, blk, 0, stream, t0, x, (const float*)nullptr, ea1, 1.f); // t0=T1
        hipLaunchKernelGGL(gemm_k3pair, dim3(N1 / 2), blk, 0, stream, B0, x, W1, t0, W1 + 384, b1, 1);
        hipLaunchKernelGGL(lap3_kernel<64>, g1d, blk, 0, stream, t1, t0, x, ea1, 2.f);   // t1=T2
        hipLaunchKernelGGL(lap3_kernel<64>, g1d, blk, 0, stream, t2, t1, t0, ea1, 2.f);  // t2=T3
        hipLaunchKernelGGL(gemm_k3pair, dim3(N1 / 2), blk, 0, stream, B0, t1, W1 + 2 * 384, t2, W1 + 3 * 384, (const float*)nullptr, 0);
        hipLaunchKernelGGL(lap3_kernel<64>, g1d, blk, 0, stream, t0, t2, t1, ea1, 2.f);  // t0=T4
        hipLaunchKernelGGL(lap3_kernel<64>, g1d, blk, 0, stream, t1, t0, t2, ea1, 2.f);  // t1=T5
        hipLaunchKernelGGL(gemm_k3pair, dim3(N1 / 2), blk, 0, stream, B0, t0, W1 + 4 * 384, t1, W1 + 5 * 384, (const float*)nullptr, 0);
    }
    bn_relu(B0, N1, g1, be1, part, meanb, invstd, stream);     // h1 = B0

    // ---------- Layer 2 ----------
    cheb128_layer(B0, B1, B2, W2, b2, ea1, 64, N1, stream);
    bn_relu(B2, N1, g2, be2, part, meanb, invstd, stream);     // h2 = B2

    // pool1: 64 -> 32
    hipLaunchKernelGGL(pool_spatial, dim3((N2 * 128) / 256), dim3(256), 0, stream,
                       B0, B2, 64, 128, N2);

    // ---------- Layer 3 ----------
    cheb128_layer(B0, B1, B2, W3, b3, ea2, 32, N2, stream);
    bn_relu(B2, N2, g3, be3, part, meanb, invstd, stream);     // h3 = B2

    // ---------- Layer 4 ----------
    cheb128_layer(B2, B1, B0, W4, b4, ea2, 32, N2, stream);
    bn_relu(B0, N2, g4, be4, part, meanb, invstd, stream);     // h4 = B0

    // pool2: 32 -> 16
    hipLaunchKernelGGL(pool_spatial, dim3((N3 * 128) / 256), dim3(256), 0, stream,
                       B2, B0, 32, 128, N3);

    // ---------- Layer 5 ----------
    cheb128_layer(B2, B1, B0, W5, b5, ea3, 16, N3, stream);
    bn_relu(B0, N3, g5, be5, part, meanb, invstd, stream);     // h5 = B0

    // ---------- Layer 6 (out 10, relu only) ----------
    cheb128_layer_out10(B0, B1, l6out, W6, b6, ea3, 16, N3, stream);
    hipLaunchKernelGGL(relu_kernel, dim3((N3 * 10 + 255) / 256), dim3(256), 0, stream,
                       l6out, N3 * 10);

    // pool3: 16 -> 8 (D=10): l6out -> p3buf [3072,10]
    hipLaunchKernelGGL(pool_spatial, dim3((3072 * 10 + 255) / 256), dim3(256), 0, stream,
                       p3buf, l6out, 16, 10, 3072);
    // pool4: orientation max: p3buf -> p4buf [512,10]
    hipLaunchKernelGGL(pool_orient, dim3((512 * 10 + 255) / 256), dim3(256), 0, stream,
                       p4buf, p3buf);
    // global max + log_softmax -> d_out [8,10]
    hipLaunchKernelGGL(global_pool_logsoftmax, dim3(1), dim3(128), 0, stream,
                       p4buf, (float*)d_out);
}

// Round 3
// 1859.157 us; speedup vs baseline: 1.2994x; 1.2994x over previous
//
#include <hip/hip_runtime.h>
#include <math.h>

#define L_OR 6
#define N_BL 48   // B*L = 8*6

typedef unsigned short u16;
typedef __attribute__((ext_vector_type(8))) short s8v;   // 8 x bf16 (16B)
typedef __attribute__((ext_vector_type(4))) float f4v;

#define N1 196608
#define N2 49152
#define N3 12288

// ---- static device workspace (BSS, allocated at module load) ----
__device__ u16   g_cat[(size_t)N1 * 768];     // 302 MB: 6 T-slots, bf16
__device__ float g_O[(size_t)N1 * 128];       // 100 MB: GEMM output fp32
__device__ float g_Tt[5 * (size_t)N1 * 3];    // layer-1 T1..T5 fp32
__device__ u16   g_Bt[128 * 768];             // transposed bf16 weights
__device__ u16   g_W6t[16 * 768];             // layer-6 weights (padded cols)
__device__ float g_O10[(size_t)N3 * 10];
__device__ float g_p3[3072 * 10];
__device__ float g_p4[512 * 10];
__device__ float g_part[256 * 256];
__device__ float g_mean[128];
__device__ float g_inv[128];

__device__ __forceinline__ float b2f(u16 v) {
    return __uint_as_float(((unsigned)v) << 16);
}
__device__ __forceinline__ u16 f2b(float f) {
    unsigned u = __float_as_uint(f);
    return (u16)((u + 0x7FFFu + ((u >> 16) & 1u)) >> 16);   // RNE
}

// ---------------------------------------------------------------------------
// bf16 Laplacian on cat buffer: cat[:,outSlot] = alpha*L(cat[:,inSlot]) - cat[:,tppSlot]
// Edge blocks in ea: [x-fwd | x-bwd | y-fwd | y-bwd | ring-fwd | ring-bwd]
// No aliasing: out/in/tpp are distinct slots.
// ---------------------------------------------------------------------------
template<int S>
__global__ __launch_bounds__(256)
void lap128b(u16* __restrict__ cat, int outSlot, int inSlot, int tppSlot,
             const float* __restrict__ ea, float alpha)
{
    int node = blockIdx.x * 8 + (threadIdx.x >> 5);
    int c4   = threadIdx.x & 31;          // 4 channels per lane

    const int x = node % S;
    const int y = (node / S) % S;
    const int g = node / (S * S);
    const int o = g % L_OR;
    const int b = g / L_OR;
    const int szx = N_BL * S * (S - 1);

    float a0 = 0.f, a1 = 0.f, a2 = 0.f, a3 = 0.f;
    const int chOff = inSlot * 128 + c4 * 4;

    auto gather = [&](int src, float w) {
        ushort4 v = *(const ushort4*)(cat + (size_t)src * 768 + chOff);
        a0 += w * b2f(v.x); a1 += w * b2f(v.y);
        a2 += w * b2f(v.z); a3 += w * b2f(v.w);
    };

    const int basex = (g * S + y) * (S - 1);
    if (x > 0)     gather(node - 1, ea[basex + x - 1]);
    if (x < S - 1) gather(node + 1, ea[szx + basex + x]);
    if (y > 0)     gather(node - S, ea[2 * szx + (g * (S - 1) + y - 1) * S + x]);
    if (y < S - 1) gather(node + S, ea[3 * szx + (g * (S - 1) + y) * S + x]);
    {   int op = (o == 0) ? L_OR - 1 : o - 1;
        int sp = ((b * L_OR + op) * S + y) * S + x;
        gather(sp, ea[4 * szx + sp]);
    }
    {   int on = (o == L_OR - 1) ? 0 : o + 1;
        int sn = ((b * L_OR + on) * S + y) * S + x;
        gather(sn, ea[4 * szx + N_BL * S * S + node]);
    }

    float r0 = alpha * a0, r1 = alpha * a1, r2 = alpha * a2, r3 = alpha * a3;
    if (tppSlot >= 0) {
        ushort4 t = *(const ushort4*)(cat + (size_t)node * 768 + tppSlot * 128 + c4 * 4);
        r0 -= b2f(t.x); r1 -= b2f(t.y); r2 -= b2f(t.z); r3 -= b2f(t.w);
    }
    ushort4 out;
    out.x = f2b(r0); out.y = f2b(r1); out.z = f2b(r2); out.w = f2b(r3);
    *(ushort4*)(cat + (size_t)node * 768 + outSlot * 128 + c4 * 4) = out;
}

// fp32 laplacian for layer 1 (D=3)
template<int S>
__global__ __launch_bounds__(256)
void lap3_kernel(float* __restrict__ out, const float* __restrict__ in,
                 const float* __restrict__ tpp, const float* __restrict__ ea,
                 float alpha)
{
    const int NN = N_BL * S * S;
    int n = blockIdx.x * 256 + threadIdx.x;
    if (n >= NN) return;
    const int x = n % S, y = (n / S) % S, g = n / (S * S);
    const int o = g % L_OR, b = g / L_OR;
    const int szx = N_BL * S * (S - 1);

    float a0 = 0.f, a1 = 0.f, a2 = 0.f;
    auto gather = [&](int src, float w) {
        a0 += w * in[src * 3 + 0];
        a1 += w * in[src * 3 + 1];
        a2 += w * in[src * 3 + 2];
    };
    const int basex = (g * S + y) * (S - 1);
    if (x > 0)     gather(n - 1, ea[basex + x - 1]);
    if (x < S - 1) gather(n + 1, ea[szx + basex + x]);
    if (y > 0)     gather(n - S, ea[2 * szx + (g * (S - 1) + y - 1) * S + x]);
    if (y < S - 1) gather(n + S, ea[3 * szx + (g * (S - 1) + y) * S + x]);
    { int op = (o == 0) ? L_OR - 1 : o - 1; int sp = ((b * L_OR + op) * S + y) * S + x;
      gather(sp, ea[4 * szx + sp]); }
    { int on = (o == L_OR - 1) ? 0 : o + 1; int sn = ((b * L_OR + on) * S + y) * S + x;
      gather(sn, ea[4 * szx + N_BL * S * S + n]); }

    float r0 = alpha * a0, r1 = alpha * a1, r2 = alpha * a2;
    if (tpp) { r0 -= tpp[n * 3 + 0]; r1 -= tpp[n * 3 + 1]; r2 -= tpp[n * 3 + 2]; }
    out[n * 3 + 0] = r0; out[n * 3 + 1] = r1; out[n * 3 + 2] = r2;
}

// ---------------------------------------------------------------------------
// MFMA GEMM: O[N,128] = cat[N,768](bf16) @ Bt^T (Bt[128 cols][768] bf16) + bias
// Block: 256 threads = 4 waves, 128 rows (32 rows/wave as 2 stripes of 16).
// mfma_f32_16x16x32_bf16: A lane(row=l&15, k=(l>>4)*8+j); B lane(k same, col=l&15);
// C lane(col=l&15, row=(l>>4)*4+j).
// ---------------------------------------------------------------------------
__global__ __launch_bounds__(256)
void gemm_mfma_cat(float* __restrict__ O, const u16* __restrict__ A,
                   const u16* __restrict__ Bt, const float* __restrict__ bias)
{
    const int wave = threadIdx.x >> 6;
    const int lane = threadIdx.x & 63;
    const int lrow = lane & 15;
    const int kg   = lane >> 4;
    const int r0   = blockIdx.x * 128 + wave * 32;

    f4v acc[2][8] = {};
    const u16* A0 = A + (size_t)(r0 + lrow) * 768 + kg * 8;
    const u16* A1 = A0 + (size_t)16 * 768;

#pragma unroll 2
    for (int k0 = 0; k0 < 768; k0 += 32) {
        s8v a0 = *(const s8v*)(A0 + k0);
        s8v a1 = *(const s8v*)(A1 + k0);
#pragma unroll
        for (int ct = 0; ct < 8; ++ct) {
            s8v bb = *(const s8v*)(Bt + (size_t)(ct * 16 + lrow) * 768 + k0 + kg * 8);
            acc[0][ct] = __builtin_amdgcn_mfma_f32_16x16x32_bf16(a0, bb, acc[0][ct], 0, 0, 0);
            acc[1][ct] = __builtin_amdgcn_mfma_f32_16x16x32_bf16(a1, bb, acc[1][ct], 0, 0, 0);
        }
    }

#pragma unroll
    for (int s = 0; s < 2; ++s)
#pragma unroll
        for (int ct = 0; ct < 8; ++ct) {
            int col = ct * 16 + lrow;
            float bv = bias[col];
#pragma unroll
            for (int j = 0; j < 4; ++j) {
                int row = r0 + s * 16 + kg * 4 + j;
                O[(size_t)row * 128 + col] = acc[s][ct][j] + bv;
            }
        }
}

// weight prep: Bt[c][slot*128+d] = bf16(W[(slot-base)%6][d][c]),  W: [6][128][128]
__global__ __launch_bounds__(256)
void wprep(const float* __restrict__ W, u16* __restrict__ Bt, int base)
{
    int idx = blockIdx.x * 256 + threadIdx.x;     // < 128*768
    int c = idx / 768, kk = idx % 768;
    int slot = kk >> 7, d = kk & 127;
    int wk = slot - base; if (wk < 0) wk += 6;
    Bt[idx] = f2b(W[(size_t)wk * 16384 + d * 128 + c]);
}

// layer-6 weight prep: W6t[c][slot*128+d] = bf16(W6[(slot-base)%6][d][c]), c<10 else 0
__global__ __launch_bounds__(256)
void w6prep(const float* __restrict__ W, u16* __restrict__ W6t, int base)
{
    int idx = blockIdx.x * 256 + threadIdx.x;     // < 16*768
    if (idx >= 16 * 768) return;
    int c = idx / 768, kk = idx % 768;
    int slot = kk >> 7, d = kk & 127;
    int wk = slot - base; if (wk < 0) wk += 6;
    W6t[idx] = (c < 10) ? f2b(W[(size_t)wk * 1280 + d * 10 + c]) : (u16)0;
}

// layer-1 GEMM: O[N1,128] = sum_k T_k[N1,3] @ W1[k] + b1   (all fp32)
__global__ __launch_bounds__(256)
void l1gemm(float* __restrict__ O, const float* __restrict__ T0,
            const float* __restrict__ Tt, const float* __restrict__ W,
            const float* __restrict__ bias)
{
    int idx = blockIdx.x * 256 + threadIdx.x;     // < N1*128
    int c = idx & 127;
    int row = idx >> 7;
    float acc = bias[c];
#pragma unroll
    for (int j = 0; j < 3; ++j) acc += T0[row * 3 + j] * W[j * 128 + c];
#pragma unroll
    for (int k = 1; k < 6; ++k) {
        const float* T = Tt + (size_t)(k - 1) * N1 * 3;
#pragma unroll
        for (int j = 0; j < 3; ++j)
            acc += T[row * 3 + j] * W[(size_t)k * 384 + j * 128 + c];
    }
    O[idx] = acc;
}

// layer-6 GEMM + bias + relu: O10[N3,10] = cat[N3,768] @ W6t^T
__global__ __launch_bounds__(256)
void out10_cat(float* __restrict__ O10, const u16* __restrict__ cat,
               const u16* __restrict__ W6t, const float* __restrict__ bias)
{
    int col = threadIdx.x & 15;
    int row = blockIdx.x * 16 + (threadIdx.x >> 4);
    const u16* a = cat + (size_t)row * 768;
    const u16* w = W6t + (size_t)col * 768;
    float acc = 0.f;
#pragma unroll 4
    for (int k0 = 0; k0 < 768; k0 += 8) {
        s8v av = *(const s8v*)(a + k0);
        s8v wv = *(const s8v*)(w + k0);
#pragma unroll
        for (int j = 0; j < 8; ++j)
            acc += b2f((u16)av[j]) * b2f((u16)wv[j]);
    }
    if (col < 10)
        O10[(size_t)row * 10 + col] = fmaxf(acc + bias[col], 0.f);
}

// ---------------------------------------------------------------------------
// BatchNorm (training stats, biased var) — deterministic two-stage
// ---------------------------------------------------------------------------
__global__ __launch_bounds__(256)
void bn_stats(const float* __restrict__ X, float* __restrict__ partials, int N)
{
    int tid = threadIdx.x;
    int c = tid & 127;
    int h = tid >> 7;
    float s = 0.f, s2 = 0.f;
    for (int r = blockIdx.x * 2 + h; r < N; r += gridDim.x * 2) {
        float v = X[(size_t)r * 128 + c];
        s += v; s2 += v * v;
    }
    __shared__ float sh[256], sh2[256];
    sh[tid] = s; sh2[tid] = s2;
    __syncthreads();
    if (tid < 128) {
        partials[blockIdx.x * 256 + tid]       = sh[tid] + sh[tid + 128];
        partials[blockIdx.x * 256 + 128 + tid] = sh2[tid] + sh2[tid + 128];
    }
}

__global__ __launch_bounds__(128)
void bn_finalize(const float* __restrict__ partials, int nblk, int N,
                 float* __restrict__ meanb, float* __restrict__ invstd)
{
    int c = threadIdx.x;
    float S = 0.f, S2 = 0.f;
    for (int b = 0; b < nblk; ++b) {
        S  += partials[b * 256 + c];
        S2 += partials[b * 256 + 128 + c];
    }
    float inv_n = 1.f / (float)N;
    float mu = S * inv_n;
    float var = S2 * inv_n - mu * mu;
    meanb[c]  = mu;
    invstd[c] = rsqrtf(var + 1e-5f);
}

// BN + relu + store bf16 into cat slot
__global__ __launch_bounds__(256)
void bn_apply_cat(const float* __restrict__ O, u16* __restrict__ cat, int slot,
                  const float* __restrict__ meanb, const float* __restrict__ invstd,
                  const float* __restrict__ g, const float* __restrict__ bt)
{
    size_t idx = (size_t)blockIdx.x * 256 + threadIdx.x;
    int c = idx & 127;
    size_t row = idx >> 7;
    float v = (O[idx] - meanb[c]) * invstd[c] * g[c] + bt[c];
    cat[row * 768 + slot * 128 + c] = f2b(fmaxf(v, 0.f));
}

// spatial 2x2 max pool within cat: slot inSlot (N nodes, side s) -> slot outSlot
__global__ __launch_bounds__(256)
void pool_cat(u16* __restrict__ cat, int inSlot, int outSlot, int s, int Nout)
{
    int idx = blockIdx.x * 256 + threadIdx.x;
    if (idx >= Nout * 128) return;
    int c  = idx & 127;
    int n2 = idx >> 7;
    int h  = s >> 1;
    int x2 = n2 % h;
    int y2 = (n2 / h) % h;
    int g  = n2 / (h * h);
    int base = (g * s + 2 * y2) * s + 2 * x2;
    int co = inSlot * 128 + c;
    float m =          b2f(cat[(size_t)base * 768 + co]);
    m = fmaxf(m, b2f(cat[(size_t)(base + 1) * 768 + co]));
    m = fmaxf(m, b2f(cat[(size_t)(base + s) * 768 + co]));
    m = fmaxf(m, b2f(cat[(size_t)(base + s + 1) * 768 + co]));
    cat[(size_t)n2 * 768 + outSlot * 128 + c] = f2b(m);
}

// fp32 spatial pool (for layer-6 D=10 output)
__global__ __launch_bounds__(256)
void pool_spatial(float* __restrict__ out, const float* __restrict__ in,
                  int s, int D, int Nout)
{
    int idx = blockIdx.x * 256 + threadIdx.x;
    if (idx >= Nout * D) return;
    int c  = idx % D;
    int n2 = idx / D;
    int h  = s >> 1;
    int x2 = n2 % h;
    int y2 = (n2 / h) % h;
    int g  = n2 / (h * h);
    int base = (g * s + 2 * y2) * s + 2 * x2;
    float m = in[(size_t)base * D + c];
    m = fmaxf(m, in[(size_t)(base + 1) * D + c]);
    m = fmaxf(m, in[(size_t)(base + s) * D + c]);
    m = fmaxf(m, in[(size_t)(base + s + 1) * D + c]);
    out[(size_t)n2 * D + c] = m;
}

__global__ __launch_bounds__(256)
void pool_orient(float* __restrict__ out, const float* __restrict__ in)
{
    int idx = blockIdx.x * 256 + threadIdx.x;
    if (idx >= 512 * 10) return;
    int c = idx % 10;
    int n = idx / 10;
    int x = n % 8, y = (n / 8) % 8, b = n / 64;
    float m = -INFINITY;
    for (int o = 0; o < L_OR; ++o)
        m = fmaxf(m, in[(size_t)((((b * L_OR + o) * 8 + y) * 8 + x)) * 10 + c]);
    out[idx] = m;
}

__global__ __launch_bounds__(128)
void global_pool_logsoftmax(const float* __restrict__ in, float* __restrict__ out)
{
    __shared__ float G[8][10];
    __shared__ float rowm[8], rowl[8];
    int t = threadIdx.x;
    if (t < 80) {
        int b = t / 10, c = t % 10;
        float m = -INFINITY;
        for (int p = 0; p < 64; ++p)
            m = fmaxf(m, in[(size_t)(b * 64 + p) * 10 + c]);
        G[b][c] = m;
    }
    __syncthreads();
    if (t < 8) {
        float m = -INFINITY;
        for (int c = 0; c < 10; ++c) m = fmaxf(m, G[t][c]);
        float s = 0.f;
        for (int c = 0; c < 10; ++c) s += expf(G[t][c] - m);
        rowm[t] = m; rowl[t] = logf(s);
    }
    __syncthreads();
    if (t < 80) {
        int b = t / 10, c = t % 10;
        out[t] = G[b][c] - rowm[b] - rowl[b];
    }
}

// ---------------------------------------------------------------------------
// Host-side orchestration
// ---------------------------------------------------------------------------
static void launch_lapb(u16* cat, int os, int is, int ts, const float* ea,
                        int S, int N, float alpha, hipStream_t st)
{
    dim3 grid(N / 8), block(256);
    if (S == 64)      hipLaunchKernelGGL(lap128b<64>, grid, block, 0, st, cat, os, is, ts, ea, alpha);
    else if (S == 32) hipLaunchKernelGGL(lap128b<32>, grid, block, 0, st, cat, os, is, ts, ea, alpha);
    else              hipLaunchKernelGGL(lap128b<16>, grid, block, 0, st, cat, os, is, ts, ea, alpha);
}

// laps for one cheb layer: T_k lives in slot (k+base)%6; T0 already in slot base%6
static void cheb_laps(u16* cat, int base, const float* ea, int S, int N, hipStream_t st)
{
    for (int k = 1; k < 6; ++k) {
        int os = (k + base) % 6;
        int is = (k - 1 + base) % 6;
        int ts = (k >= 2) ? (k - 2 + base) % 6 : -1;
        launch_lapb(cat, os, is, ts, ea, S, N, (k == 1) ? 1.f : 2.f, st);
    }
}

static void bn_to_cat(const float* O, u16* cat, int slot, int N,
                      const float* g, const float* bt,
                      float* part, float* meanb, float* invstd, hipStream_t st)
{
    hipLaunchKernelGGL(bn_stats, dim3(256), dim3(256), 0, st, O, part, N);
    hipLaunchKernelGGL(bn_finalize, dim3(1), dim3(128), 0, st, part, 256, N, meanb, invstd);
    hipLaunchKernelGGL(bn_apply_cat, dim3((N * 128) / 256), dim3(256), 0, st,
                       O, cat, slot, meanb, invstd, g, bt);
}

extern "C" void kernel_launch(void* const* d_in, const int* in_sizes, int n_in,
                              void* d_out, int out_size, void* d_ws, size_t ws_size,
                              hipStream_t stream)
{
    const float* x   = (const float*)d_in[0];
    const float* ea1 = (const float*)d_in[2];
    const float* ea2 = (const float*)d_in[4];
    const float* ea3 = (const float*)d_in[6];
    const float* W1  = (const float*)d_in[12];
    const float* b1  = (const float*)d_in[13];
    const float* W2  = (const float*)d_in[14];
    const float* b2  = (const float*)d_in[15];
    const float* W3  = (const float*)d_in[16];
    const float* b3  = (const float*)d_in[17];
    const float* W4  = (const float*)d_in[18];
    const float* b4  = (const float*)d_in[19];
    const float* W5  = (const float*)d_in[20];
    const float* b5  = (const float*)d_in[21];
    const float* W6  = (const float*)d_in[22];
    const float* b6  = (const float*)d_in[23];
    const float* g1  = (const float*)d_in[24];
    const float* be1 = (const float*)d_in[25];
    const float* g2  = (const float*)d_in[26];
    const float* be2 = (const float*)d_in[27];
    const float* g3  = (const float*)d_in[28];
    const float* be3 = (const float*)d_in[29];
    const float* g4  = (const float*)d_in[30];
    const float* be4 = (const float*)d_in[31];
    const float* g5  = (const float*)d_in[32];
    const float* be5 = (const float*)d_in[33];

    u16 *cat, *Bt, *W6t;
    float *O, *Tt, *O10, *p3, *p4, *part, *meanb, *invstd;
    if (hipGetSymbolAddress((void**)&cat, HIP_SYMBOL(g_cat)) != hipSuccess) return;
    if (hipGetSymbolAddress((void**)&O,   HIP_SYMBOL(g_O))   != hipSuccess) return;
    if (hipGetSymbolAddress((void**)&Tt,  HIP_SYMBOL(g_Tt))  != hipSuccess) return;
    if (hipGetSymbolAddress((void**)&Bt,  HIP_SYMBOL(g_Bt))  != hipSuccess) return;
    if (hipGetSymbolAddress((void**)&W6t, HIP_SYMBOL(g_W6t)) != hipSuccess) return;
    if (hipGetSymbolAddress((void**)&O10, HIP_SYMBOL(g_O10)) != hipSuccess) return;
    if (hipGetSymbolAddress((void**)&p3,  HIP_SYMBOL(g_p3))  != hipSuccess) return;
    if (hipGetSymbolAddress((void**)&p4,  HIP_SYMBOL(g_p4))  != hipSuccess) return;
    if (hipGetSymbolAddress((void**)&part,   HIP_SYMBOL(g_part)) != hipSuccess) return;
    if (hipGetSymbolAddress((void**)&meanb,  HIP_SYMBOL(g_mean)) != hipSuccess) return;
    if (hipGetSymbolAddress((void**)&invstd, HIP_SYMBOL(g_inv))  != hipSuccess) return;

    dim3 blk(256);

    // ---------- Layer 1: cheb(x[N1,3], W1) -> O fp32; BN -> cat slot0 ----------
    {
        float* t1 = Tt;
        float* t2 = Tt + (size_t)N1 * 3;
        float* t3 = Tt + (size_t)2 * N1 * 3;
        float* t4 = Tt + (size_t)3 * N1 * 3;
        float* t5 = Tt + (size_t)4 * N1 * 3;
        dim3 gl((N1 + 255) / 256);
        hipLaunchKernelGGL(lap3_kernel<64>, gl, blk, 0, stream, t1, x,  (const float*)nullptr, ea1, 1.f);
        hipLaunchKernelGGL(lap3_kernel<64>, gl, blk, 0, stream, t2, t1, x,  ea1, 2.f);
        hipLaunchKernelGGL(lap3_kernel<64>, gl, blk, 0, stream, t3, t2, t1, ea1, 2.f);
        hipLaunchKernelGGL(lap3_kernel<64>, gl, blk, 0, stream, t4, t3, t2, ea1, 2.f);
        hipLaunchKernelGGL(lap3_kernel<64>, gl, blk, 0, stream, t5, t4, t3, ea1, 2.f);
        hipLaunchKernelGGL(l1gemm, dim3((N1 * 128) / 256), blk, 0, stream, O, x, Tt, W1, b1);
    }
    bn_to_cat(O, cat, 0, N1, g1, be1, part, meanb, invstd, stream);   // h1 -> slot0

    // ---------- Layer 2 (N1, base 0) ----------
    hipLaunchKernelGGL(wprep, dim3(384), blk, 0, stream, W2, Bt, 0);
    cheb_laps(cat, 0, ea1, 64, N1, stream);
    hipLaunchKernelGGL(gemm_mfma_cat, dim3(N1 / 128), blk, 0, stream, O, cat, Bt, b2);
    bn_to_cat(O, cat, 0, N1, g2, be2, part, meanb, invstd, stream);   // h2 -> slot0
    // pool1: 64 -> 32, h2(slot0,N1) -> slot5(N2)
    hipLaunchKernelGGL(pool_cat, dim3((N2 * 128) / 256), blk, 0, stream, cat, 0, 5, 64, N2);

    // ---------- Layer 3 (N2, base 5) ----------
    hipLaunchKernelGGL(wprep, dim3(384), blk, 0, stream, W3, Bt, 5);
    cheb_laps(cat, 5, ea2, 32, N2, stream);
    hipLaunchKernelGGL(gemm_mfma_cat, dim3(N2 / 128), blk, 0, stream, O, cat, Bt, b3);
    bn_to_cat(O, cat, 0, N2, g3, be3, part, meanb, invstd, stream);   // h3 -> slot0

    // ---------- Layer 4 (N2, base 0) ----------
    hipLaunchKernelGGL(wprep, dim3(384), blk, 0, stream, W4, Bt, 0);
    cheb_laps(cat, 0, ea2, 32, N2, stream);
    hipLaunchKernelGGL(gemm_mfma_cat, dim3(N2 / 128), blk, 0, stream, O, cat, Bt, b4);
    bn_to_cat(O, cat, 0, N2, g4, be4, part, meanb, invstd, stream);   // h4 -> slot0
    // pool2: 32 -> 16, h4(slot0,N2) -> slot5(N3)
    hipLaunchKernelGGL(pool_cat, dim3((N3 * 128) / 256), blk, 0, stream, cat, 0, 5, 32, N3);

    // ---------- Layer 5 (N3, base 5) ----------
    hipLaunchKernelGGL(wprep, dim3(384), blk, 0, stream, W5, Bt, 5);
    cheb_laps(cat, 5, ea3, 16, N3, stream);
    hipLaunchKernelGGL(gemm_mfma_cat, dim3(N3 / 128), blk, 0, stream, O, cat, Bt, b5);
    bn_to_cat(O, cat, 0, N3, g5, be5, part, meanb, invstd, stream);   // h5 -> slot0

    // ---------- Layer 6 (N3, base 0, out 10, relu fused) ----------
    hipLaunchKernelGGL(w6prep, dim3(48), blk, 0, stream, W6, W6t, 0);
    cheb_laps(cat, 0, ea3, 16, N3, stream);
    hipLaunchKernelGGL(out10_cat, dim3(N3 / 16), blk, 0, stream, O10, cat, W6t, b6);

    // pool3: 16 -> 8 (D=10)
    hipLaunchKernelGGL(pool_spatial, dim3((3072 * 10 + 255) / 256), blk, 0, stream,
                       p3, O10, 16, 10, 3072);
    hipLaunchKernelGGL(pool_orient, dim3((512 * 10 + 255) / 256), blk, 0, stream, p4, p3);
    hipLaunchKernelGGL(global_pool_logsoftmax, dim3(1), dim3(128), 0, stream,
                       p4, (float*)d_out);
}

// Round 4
// 1599.784 us; speedup vs baseline: 1.5101x; 1.1621x over previous
//
#include <hip/hip_runtime.h>
#include <math.h>

#define L_OR 6
#define N_BL 48   // B*L = 8*6

typedef unsigned short u16;
typedef __attribute__((ext_vector_type(8))) short s8v;   // 8 x bf16 (16B)
typedef __attribute__((ext_vector_type(4))) float f4v;

#define N1 196608
#define N2 49152
#define N3 12288

// ---- static device workspace (BSS, allocated at module load) ----
__device__ u16   g_cat[(size_t)N1 * 768 + 1024];  // 302 MB: 6 T-slots bf16 (+prefetch pad)
__device__ u16   g_O[(size_t)N1 * 128];           // 50 MB: GEMM output bf16
__device__ float g_Tt[5 * (size_t)N1 * 3];        // layer-1 T1..T5 fp32
__device__ u16   g_Bt[128 * 768 + 4096];          // fragment-ordered bf16 weights (+pad)
__device__ u16   g_W6t[16 * 768];                 // layer-6 weights (padded cols)
__device__ float g_O10[(size_t)N3 * 10];
__device__ float g_p3[3072 * 10];
__device__ float g_p4[512 * 10];
__device__ float g_part[256 * 256];
__device__ float g_mean[128];
__device__ float g_inv[128];

__device__ __forceinline__ float b2f(u16 v) {
    return __uint_as_float(((unsigned)v) << 16);
}
__device__ __forceinline__ u16 f2b(float f) {
    unsigned u = __float_as_uint(f);
    return (u16)((u + 0x7FFFu + ((u >> 16) & 1u)) >> 16);   // RNE
}

// ---------------------------------------------------------------------------
// bf16 Laplacian on cat buffer: cat[:,outSlot] = alpha*L(cat[:,inSlot]) - cat[:,tppSlot]
// Edge blocks in ea: [x-fwd | x-bwd | y-fwd | y-bwd | ring-fwd | ring-bwd]
// ---------------------------------------------------------------------------
template<int S>
__global__ __launch_bounds__(256)
void lap128b(u16* __restrict__ cat, int outSlot, int inSlot, int tppSlot,
             const float* __restrict__ ea, float alpha)
{
    int node = blockIdx.x * 8 + (threadIdx.x >> 5);
    int c4   = threadIdx.x & 31;          // 4 channels per lane

    const int x = node % S;
    const int y = (node / S) % S;
    const int g = node / (S * S);
    const int o = g % L_OR;
    const int b = g / L_OR;
    const int szx = N_BL * S * (S - 1);

    float a0 = 0.f, a1 = 0.f, a2 = 0.f, a3 = 0.f;
    const int chOff = inSlot * 128 + c4 * 4;

    auto gather = [&](int src, float w) {
        ushort4 v = *(const ushort4*)(cat + (size_t)src * 768 + chOff);
        a0 += w * b2f(v.x); a1 += w * b2f(v.y);
        a2 += w * b2f(v.z); a3 += w * b2f(v.w);
    };

    const int basex = (g * S + y) * (S - 1);
    if (x > 0)     gather(node - 1, ea[basex + x - 1]);
    if (x < S - 1) gather(node + 1, ea[szx + basex + x]);
    if (y > 0)     gather(node - S, ea[2 * szx + (g * (S - 1) + y - 1) * S + x]);
    if (y < S - 1) gather(node + S, ea[3 * szx + (g * (S - 1) + y) * S + x]);
    {   int op = (o == 0) ? L_OR - 1 : o - 1;
        int sp = ((b * L_OR + op) * S + y) * S + x;
        gather(sp, ea[4 * szx + sp]);
    }
    {   int on = (o == L_OR - 1) ? 0 : o + 1;
        int sn = ((b * L_OR + on) * S + y) * S + x;
        gather(sn, ea[4 * szx + N_BL * S * S + node]);
    }

    float r0 = alpha * a0, r1 = alpha * a1, r2 = alpha * a2, r3 = alpha * a3;
    if (tppSlot >= 0) {
        ushort4 t = *(const ushort4*)(cat + (size_t)node * 768 + tppSlot * 128 + c4 * 4);
        r0 -= b2f(t.x); r1 -= b2f(t.y); r2 -= b2f(t.z); r3 -= b2f(t.w);
    }
    ushort4 out;
    out.x = f2b(r0); out.y = f2b(r1); out.z = f2b(r2); out.w = f2b(r3);
    *(ushort4*)(cat + (size_t)node * 768 + outSlot * 128 + c4 * 4) = out;
}

// fp32 laplacian for layer 1 (D=3)
template<int S>
__global__ __launch_bounds__(256)
void lap3_kernel(float* __restrict__ out, const float* __restrict__ in,
                 const float* __restrict__ tpp, const float* __restrict__ ea,
                 float alpha)
{
    const int NN = N_BL * S * S;
    int n = blockIdx.x * 256 + threadIdx.x;
    if (n >= NN) return;
    const int x = n % S, y = (n / S) % S, g = n / (S * S);
    const int o = g % L_OR, b = g / L_OR;
    const int szx = N_BL * S * (S - 1);

    float a0 = 0.f, a1 = 0.f, a2 = 0.f;
    auto gather = [&](int src, float w) {
        a0 += w * in[src * 3 + 0];
        a1 += w * in[src * 3 + 1];
        a2 += w * in[src * 3 + 2];
    };
    const int basex = (g * S + y) * (S - 1);
    if (x > 0)     gather(n - 1, ea[basex + x - 1]);
    if (x < S - 1) gather(n + 1, ea[szx + basex + x]);
    if (y > 0)     gather(n - S, ea[2 * szx + (g * (S - 1) + y - 1) * S + x]);
    if (y < S - 1) gather(n + S, ea[3 * szx + (g * (S - 1) + y) * S + x]);
    { int op = (o == 0) ? L_OR - 1 : o - 1; int sp = ((b * L_OR + op) * S + y) * S + x;
      gather(sp, ea[4 * szx + sp]); }
    { int on = (o == L_OR - 1) ? 0 : o + 1; int sn = ((b * L_OR + on) * S + y) * S + x;
      gather(sn, ea[4 * szx + N_BL * S * S + n]); }

    float r0 = alpha * a0, r1 = alpha * a1, r2 = alpha * a2;
    if (tpp) { r0 -= tpp[n * 3 + 0]; r1 -= tpp[n * 3 + 1]; r2 -= tpp[n * 3 + 2]; }
    out[n * 3 + 0] = r0; out[n * 3 + 1] = r1; out[n * 3 + 2] = r2;
}

// ---------------------------------------------------------------------------
// MFMA GEMM: O[N,128](bf16) = cat[N,768](bf16) @ W + bias
// B is fragment-ordered: Bf[((k0s*8 + ct)*64 + lane)*8 + j], 1KB coalesced/wave.
// Manual depth-1 double-buffered pipeline, 2-phase (no reg copies).
// ---------------------------------------------------------------------------
__global__ __launch_bounds__(256)
void gemm_mfma_cat(u16* __restrict__ O, const u16* __restrict__ A,
                   const u16* __restrict__ Bf, const float* __restrict__ bias)
{
    const int wave = threadIdx.x >> 6;
    const int lane = threadIdx.x & 63;
    const int lrow = lane & 15;
    const int kg   = lane >> 4;
    const int r0   = blockIdx.x * 128 + wave * 32;

    const u16* A0 = A + (size_t)(r0 + lrow) * 768 + kg * 8;
    const u16* A1 = A0 + (size_t)16 * 768;
    const u16* Bp = Bf + lane * 8;

    f4v acc[2][8] = {};
    s8v a0e, a1e, a0o, a1o, be[8], bo[8];

    a0e = *(const s8v*)(A0);
    a1e = *(const s8v*)(A1);
#pragma unroll
    for (int ct = 0; ct < 8; ++ct) be[ct] = *(const s8v*)(Bp + ct * 512);

#pragma unroll 1
    for (int k0s = 0; k0s < 24; k0s += 2) {
        // prefetch odd (k0s+1)
        a0o = *(const s8v*)(A0 + (k0s + 1) * 32);
        a1o = *(const s8v*)(A1 + (k0s + 1) * 32);
#pragma unroll
        for (int ct = 0; ct < 8; ++ct)
            bo[ct] = *(const s8v*)(Bp + ((k0s + 1) * 8 + ct) * 512);
        // compute even with (a0e, be)
#pragma unroll
        for (int ct = 0; ct < 8; ++ct) {
            acc[0][ct] = __builtin_amdgcn_mfma_f32_16x16x32_bf16(a0e, be[ct], acc[0][ct], 0, 0, 0);
            acc[1][ct] = __builtin_amdgcn_mfma_f32_16x16x32_bf16(a1e, be[ct], acc[1][ct], 0, 0, 0);
        }
        // prefetch next even (k0s+2) — last iter reads pad (harmless)
        a0e = *(const s8v*)(A0 + (k0s + 2) * 32);
        a1e = *(const s8v*)(A1 + (k0s + 2) * 32);
#pragma unroll
        for (int ct = 0; ct < 8; ++ct)
            be[ct] = *(const s8v*)(Bp + ((k0s + 2) * 8 + ct) * 512);
        // compute odd with (a0o, bo)
#pragma unroll
        for (int ct = 0; ct < 8; ++ct) {
            acc[0][ct] = __builtin_amdgcn_mfma_f32_16x16x32_bf16(a0o, bo[ct], acc[0][ct], 0, 0, 0);
            acc[1][ct] = __builtin_amdgcn_mfma_f32_16x16x32_bf16(a1o, bo[ct], acc[1][ct], 0, 0, 0);
        }
    }

#pragma unroll
    for (int s = 0; s < 2; ++s)
#pragma unroll
        for (int ct = 0; ct < 8; ++ct) {
            int col = ct * 16 + lrow;
            float bv = bias[col];
#pragma unroll
            for (int j = 0; j < 4; ++j) {
                int row = r0 + s * 16 + kg * 4 + j;
                O[(size_t)row * 128 + col] = f2b(acc[s][ct][j] + bv);
            }
        }
}

// weight prep into fragment order:
// Bf[((k0s*8+ct)*64+lane)*8+j] = bf16(W[wk][d][col]) where
// k=k0s*32+(lane>>4)*8+j, col=ct*16+(lane&15), slot=k>>7, d=k&127, wk=(slot-base)%6
__global__ __launch_bounds__(256)
void wprep(const float* __restrict__ W, u16* __restrict__ Bf, int base)
{
    int idx = blockIdx.x * 256 + threadIdx.x;     // < 128*768
    int j    = idx & 7;
    int lane = (idx >> 3) & 63;
    int ct   = (idx >> 9) & 7;
    int k0s  = idx >> 12;
    int k    = k0s * 32 + (lane >> 4) * 8 + j;
    int col  = ct * 16 + (lane & 15);
    int slot = k >> 7, d = k & 127;
    int wk = slot - base; if (wk < 0) wk += 6;
    Bf[idx] = f2b(W[(size_t)wk * 16384 + d * 128 + col]);
}

// layer-6 weight prep: W6t[c][slot*128+d] = bf16(W6[(slot-base)%6][d][c]), c<10 else 0
__global__ __launch_bounds__(256)
void w6prep(const float* __restrict__ W, u16* __restrict__ W6t, int base)
{
    int idx = blockIdx.x * 256 + threadIdx.x;     // < 16*768
    if (idx >= 16 * 768) return;
    int c = idx / 768, kk = idx % 768;
    int slot = kk >> 7, d = kk & 127;
    int wk = slot - base; if (wk < 0) wk += 6;
    W6t[idx] = (c < 10) ? f2b(W[(size_t)wk * 1280 + d * 10 + c]) : (u16)0;
}

// layer-1 GEMM: O[N1,128](bf16) = sum_k T_k[N1,3] @ W1[k] + b1
__global__ __launch_bounds__(256)
void l1gemm(u16* __restrict__ O, const float* __restrict__ T0,
            const float* __restrict__ Tt, const float* __restrict__ W,
            const float* __restrict__ bias)
{
    int idx = blockIdx.x * 256 + threadIdx.x;     // < N1*128
    int c = idx & 127;
    int row = idx >> 7;
    float acc = bias[c];
#pragma unroll
    for (int j = 0; j < 3; ++j) acc += T0[row * 3 + j] * W[j * 128 + c];
#pragma unroll
    for (int k = 1; k < 6; ++k) {
        const float* T = Tt + (size_t)(k - 1) * N1 * 3;
#pragma unroll
        for (int j = 0; j < 3; ++j)
            acc += T[row * 3 + j] * W[(size_t)k * 384 + j * 128 + c];
    }
    O[idx] = f2b(acc);
}

// layer-6 GEMM + bias + relu: O10[N3,10] = cat[N3,768] @ W6t^T
__global__ __launch_bounds__(256)
void out10_cat(float* __restrict__ O10, const u16* __restrict__ cat,
               const u16* __restrict__ W6t, const float* __restrict__ bias)
{
    int col = threadIdx.x & 15;
    int row = blockIdx.x * 16 + (threadIdx.x >> 4);
    const u16* a = cat + (size_t)row * 768;
    const u16* w = W6t + (size_t)col * 768;
    float acc = 0.f;
#pragma unroll 4
    for (int k0 = 0; k0 < 768; k0 += 8) {
        s8v av = *(const s8v*)(a + k0);
        s8v wv = *(const s8v*)(w + k0);
#pragma unroll
        for (int j = 0; j < 8; ++j)
            acc += b2f((u16)av[j]) * b2f((u16)wv[j]);
    }
    if (col < 10)
        O10[(size_t)row * 10 + col] = fmaxf(acc + bias[col], 0.f);
}

// ---------------------------------------------------------------------------
// BatchNorm (training stats, biased var) — deterministic two-stage, bf16 input
// ---------------------------------------------------------------------------
__global__ __launch_bounds__(256)
void bn_stats(const u16* __restrict__ X, float* __restrict__ partials, int N)
{
    int tid = threadIdx.x;
    int c = tid & 127;
    int h = tid >> 7;
    float s = 0.f, s2 = 0.f;
    for (int r = blockIdx.x * 2 + h; r < N; r += gridDim.x * 2) {
        float v = b2f(X[(size_t)r * 128 + c]);
        s += v; s2 += v * v;
    }
    __shared__ float sh[256], sh2[256];
    sh[tid] = s; sh2[tid] = s2;
    __syncthreads();
    if (tid < 128) {
        partials[blockIdx.x * 256 + tid]       = sh[tid] + sh[tid + 128];
        partials[blockIdx.x * 256 + 128 + tid] = sh2[tid] + sh2[tid + 128];
    }
}

__global__ __launch_bounds__(128)
void bn_finalize(const float* __restrict__ partials, int nblk, int N,
                 float* __restrict__ meanb, float* __restrict__ invstd)
{
    int c = threadIdx.x;
    float S = 0.f, S2 = 0.f;
    for (int b = 0; b < nblk; ++b) {
        S  += partials[b * 256 + c];
        S2 += partials[b * 256 + 128 + c];
    }
    float inv_n = 1.f / (float)N;
    float mu = S * inv_n;
    float var = S2 * inv_n - mu * mu;
    meanb[c]  = mu;
    invstd[c] = rsqrtf(var + 1e-5f);
}

// BN + relu + store bf16 into cat slot
__global__ __launch_bounds__(256)
void bn_apply_cat(const u16* __restrict__ O, u16* __restrict__ cat, int slot,
                  const float* __restrict__ meanb, const float* __restrict__ invstd,
                  const float* __restrict__ g, const float* __restrict__ bt)
{
    size_t idx = (size_t)blockIdx.x * 256 + threadIdx.x;
    int c = idx & 127;
    size_t row = idx >> 7;
    float v = (b2f(O[idx]) - meanb[c]) * invstd[c] * g[c] + bt[c];
    cat[row * 768 + slot * 128 + c] = f2b(fmaxf(v, 0.f));
}

// BN + relu + 2x2 spatial max-pool fused: O (N nodes, side s, bf16) -> cat slot (Nout)
__global__ __launch_bounds__(256)
void bn_apply_pool(const u16* __restrict__ O, u16* __restrict__ cat, int outSlot,
                   int s, int Nout,
                   const float* __restrict__ meanb, const float* __restrict__ invstd,
                   const float* __restrict__ g, const float* __restrict__ bt)
{
    int idx = blockIdx.x * 256 + threadIdx.x;
    if (idx >= Nout * 128) return;
    int c  = idx & 127;
    int n2 = idx >> 7;
    int h  = s >> 1;
    int x2 = n2 % h;
    int y2 = (n2 / h) % h;
    int gg = n2 / (h * h);
    int base = (gg * s + 2 * y2) * s + 2 * x2;
    float sc = invstd[c] * g[c];
    float sh = bt[c] - meanb[c] * sc;
    float m =          b2f(O[(size_t)base * 128 + c]) * sc + sh;
    m = fmaxf(m, b2f(O[(size_t)(base + 1) * 128 + c]) * sc + sh);
    m = fmaxf(m, b2f(O[(size_t)(base + s) * 128 + c]) * sc + sh);
    m = fmaxf(m, b2f(O[(size_t)(base + s + 1) * 128 + c]) * sc + sh);
    cat[(size_t)n2 * 768 + outSlot * 128 + c] = f2b(fmaxf(m, 0.f));
}

// fp32 spatial pool (for layer-6 D=10 output)
__global__ __launch_bounds__(256)
void pool_spatial(float* __restrict__ out, const float* __restrict__ in,
                  int s, int D, int Nout)
{
    int idx = blockIdx.x * 256 + threadIdx.x;
    if (idx >= Nout * D) return;
    int c  = idx % D;
    int n2 = idx / D;
    int h  = s >> 1;
    int x2 = n2 % h;
    int y2 = (n2 / h) % h;
    int g  = n2 / (h * h);
    int base = (g * s + 2 * y2) * s + 2 * x2;
    float m = in[(size_t)base * D + c];
    m = fmaxf(m, in[(size_t)(base + 1) * D + c]);
    m = fmaxf(m, in[(size_t)(base + s) * D + c]);
    m = fmaxf(m, in[(size_t)(base + s + 1) * D + c]);
    out[(size_t)n2 * D + c] = m;
}

__global__ __launch_bounds__(256)
void pool_orient(float* __restrict__ out, const float* __restrict__ in)
{
    int idx = blockIdx.x * 256 + threadIdx.x;
    if (idx >= 512 * 10) return;
    int c = idx % 10;
    int n = idx / 10;
    int x = n % 8, y = (n / 8) % 8, b = n / 64;
    float m = -INFINITY;
    for (int o = 0; o < L_OR; ++o)
        m = fmaxf(m, in[(size_t)((((b * L_OR + o) * 8 + y) * 8 + x)) * 10 + c]);
    out[idx] = m;
}

__global__ __launch_bounds__(128)
void global_pool_logsoftmax(const float* __restrict__ in, float* __restrict__ out)
{
    __shared__ float G[8][10];
    __shared__ float rowm[8], rowl[8];
    int t = threadIdx.x;
    if (t < 80) {
        int b = t / 10, c = t % 10;
        float m = -INFINITY;
        for (int p = 0; p < 64; ++p)
            m = fmaxf(m, in[(size_t)(b * 64 + p) * 10 + c]);
        G[b][c] = m;
    }
    __syncthreads();
    if (t < 8) {
        float m = -INFINITY;
        for (int c = 0; c < 10; ++c) m = fmaxf(m, G[t][c]);
        float s = 0.f;
        for (int c = 0; c < 10; ++c) s += expf(G[t][c] - m);
        rowm[t] = m; rowl[t] = logf(s);
    }
    __syncthreads();
    if (t < 80) {
        int b = t / 10, c = t % 10;
        out[t] = G[b][c] - rowm[b] - rowl[b];
    }
}

// ---------------------------------------------------------------------------
// Host-side orchestration
// ---------------------------------------------------------------------------
static void launch_lapb(u16* cat, int os, int is, int ts, const float* ea,
                        int S, int N, float alpha, hipStream_t st)
{
    dim3 grid(N / 8), block(256);
    if (S == 64)      hipLaunchKernelGGL(lap128b<64>, grid, block, 0, st, cat, os, is, ts, ea, alpha);
    else if (S == 32) hipLaunchKernelGGL(lap128b<32>, grid, block, 0, st, cat, os, is, ts, ea, alpha);
    else              hipLaunchKernelGGL(lap128b<16>, grid, block, 0, st, cat, os, is, ts, ea, alpha);
}

static void cheb_laps(u16* cat, int base, const float* ea, int S, int N, hipStream_t st)
{
    for (int k = 1; k < 6; ++k) {
        int os = (k + base) % 6;
        int is = (k - 1 + base) % 6;
        int ts = (k >= 2) ? (k - 2 + base) % 6 : -1;
        launch_lapb(cat, os, is, ts, ea, S, N, (k == 1) ? 1.f : 2.f, st);
    }
}

static void bn_pass(const u16* O, int N, float* part, float* meanb, float* invstd,
                    hipStream_t st)
{
    hipLaunchKernelGGL(bn_stats, dim3(256), dim3(256), 0, st, O, part, N);
    hipLaunchKernelGGL(bn_finalize, dim3(1), dim3(128), 0, st, part, 256, N, meanb, invstd);
}

extern "C" void kernel_launch(void* const* d_in, const int* in_sizes, int n_in,
                              void* d_out, int out_size, void* d_ws, size_t ws_size,
                              hipStream_t stream)
{
    const float* x   = (const float*)d_in[0];
    const float* ea1 = (const float*)d_in[2];
    const float* ea2 = (const float*)d_in[4];
    const float* ea3 = (const float*)d_in[6];
    const float* W1  = (const float*)d_in[12];
    const float* b1  = (const float*)d_in[13];
    const float* W2  = (const float*)d_in[14];
    const float* b2  = (const float*)d_in[15];
    const float* W3  = (const float*)d_in[16];
    const float* b3  = (const float*)d_in[17];
    const float* W4  = (const float*)d_in[18];
    const float* b4  = (const float*)d_in[19];
    const float* W5  = (const float*)d_in[20];
    const float* b5  = (const float*)d_in[21];
    const float* W6  = (const float*)d_in[22];
    const float* b6  = (const float*)d_in[23];
    const float* g1  = (const float*)d_in[24];
    const float* be1 = (const float*)d_in[25];
    const float* g2  = (const float*)d_in[26];
    const float* be2 = (const float*)d_in[27];
    const float* g3  = (const float*)d_in[28];
    const float* be3 = (const float*)d_in[29];
    const float* g4  = (const float*)d_in[30];
    const float* be4 = (const float*)d_in[31];
    const float* g5  = (const float*)d_in[32];
    const float* be5 = (const float*)d_in[33];

    u16 *cat, *O, *Bt, *W6t;
    float *Tt, *O10, *p3, *p4, *part, *meanb, *invstd;
    if (hipGetSymbolAddress((void**)&cat, HIP_SYMBOL(g_cat)) != hipSuccess) return;
    if (hipGetSymbolAddress((void**)&O,   HIP_SYMBOL(g_O))   != hipSuccess) return;
    if (hipGetSymbolAddress((void**)&Tt,  HIP_SYMBOL(g_Tt))  != hipSuccess) return;
    if (hipGetSymbolAddress((void**)&Bt,  HIP_SYMBOL(g_Bt))  != hipSuccess) return;
    if (hipGetSymbolAddress((void**)&W6t, HIP_SYMBOL(g_W6t)) != hipSuccess) return;
    if (hipGetSymbolAddress((void**)&O10, HIP_SYMBOL(g_O10)) != hipSuccess) return;
    if (hipGetSymbolAddress((void**)&p3,  HIP_SYMBOL(g_p3))  != hipSuccess) return;
    if (hipGetSymbolAddress((void**)&p4,  HIP_SYMBOL(g_p4))  != hipSuccess) return;
    if (hipGetSymbolAddress((void**)&part,   HIP_SYMBOL(g_part)) != hipSuccess) return;
    if (hipGetSymbolAddress((void**)&meanb,  HIP_SYMBOL(g_mean)) != hipSuccess) return;
    if (hipGetSymbolAddress((void**)&invstd, HIP_SYMBOL(g_inv))  != hipSuccess) return;

    dim3 blk(256);

    // ---------- Layer 1: cheb(x[N1,3], W1) -> O bf16; BN -> cat slot0 ----------
    {
        float* t1 = Tt;
        float* t2 = Tt + (size_t)N1 * 3;
        float* t3 = Tt + (size_t)2 * N1 * 3;
        float* t4 = Tt + (size_t)3 * N1 * 3;
        float* t5 = Tt + (size_t)4 * N1 * 3;
        dim3 gl((N1 + 255) / 256);
        hipLaunchKernelGGL(lap3_kernel<64>, gl, blk, 0, stream, t1, x,  (const float*)nullptr, ea1, 1.f);
        hipLaunchKernelGGL(lap3_kernel<64>, gl, blk, 0, stream, t2, t1, x,  ea1, 2.f);
        hipLaunchKernelGGL(lap3_kernel<64>, gl, blk, 0, stream, t3, t2, t1, ea1, 2.f);
        hipLaunchKernelGGL(lap3_kernel<64>, gl, blk, 0, stream, t4, t3, t2, ea1, 2.f);
        hipLaunchKernelGGL(lap3_kernel<64>, gl, blk, 0, stream, t5, t4, t3, ea1, 2.f);
        hipLaunchKernelGGL(l1gemm, dim3((N1 * 128) / 256), blk, 0, stream, O, x, Tt, W1, b1);
    }
    bn_pass(O, N1, part, meanb, invstd, stream);
    hipLaunchKernelGGL(bn_apply_cat, dim3((N1 * 128) / 256), blk, 0, stream,
                       O, cat, 0, meanb, invstd, g1, be1);

    // ---------- Layer 2 (N1, base 0) ----------
    hipLaunchKernelGGL(wprep, dim3(384), blk, 0, stream, W2, Bt, 0);
    cheb_laps(cat, 0, ea1, 64, N1, stream);
    hipLaunchKernelGGL(gemm_mfma_cat, dim3(N1 / 128), blk, 0, stream, O, cat, Bt, b2);
    bn_pass(O, N1, part, meanb, invstd, stream);
    // fused BN+relu+pool1 (64->32): -> slot5 (h2 pooled @N2)
    hipLaunchKernelGGL(bn_apply_pool, dim3((N2 * 128) / 256), blk, 0, stream,
                       O, cat, 5, 64, N2, meanb, invstd, g2, be2);

    // ---------- Layer 3 (N2, base 5) ----------
    hipLaunchKernelGGL(wprep, dim3(384), blk, 0, stream, W3, Bt, 5);
    cheb_laps(cat, 5, ea2, 32, N2, stream);
    hipLaunchKernelGGL(gemm_mfma_cat, dim3(N2 / 128), blk, 0, stream, O, cat, Bt, b3);
    bn_pass(O, N2, part, meanb, invstd, stream);
    hipLaunchKernelGGL(bn_apply_cat, dim3((N2 * 128) / 256), blk, 0, stream,
                       O, cat, 0, meanb, invstd, g3, be3);   // h3 -> slot0

    // ---------- Layer 4 (N2, base 0) ----------
    hipLaunchKernelGGL(wprep, dim3(384), blk, 0, stream, W4, Bt, 0);
    cheb_laps(cat, 0, ea2, 32, N2, stream);
    hipLaunchKernelGGL(gemm_mfma_cat, dim3(N2 / 128), blk, 0, stream, O, cat, Bt, b4);
    bn_pass(O, N2, part, meanb, invstd, stream);
    // fused BN+relu+pool2 (32->16): -> slot5 (h4 pooled @N3)
    hipLaunchKernelGGL(bn_apply_pool, dim3((N3 * 128) / 256), blk, 0, stream,
                       O, cat, 5, 32, N3, meanb, invstd, g4, be4);

    // ---------- Layer 5 (N3, base 5) ----------
    hipLaunchKernelGGL(wprep, dim3(384), blk, 0, stream, W5, Bt, 5);
    cheb_laps(cat, 5, ea3, 16, N3, stream);
    hipLaunchKernelGGL(gemm_mfma_cat, dim3(N3 / 128), blk, 0, stream, O, cat, Bt, b5);
    bn_pass(O, N3, part, meanb, invstd, stream);
    hipLaunchKernelGGL(bn_apply_cat, dim3((N3 * 128) / 256), blk, 0, stream,
                       O, cat, 0, meanb, invstd, g5, be5);   // h5 -> slot0

    // ---------- Layer 6 (N3, base 0, out 10, relu fused) ----------
    hipLaunchKernelGGL(w6prep, dim3(48), blk, 0, stream, W6, W6t, 0);
    cheb_laps(cat, 0, ea3, 16, N3, stream);
    hipLaunchKernelGGL(out10_cat, dim3(N3 / 16), blk, 0, stream, O10, cat, W6t, b6);

    // pool3: 16 -> 8 (D=10)
    hipLaunchKernelGGL(pool_spatial, dim3((3072 * 10 + 255) / 256), blk, 0, stream,
                       p3, O10, 16, 10, 3072);
    hipLaunchKernelGGL(pool_orient, dim3((512 * 10 + 255) / 256), blk, 0, stream, p4, p3);
    hipLaunchKernelGGL(global_pool_logsoftmax, dim3(1), dim3(128), 0, stream,
                       p4, (float*)d_out);
}

// Round 5
// 1416.078 us; speedup vs baseline: 1.7060x; 1.1297x over previous
//
#include <hip/hip_runtime.h>
#include <math.h>

#define L_OR 6
#define N_BL 48   // B*L = 8*6

typedef unsigned short u16;
typedef __attribute__((ext_vector_type(8))) short s8v;   // 8 x bf16 (16B)
typedef __attribute__((ext_vector_type(4))) float f4v;

#define N1 196608
#define N2 49152
#define N3 12288

// ---- static device workspace (BSS, allocated at module load) ----
__device__ u16   g_cat[(size_t)N1 * 768 + 1024];  // 302 MB: 6 T-slots bf16 (+prefetch pad)
__device__ u16   g_O[(size_t)N1 * 128];           // 50 MB: GEMM output bf16
__device__ float g_Tt[5 * (size_t)N1 * 3];        // layer-1 T1..T5 fp32
__device__ u16   g_Bt[128 * 768 + 4096];          // fragment-ordered bf16 weights (+pad)
__device__ u16   g_W6t[16 * 768];                 // layer-6 weights (padded cols)
__device__ float g_O10[(size_t)N3 * 10];
__device__ float g_p3[3072 * 10];
__device__ float g_p4[512 * 10];
__device__ float g_part[1536 * 256];              // per-block BN partials
__device__ float g_mean[128];
__device__ float g_inv[128];

__device__ __forceinline__ float b2f(u16 v) {
    return __uint_as_float(((unsigned)v) << 16);
}
__device__ __forceinline__ u16 f2b(float f) {
    unsigned u = __float_as_uint(f);
    return (u16)((u + 0x7FFFu + ((u >> 16) & 1u)) >> 16);   // RNE
}

// ---------------------------------------------------------------------------
// bf16 Laplacian on cat buffer: cat[:,outSlot] = alpha*L(cat[:,inSlot]) - cat[:,tppSlot]
// 16 lanes per node, 8 channels (16B) per lane.
// ---------------------------------------------------------------------------
template<int S>
__global__ __launch_bounds__(256)
void lap128b(u16* __restrict__ cat, int outSlot, int inSlot, int tppSlot,
             const float* __restrict__ ea, float alpha)
{
    int node = blockIdx.x * 16 + (threadIdx.x >> 4);
    int c8   = threadIdx.x & 15;          // 8 channels per lane

    const int x = node % S;
    const int y = (node / S) % S;
    const int g = node / (S * S);
    const int o = g % L_OR;
    const int b = g / L_OR;
    const int szx = N_BL * S * (S - 1);

    float a[8] = {0.f, 0.f, 0.f, 0.f, 0.f, 0.f, 0.f, 0.f};
    const int chOff = inSlot * 128 + c8 * 8;

    auto gather = [&](int src, float w) {
        s8v v = *(const s8v*)(cat + (size_t)src * 768 + chOff);
#pragma unroll
        for (int j = 0; j < 8; ++j) a[j] += w * b2f((u16)v[j]);
    };

    const int basex = (g * S + y) * (S - 1);
    if (x > 0)     gather(node - 1, ea[basex + x - 1]);
    if (x < S - 1) gather(node + 1, ea[szx + basex + x]);
    if (y > 0)     gather(node - S, ea[2 * szx + (g * (S - 1) + y - 1) * S + x]);
    if (y < S - 1) gather(node + S, ea[3 * szx + (g * (S - 1) + y) * S + x]);
    {   int op = (o == 0) ? L_OR - 1 : o - 1;
        int sp = ((b * L_OR + op) * S + y) * S + x;
        gather(sp, ea[4 * szx + sp]);
    }
    {   int on = (o == L_OR - 1) ? 0 : o + 1;
        int sn = ((b * L_OR + on) * S + y) * S + x;
        gather(sn, ea[4 * szx + N_BL * S * S + node]);
    }

    float r[8];
#pragma unroll
    for (int j = 0; j < 8; ++j) r[j] = alpha * a[j];
    if (tppSlot >= 0) {
        s8v t = *(const s8v*)(cat + (size_t)node * 768 + tppSlot * 128 + c8 * 8);
#pragma unroll
        for (int j = 0; j < 8; ++j) r[j] -= b2f((u16)t[j]);
    }
    s8v ov;
#pragma unroll
    for (int j = 0; j < 8; ++j) ov[j] = (short)f2b(r[j]);
    *(s8v*)(cat + (size_t)node * 768 + outSlot * 128 + c8 * 8) = ov;
}

// fp32 laplacian for layer 1 (D=3)
template<int S>
__global__ __launch_bounds__(256)
void lap3_kernel(float* __restrict__ out, const float* __restrict__ in,
                 const float* __restrict__ tpp, const float* __restrict__ ea,
                 float alpha)
{
    const int NN = N_BL * S * S;
    int n = blockIdx.x * 256 + threadIdx.x;
    if (n >= NN) return;
    const int x = n % S, y = (n / S) % S, g = n / (S * S);
    const int o = g % L_OR, b = g / L_OR;
    const int szx = N_BL * S * (S - 1);

    float a0 = 0.f, a1 = 0.f, a2 = 0.f;
    auto gather = [&](int src, float w) {
        a0 += w * in[src * 3 + 0];
        a1 += w * in[src * 3 + 1];
        a2 += w * in[src * 3 + 2];
    };
    const int basex = (g * S + y) * (S - 1);
    if (x > 0)     gather(n - 1, ea[basex + x - 1]);
    if (x < S - 1) gather(n + 1, ea[szx + basex + x]);
    if (y > 0)     gather(n - S, ea[2 * szx + (g * (S - 1) + y - 1) * S + x]);
    if (y < S - 1) gather(n + S, ea[3 * szx + (g * (S - 1) + y) * S + x]);
    { int op = (o == 0) ? L_OR - 1 : o - 1; int sp = ((b * L_OR + op) * S + y) * S + x;
      gather(sp, ea[4 * szx + sp]); }
    { int on = (o == L_OR - 1) ? 0 : o + 1; int sn = ((b * L_OR + on) * S + y) * S + x;
      gather(sn, ea[4 * szx + N_BL * S * S + n]); }

    float r0 = alpha * a0, r1 = alpha * a1, r2 = alpha * a2;
    if (tpp) { r0 -= tpp[n * 3 + 0]; r1 -= tpp[n * 3 + 1]; r2 -= tpp[n * 3 + 2]; }
    out[n * 3 + 0] = r0; out[n * 3 + 1] = r1; out[n * 3 + 2] = r2;
}

// ---------------------------------------------------------------------------
// MFMA GEMM + fused BN-stats: O[N,128](bf16) = cat[N,768](bf16) @ W + bias,
// and partials[blk][256] = per-block channel {sum, sumsq} of the fp32 output.
// ---------------------------------------------------------------------------
__global__ __launch_bounds__(256)
void gemm_mfma_cat(u16* __restrict__ O, const u16* __restrict__ A,
                   const u16* __restrict__ Bf, const float* __restrict__ bias,
                   float* __restrict__ partials)
{
    const int wave = threadIdx.x >> 6;
    const int lane = threadIdx.x & 63;
    const int lrow = lane & 15;
    const int kg   = lane >> 4;
    const int r0   = blockIdx.x * 128 + wave * 32;

    const u16* A0 = A + (size_t)(r0 + lrow) * 768 + kg * 8;
    const u16* A1 = A0 + (size_t)16 * 768;
    const u16* Bp = Bf + lane * 8;

    f4v acc[2][8] = {};
    s8v a0e, a1e, a0o, a1o, be[8], bo[8];

    a0e = *(const s8v*)(A0);
    a1e = *(const s8v*)(A1);
#pragma unroll
    for (int ct = 0; ct < 8; ++ct) be[ct] = *(const s8v*)(Bp + ct * 512);

#pragma unroll 1
    for (int k0s = 0; k0s < 24; k0s += 2) {
        a0o = *(const s8v*)(A0 + (k0s + 1) * 32);
        a1o = *(const s8v*)(A1 + (k0s + 1) * 32);
#pragma unroll
        for (int ct = 0; ct < 8; ++ct)
            bo[ct] = *(const s8v*)(Bp + ((k0s + 1) * 8 + ct) * 512);
#pragma unroll
        for (int ct = 0; ct < 8; ++ct) {
            acc[0][ct] = __builtin_amdgcn_mfma_f32_16x16x32_bf16(a0e, be[ct], acc[0][ct], 0, 0, 0);
            acc[1][ct] = __builtin_amdgcn_mfma_f32_16x16x32_bf16(a1e, be[ct], acc[1][ct], 0, 0, 0);
        }
        a0e = *(const s8v*)(A0 + (k0s + 2) * 32);
        a1e = *(const s8v*)(A1 + (k0s + 2) * 32);
#pragma unroll
        for (int ct = 0; ct < 8; ++ct)
            be[ct] = *(const s8v*)(Bp + ((k0s + 2) * 8 + ct) * 512);
#pragma unroll
        for (int ct = 0; ct < 8; ++ct) {
            acc[0][ct] = __builtin_amdgcn_mfma_f32_16x16x32_bf16(a0o, bo[ct], acc[0][ct], 0, 0, 0);
            acc[1][ct] = __builtin_amdgcn_mfma_f32_16x16x32_bf16(a1o, bo[ct], acc[1][ct], 0, 0, 0);
        }
    }

    __shared__ float sred[4][2][8][16];
    float cs[8], cq[8];
#pragma unroll
    for (int ct = 0; ct < 8; ++ct) { cs[ct] = 0.f; cq[ct] = 0.f; }

#pragma unroll
    for (int s = 0; s < 2; ++s)
#pragma unroll
        for (int ct = 0; ct < 8; ++ct) {
            int col = ct * 16 + lrow;
            float bv = bias[col];
#pragma unroll
            for (int j = 0; j < 4; ++j) {
                int row = r0 + s * 16 + kg * 4 + j;
                float v = acc[s][ct][j] + bv;
                O[(size_t)row * 128 + col] = f2b(v);
                cs[ct] += v; cq[ct] += v * v;
            }
        }
    // reduce over kg (lanes lrow, lrow+16, lrow+32, lrow+48)
#pragma unroll
    for (int ct = 0; ct < 8; ++ct) {
        cs[ct] += __shfl_xor(cs[ct], 16); cs[ct] += __shfl_xor(cs[ct], 32);
        cq[ct] += __shfl_xor(cq[ct], 16); cq[ct] += __shfl_xor(cq[ct], 32);
    }
    if (lane < 16) {
#pragma unroll
        for (int ct = 0; ct < 8; ++ct) {
            sred[wave][0][ct][lane] = cs[ct];
            sred[wave][1][ct][lane] = cq[ct];
        }
    }
    __syncthreads();
    if (threadIdx.x < 128) {
        int ct = threadIdx.x >> 4, lr = threadIdx.x & 15;
        float S = 0.f, Q = 0.f;
#pragma unroll
        for (int w = 0; w < 4; ++w) { S += sred[w][0][ct][lr]; Q += sred[w][1][ct][lr]; }
        partials[blockIdx.x * 256 + threadIdx.x]       = S;
        partials[blockIdx.x * 256 + 128 + threadIdx.x] = Q;
    }
}

// weight prep into fragment order (see gemm_mfma_cat)
__global__ __launch_bounds__(256)
void wprep(const float* __restrict__ W, u16* __restrict__ Bf, int base)
{
    int idx = blockIdx.x * 256 + threadIdx.x;     // < 128*768
    int j    = idx & 7;
    int lane = (idx >> 3) & 63;
    int ct   = (idx >> 9) & 7;
    int k0s  = idx >> 12;
    int k    = k0s * 32 + (lane >> 4) * 8 + j;
    int col  = ct * 16 + (lane & 15);
    int slot = k >> 7, d = k & 127;
    int wk = slot - base; if (wk < 0) wk += 6;
    Bf[idx] = f2b(W[(size_t)wk * 16384 + d * 128 + col]);
}

__global__ __launch_bounds__(256)
void w6prep(const float* __restrict__ W, u16* __restrict__ W6t, int base)
{
    int idx = blockIdx.x * 256 + threadIdx.x;     // < 16*768
    if (idx >= 16 * 768) return;
    int c = idx / 768, kk = idx % 768;
    int slot = kk >> 7, d = kk & 127;
    int wk = slot - base; if (wk < 0) wk += 6;
    W6t[idx] = (c < 10) ? f2b(W[(size_t)wk * 1280 + d * 10 + c]) : (u16)0;
}

// layer-1 GEMM + fused stats. Block = 128 rows; T values staged in LDS.
__global__ __launch_bounds__(256)
void l1gemm(u16* __restrict__ O, const float* __restrict__ T0,
            const float* __restrict__ Tt, const float* __restrict__ W,
            const float* __restrict__ bias, float* __restrict__ partials)
{
    __shared__ float Ts[128][18];
    __shared__ float sh[2][128], sh2[2][128];
    int tid = threadIdx.x;
    int rbase = blockIdx.x * 128;
    for (int i = tid; i < 128 * 18; i += 256) {
        int r = i / 18, t = i % 18;
        int k = t / 3, j = t % 3;
        Ts[r][t] = (k == 0) ? T0[(size_t)(rbase + r) * 3 + j]
                            : Tt[(size_t)(k - 1) * N1 * 3 + (size_t)(rbase + r) * 3 + j];
    }
    __syncthreads();
    int c = tid & 127, h = tid >> 7;
    float w[18];
#pragma unroll
    for (int k = 0; k < 6; ++k)
#pragma unroll
        for (int j = 0; j < 3; ++j) w[k * 3 + j] = W[(size_t)k * 384 + j * 128 + c];
    float bv = bias[c];
    float S = 0.f, Q = 0.f;
    for (int i = 0; i < 64; ++i) {
        int r = h * 64 + i;
        float acc = bv;
#pragma unroll
        for (int t = 0; t < 18; ++t) acc += Ts[r][t] * w[t];
        O[(size_t)(rbase + r) * 128 + c] = f2b(acc);
        S += acc; Q += acc * acc;
    }
    sh[h][c] = S; sh2[h][c] = Q;
    __syncthreads();
    if (tid < 128) {
        partials[blockIdx.x * 256 + tid]       = sh[0][tid] + sh[1][tid];
        partials[blockIdx.x * 256 + 128 + tid] = sh2[0][tid] + sh2[1][tid];
    }
}

// layer-6 GEMM + bias + relu
__global__ __launch_bounds__(256)
void out10_cat(float* __restrict__ O10, const u16* __restrict__ cat,
               const u16* __restrict__ W6t, const float* __restrict__ bias)
{
    int col = threadIdx.x & 15;
    int row = blockIdx.x * 16 + (threadIdx.x >> 4);
    const u16* a = cat + (size_t)row * 768;
    const u16* w = W6t + (size_t)col * 768;
    float acc = 0.f;
#pragma unroll 4
    for (int k0 = 0; k0 < 768; k0 += 8) {
        s8v av = *(const s8v*)(a + k0);
        s8v wv = *(const s8v*)(w + k0);
#pragma unroll
        for (int j = 0; j < 8; ++j)
            acc += b2f((u16)av[j]) * b2f((u16)wv[j]);
    }
    if (col < 10)
        O10[(size_t)row * 10 + col] = fmaxf(acc + bias[col], 0.f);
}

// ---------------------------------------------------------------------------
// BN finalize: reduce per-block partials -> mean, invstd
// ---------------------------------------------------------------------------
__global__ __launch_bounds__(256)
void bn_finalize(const float* __restrict__ partials, int nblk, int N,
                 float* __restrict__ meanb, float* __restrict__ invstd)
{
    __shared__ float sh[2][128], sh2[2][128];
    int tid = threadIdx.x;
    int c = tid & 127, h = tid >> 7;
    float S = 0.f, Q = 0.f;
    for (int b = h; b < nblk; b += 2) {
        S += partials[b * 256 + c];
        Q += partials[b * 256 + 128 + c];
    }
    sh[h][c] = S; sh2[h][c] = Q;
    __syncthreads();
    if (tid < 128) {
        float Sa = sh[0][tid] + sh[1][tid];
        float Qa = sh2[0][tid] + sh2[1][tid];
        float inv_n = 1.f / (float)N;
        float mu = Sa * inv_n;
        float var = Qa * inv_n - mu * mu;
        meanb[tid] = mu;
        invstd[tid] = rsqrtf(var + 1e-5f);
    }
}

// BN + relu + store bf16 into cat slot (8 channels/thread)
__global__ __launch_bounds__(256)
void bn_apply_cat8(const u16* __restrict__ O, u16* __restrict__ cat, int slot,
                   const float* __restrict__ meanb, const float* __restrict__ invstd,
                   const float* __restrict__ g, const float* __restrict__ bt)
{
    int idx = blockIdx.x * 256 + threadIdx.x;    // over N*16
    int c8 = idx & 15;
    size_t row = idx >> 4;
    s8v v = *(const s8v*)(O + row * 128 + c8 * 8);
    s8v ov;
#pragma unroll
    for (int j = 0; j < 8; ++j) {
        int c = c8 * 8 + j;
        float val = (b2f((u16)v[j]) - meanb[c]) * invstd[c] * g[c] + bt[c];
        ov[j] = (short)f2b(fmaxf(val, 0.f));
    }
    *(s8v*)(cat + row * 768 + slot * 128 + c8 * 8) = ov;
}

// BN + relu + 2x2 max-pool fused (8 channels/thread)
__global__ __launch_bounds__(256)
void bn_apply_pool8(const u16* __restrict__ O, u16* __restrict__ cat, int outSlot,
                    int s, int Nout,
                    const float* __restrict__ meanb, const float* __restrict__ invstd,
                    const float* __restrict__ g, const float* __restrict__ bt)
{
    int idx = blockIdx.x * 256 + threadIdx.x;    // over Nout*16
    if (idx >= Nout * 16) return;
    int c8 = idx & 15;
    int n2 = idx >> 4;
    int h  = s >> 1;
    int x2 = n2 % h;
    int y2 = (n2 / h) % h;
    int gg = n2 / (h * h);
    int base = (gg * s + 2 * y2) * s + 2 * x2;
    s8v v0 = *(const s8v*)(O + (size_t)base * 128 + c8 * 8);
    s8v v1 = *(const s8v*)(O + (size_t)(base + 1) * 128 + c8 * 8);
    s8v v2 = *(const s8v*)(O + (size_t)(base + s) * 128 + c8 * 8);
    s8v v3 = *(const s8v*)(O + (size_t)(base + s + 1) * 128 + c8 * 8);
    s8v ov;
#pragma unroll
    for (int j = 0; j < 8; ++j) {
        int c = c8 * 8 + j;
        float sc = invstd[c] * g[c];
        float so = bt[c] - meanb[c] * sc;
        float m =          b2f((u16)v0[j]) * sc + so;
        m = fmaxf(m, b2f((u16)v1[j]) * sc + so);
        m = fmaxf(m, b2f((u16)v2[j]) * sc + so);
        m = fmaxf(m, b2f((u16)v3[j]) * sc + so);
        ov[j] = (short)f2b(fmaxf(m, 0.f));
    }
    *(s8v*)(cat + (size_t)n2 * 768 + outSlot * 128 + c8 * 8) = ov;
}

// fp32 spatial pool (for layer-6 D=10 output)
__global__ __launch_bounds__(256)
void pool_spatial(float* __restrict__ out, const float* __restrict__ in,
                  int s, int D, int Nout)
{
    int idx = blockIdx.x * 256 + threadIdx.x;
    if (idx >= Nout * D) return;
    int c  = idx % D;
    int n2 = idx / D;
    int h  = s >> 1;
    int x2 = n2 % h;
    int y2 = (n2 / h) % h;
    int g  = n2 / (h * h);
    int base = (g * s + 2 * y2) * s + 2 * x2;
    float m = in[(size_t)base * D + c];
    m = fmaxf(m, in[(size_t)(base + 1) * D + c]);
    m = fmaxf(m, in[(size_t)(base + s) * D + c]);
    m = fmaxf(m, in[(size_t)(base + s + 1) * D + c]);
    out[(size_t)n2 * D + c] = m;
}

__global__ __launch_bounds__(256)
void pool_orient(float* __restrict__ out, const float* __restrict__ in)
{
    int idx = blockIdx.x * 256 + threadIdx.x;
    if (idx >= 512 * 10) return;
    int c = idx % 10;
    int n = idx / 10;
    int x = n % 8, y = (n / 8) % 8, b = n / 64;
    float m = -INFINITY;
    for (int o = 0; o < L_OR; ++o)
        m = fmaxf(m, in[(size_t)((((b * L_OR + o) * 8 + y) * 8 + x)) * 10 + c]);
    out[idx] = m;
}

__global__ __launch_bounds__(128)
void global_pool_logsoftmax(const float* __restrict__ in, float* __restrict__ out)
{
    __shared__ float G[8][10];
    __shared__ float rowm[8], rowl[8];
    int t = threadIdx.x;
    if (t < 80) {
        int b = t / 10, c = t % 10;
        float m = -INFINITY;
        for (int p = 0; p < 64; ++p)
            m = fmaxf(m, in[(size_t)(b * 64 + p) * 10 + c]);
        G[b][c] = m;
    }
    __syncthreads();
    if (t < 8) {
        float m = -INFINITY;
        for (int c = 0; c < 10; ++c) m = fmaxf(m, G[t][c]);
        float s = 0.f;
        for (int c = 0; c < 10; ++c) s += expf(G[t][c] - m);
        rowm[t] = m; rowl[t] = logf(s);
    }
    __syncthreads();
    if (t < 80) {
        int b = t / 10, c = t % 10;
        out[t] = G[b][c] - rowm[b] - rowl[b];
    }
}

// ---------------------------------------------------------------------------
// Host-side orchestration
// ---------------------------------------------------------------------------
static void launch_lapb(u16* cat, int os, int is, int ts, const float* ea,
                        int S, int N, float alpha, hipStream_t st)
{
    dim3 grid(N / 16), block(256);
    if (S == 64)      hipLaunchKernelGGL(lap128b<64>, grid, block, 0, st, cat, os, is, ts, ea, alpha);
    else if (S == 32) hipLaunchKernelGGL(lap128b<32>, grid, block, 0, st, cat, os, is, ts, ea, alpha);
    else              hipLaunchKernelGGL(lap128b<16>, grid, block, 0, st, cat, os, is, ts, ea, alpha);
}

static void cheb_laps(u16* cat, int base, const float* ea, int S, int N, hipStream_t st)
{
    for (int k = 1; k < 6; ++k) {
        int os = (k + base) % 6;
        int is = (k - 1 + base) % 6;
        int ts = (k >= 2) ? (k - 2 + base) % 6 : -1;
        launch_lapb(cat, os, is, ts, ea, S, N, (k == 1) ? 1.f : 2.f, st);
    }
}

extern "C" void kernel_launch(void* const* d_in, const int* in_sizes, int n_in,
                              void* d_out, int out_size, void* d_ws, size_t ws_size,
                              hipStream_t stream)
{
    const float* x   = (const float*)d_in[0];
    const float* ea1 = (const float*)d_in[2];
    const float* ea2 = (const float*)d_in[4];
    const float* ea3 = (const float*)d_in[6];
    const float* W1  = (const float*)d_in[12];
    const float* b1  = (const float*)d_in[13];
    const float* W2  = (const float*)d_in[14];
    const float* b2  = (const float*)d_in[15];
    const float* W3  = (const float*)d_in[16];
    const float* b3  = (const float*)d_in[17];
    const float* W4  = (const float*)d_in[18];
    const float* b4  = (const float*)d_in[19];
    const float* W5  = (const float*)d_in[20];
    const float* b5  = (const float*)d_in[21];
    const float* W6  = (const float*)d_in[22];
    const float* b6  = (const float*)d_in[23];
    const float* g1  = (const float*)d_in[24];
    const float* be1 = (const float*)d_in[25];
    const float* g2  = (const float*)d_in[26];
    const float* be2 = (const float*)d_in[27];
    const float* g3  = (const float*)d_in[28];
    const float* be3 = (const float*)d_in[29];
    const float* g4  = (const float*)d_in[30];
    const float* be4 = (const float*)d_in[31];
    const float* g5  = (const float*)d_in[32];
    const float* be5 = (const float*)d_in[33];

    u16 *cat, *O, *Bt, *W6t;
    float *Tt, *O10, *p3, *p4, *part, *meanb, *invstd;
    if (hipGetSymbolAddress((void**)&cat, HIP_SYMBOL(g_cat)) != hipSuccess) return;
    if (hipGetSymbolAddress((void**)&O,   HIP_SYMBOL(g_O))   != hipSuccess) return;
    if (hipGetSymbolAddress((void**)&Tt,  HIP_SYMBOL(g_Tt))  != hipSuccess) return;
    if (hipGetSymbolAddress((void**)&Bt,  HIP_SYMBOL(g_Bt))  != hipSuccess) return;
    if (hipGetSymbolAddress((void**)&W6t, HIP_SYMBOL(g_W6t)) != hipSuccess) return;
    if (hipGetSymbolAddress((void**)&O10, HIP_SYMBOL(g_O10)) != hipSuccess) return;
    if (hipGetSymbolAddress((void**)&p3,  HIP_SYMBOL(g_p3))  != hipSuccess) return;
    if (hipGetSymbolAddress((void**)&p4,  HIP_SYMBOL(g_p4))  != hipSuccess) return;
    if (hipGetSymbolAddress((void**)&part,   HIP_SYMBOL(g_part)) != hipSuccess) return;
    if (hipGetSymbolAddress((void**)&meanb,  HIP_SYMBOL(g_mean)) != hipSuccess) return;
    if (hipGetSymbolAddress((void**)&invstd, HIP_SYMBOL(g_inv))  != hipSuccess) return;

    dim3 blk(256);

    // ---------- Layer 1: cheb(x[N1,3], W1) -> O bf16 (+stats); BN -> cat slot0 ----------
    {
        float* t1 = Tt;
        float* t2 = Tt + (size_t)N1 * 3;
        float* t3 = Tt + (size_t)2 * N1 * 3;
        float* t4 = Tt + (size_t)3 * N1 * 3;
        float* t5 = Tt + (size_t)4 * N1 * 3;
        dim3 gl((N1 + 255) / 256);
        hipLaunchKernelGGL(lap3_kernel<64>, gl, blk, 0, stream, t1, x,  (const float*)nullptr, ea1, 1.f);
        hipLaunchKernelGGL(lap3_kernel<64>, gl, blk, 0, stream, t2, t1, x,  ea1, 2.f);
        hipLaunchKernelGGL(lap3_kernel<64>, gl, blk, 0, stream, t3, t2, t1, ea1, 2.f);
        hipLaunchKernelGGL(lap3_kernel<64>, gl, blk, 0, stream, t4, t3, t2, ea1, 2.f);
        hipLaunchKernelGGL(lap3_kernel<64>, gl, blk, 0, stream, t5, t4, t3, ea1, 2.f);
        hipLaunchKernelGGL(l1gemm, dim3(N1 / 128), blk, 0, stream, O, x, Tt, W1, b1, part);
    }
    hipLaunchKernelGGL(bn_finalize, dim3(1), blk, 0, stream, part, N1 / 128, N1, meanb, invstd);
    hipLaunchKernelGGL(bn_apply_cat8, dim3(N1 / 16), blk, 0, stream,
                       O, cat, 0, meanb, invstd, g1, be1);

    // ---------- Layer 2 (N1, base 0) ----------
    hipLaunchKernelGGL(wprep, dim3(384), blk, 0, stream, W2, Bt, 0);
    cheb_laps(cat, 0, ea1, 64, N1, stream);
    hipLaunchKernelGGL(gemm_mfma_cat, dim3(N1 / 128), blk, 0, stream, O, cat, Bt, b2, part);
    hipLaunchKernelGGL(bn_finalize, dim3(1), blk, 0, stream, part, N1 / 128, N1, meanb, invstd);
    hipLaunchKernelGGL(bn_apply_pool8, dim3(N2 / 16), blk, 0, stream,
                       O, cat, 5, 64, N2, meanb, invstd, g2, be2);

    // ---------- Layer 3 (N2, base 5) ----------
    hipLaunchKernelGGL(wprep, dim3(384), blk, 0, stream, W3, Bt, 5);
    cheb_laps(cat, 5, ea2, 32, N2, stream);
    hipLaunchKernelGGL(gemm_mfma_cat, dim3(N2 / 128), blk, 0, stream, O, cat, Bt, b3, part);
    hipLaunchKernelGGL(bn_finalize, dim3(1), blk, 0, stream, part, N2 / 128, N2, meanb, invstd);
    hipLaunchKernelGGL(bn_apply_cat8, dim3(N2 / 16), blk, 0, stream,
                       O, cat, 0, meanb, invstd, g3, be3);

    // ---------- Layer 4 (N2, base 0) ----------
    hipLaunchKernelGGL(wprep, dim3(384), blk, 0, stream, W4, Bt, 0);
    cheb_laps(cat, 0, ea2, 32, N2, stream);
    hipLaunchKernelGGL(gemm_mfma_cat, dim3(N2 / 128), blk, 0, stream, O, cat, Bt, b4, part);
    hipLaunchKernelGGL(bn_finalize, dim3(1), blk, 0, stream, part, N2 / 128, N2, meanb, invstd);
    hipLaunchKernelGGL(bn_apply_pool8, dim3(N3 / 16), blk, 0, stream,
                       O, cat, 5, 32, N3, meanb, invstd, g4, be4);

    // ---------- Layer 5 (N3, base 5) ----------
    hipLaunchKernelGGL(wprep, dim3(384), blk, 0, stream, W5, Bt, 5);
    cheb_laps(cat, 5, ea3, 16, N3, stream);
    hipLaunchKernelGGL(gemm_mfma_cat, dim3(N3 / 128), blk, 0, stream, O, cat, Bt, b5, part);
    hipLaunchKernelGGL(bn_finalize, dim3(1), blk, 0, stream, part, N3 / 128, N3, meanb, invstd);
    hipLaunchKernelGGL(bn_apply_cat8, dim3(N3 / 16), blk, 0, stream,
                       O, cat, 0, meanb, invstd, g5, be5);

    // ---------- Layer 6 (N3, base 0, out 10, relu fused) ----------
    hipLaunchKernelGGL(w6prep, dim3(48), blk, 0, stream, W6, W6t, 0);
    cheb_laps(cat, 0, ea3, 16, N3, stream);
    hipLaunchKernelGGL(out10_cat, dim3(N3 / 16), blk, 0, stream, O10, cat, W6t, b6);

    // pool3: 16 -> 8 (D=10)
    hipLaunchKernelGGL(pool_spatial, dim3((3072 * 10 + 255) / 256), blk, 0, stream,
                       p3, O10, 16, 10, 3072);
    hipLaunchKernelGGL(pool_orient, dim3((512 * 10 + 255) / 256), blk, 0, stream, p4, p3);
    hipLaunchKernelGGL(global_pool_logsoftmax, dim3(1), dim3(128), 0, stream,
                       p4, (float*)d_out);
}

// Round 6
// 871.014 us; speedup vs baseline: 2.7736x; 1.6258x over previous
//
#include <hip/hip_runtime.h>
#include <math.h>

#define L_OR 6
#define N_BL 48   // B*L = 8*6

typedef unsigned short u16;
typedef __attribute__((ext_vector_type(8))) short s8v;   // 8 x bf16 (16B)
typedef __attribute__((ext_vector_type(4))) float f4v;

#define N1 196608
#define N2 49152
#define N3 12288

// ---- static device workspace (BSS, allocated at module load) ----
__device__ u16   g_cat[(size_t)N1 * 768 + 1024];  // 302 MB: 6 T-slots bf16 (+prefetch pad)
__device__ u16   g_O[(size_t)N1 * 128];           // 50 MB: GEMM output bf16
__device__ float g_Tt[5 * (size_t)N1 * 3];        // layer-1 T1..T5 fp32
__device__ u16   g_Bt[128 * 768 + 4096];          // fragment-ordered bf16 weights (+pad)
__device__ u16   g_W6t[16 * 768];                 // layer-6 weights (padded cols)
__device__ float g_O10[(size_t)N3 * 10];
__device__ float g_p3[3072 * 10];
__device__ float g_p4[512 * 10];
__device__ float g_part[1536 * 256];              // per-block BN partials
__device__ float g_part2[64 * 256];               // stage-2 BN partials
__device__ float g_mean[128];
__device__ float g_inv[128];

__device__ __forceinline__ float b2f(u16 v) {
    return __uint_as_float(((unsigned)v) << 16);
}
__device__ __forceinline__ u16 f2b(float f) {
    unsigned u = __float_as_uint(f);
    return (u16)((u + 0x7FFFu + ((u >> 16) & 1u)) >> 16);   // RNE
}

// ---------------------------------------------------------------------------
// bf16 Laplacian on cat buffer: cat[:,outSlot] = alpha*L(cat[:,inSlot]) - cat[:,tppSlot]
// 16 lanes per node, 8 channels (16B) per lane.
// ---------------------------------------------------------------------------
template<int S>
__global__ __launch_bounds__(256)
void lap128b(u16* __restrict__ cat, int outSlot, int inSlot, int tppSlot,
             const float* __restrict__ ea, float alpha)
{
    int node = blockIdx.x * 16 + (threadIdx.x >> 4);
    int c8   = threadIdx.x & 15;          // 8 channels per lane

    const int x = node % S;
    const int y = (node / S) % S;
    const int g = node / (S * S);
    const int o = g % L_OR;
    const int b = g / L_OR;
    const int szx = N_BL * S * (S - 1);

    float a[8] = {0.f, 0.f, 0.f, 0.f, 0.f, 0.f, 0.f, 0.f};
    const int chOff = inSlot * 128 + c8 * 8;

    auto gather = [&](int src, float w) {
        s8v v = *(const s8v*)(cat + (size_t)src * 768 + chOff);
#pragma unroll
        for (int j = 0; j < 8; ++j) a[j] += w * b2f((u16)v[j]);
    };

    const int basex = (g * S + y) * (S - 1);
    if (x > 0)     gather(node - 1, ea[basex + x - 1]);
    if (x < S - 1) gather(node + 1, ea[szx + basex + x]);
    if (y > 0)     gather(node - S, ea[2 * szx + (g * (S - 1) + y - 1) * S + x]);
    if (y < S - 1) gather(node + S, ea[3 * szx + (g * (S - 1) + y) * S + x]);
    {   int op = (o == 0) ? L_OR - 1 : o - 1;
        int sp = ((b * L_OR + op) * S + y) * S + x;
        gather(sp, ea[4 * szx + sp]);
    }
    {   int on = (o == L_OR - 1) ? 0 : o + 1;
        int sn = ((b * L_OR + on) * S + y) * S + x;
        gather(sn, ea[4 * szx + N_BL * S * S + node]);
    }

    float r[8];
#pragma unroll
    for (int j = 0; j < 8; ++j) r[j] = alpha * a[j];
    if (tppSlot >= 0) {
        s8v t = *(const s8v*)(cat + (size_t)node * 768 + tppSlot * 128 + c8 * 8);
#pragma unroll
        for (int j = 0; j < 8; ++j) r[j] -= b2f((u16)t[j]);
    }
    s8v ov;
#pragma unroll
    for (int j = 0; j < 8; ++j) ov[j] = (short)f2b(r[j]);
    *(s8v*)(cat + (size_t)node * 768 + outSlot * 128 + c8 * 8) = ov;
}

// fp32 laplacian for layer 1 (D=3)
template<int S>
__global__ __launch_bounds__(256)
void lap3_kernel(float* __restrict__ out, const float* __restrict__ in,
                 const float* __restrict__ tpp, const float* __restrict__ ea,
                 float alpha)
{
    const int NN = N_BL * S * S;
    int n = blockIdx.x * 256 + threadIdx.x;
    if (n >= NN) return;
    const int x = n % S, y = (n / S) % S, g = n / (S * S);
    const int o = g % L_OR, b = g / L_OR;
    const int szx = N_BL * S * (S - 1);

    float a0 = 0.f, a1 = 0.f, a2 = 0.f;
    auto gather = [&](int src, float w) {
        a0 += w * in[src * 3 + 0];
        a1 += w * in[src * 3 + 1];
        a2 += w * in[src * 3 + 2];
    };
    const int basex = (g * S + y) * (S - 1);
    if (x > 0)     gather(n - 1, ea[basex + x - 1]);
    if (x < S - 1) gather(n + 1, ea[szx + basex + x]);
    if (y > 0)     gather(n - S, ea[2 * szx + (g * (S - 1) + y - 1) * S + x]);
    if (y < S - 1) gather(n + S, ea[3 * szx + (g * (S - 1) + y) * S + x]);
    { int op = (o == 0) ? L_OR - 1 : o - 1; int sp = ((b * L_OR + op) * S + y) * S + x;
      gather(sp, ea[4 * szx + sp]); }
    { int on = (o == L_OR - 1) ? 0 : o + 1; int sn = ((b * L_OR + on) * S + y) * S + x;
      gather(sn, ea[4 * szx + N_BL * S * S + n]); }

    float r0 = alpha * a0, r1 = alpha * a1, r2 = alpha * a2;
    if (tpp) { r0 -= tpp[n * 3 + 0]; r1 -= tpp[n * 3 + 1]; r2 -= tpp[n * 3 + 2]; }
    out[n * 3 + 0] = r0; out[n * 3 + 1] = r1; out[n * 3 + 2] = r2;
}

// ---------------------------------------------------------------------------
// MFMA GEMM + fused BN-stats: O[N,128](bf16) = cat[N,768](bf16) @ W + bias,
// and partials[blk][256] = per-block channel {sum, sumsq} of the fp32 output.
// ---------------------------------------------------------------------------
__global__ __launch_bounds__(256)
void gemm_mfma_cat(u16* __restrict__ O, const u16* __restrict__ A,
                   const u16* __restrict__ Bf, const float* __restrict__ bias,
                   float* __restrict__ partials)
{
    const int wave = threadIdx.x >> 6;
    const int lane = threadIdx.x & 63;
    const int lrow = lane & 15;
    const int kg   = lane >> 4;
    const int r0   = blockIdx.x * 128 + wave * 32;

    const u16* A0 = A + (size_t)(r0 + lrow) * 768 + kg * 8;
    const u16* A1 = A0 + (size_t)16 * 768;
    const u16* Bp = Bf + lane * 8;

    f4v acc[2][8] = {};
    s8v a0e, a1e, a0o, a1o, be[8], bo[8];

    a0e = *(const s8v*)(A0);
    a1e = *(const s8v*)(A1);
#pragma unroll
    for (int ct = 0; ct < 8; ++ct) be[ct] = *(const s8v*)(Bp + ct * 512);

#pragma unroll 1
    for (int k0s = 0; k0s < 24; k0s += 2) {
        a0o = *(const s8v*)(A0 + (k0s + 1) * 32);
        a1o = *(const s8v*)(A1 + (k0s + 1) * 32);
#pragma unroll
        for (int ct = 0; ct < 8; ++ct)
            bo[ct] = *(const s8v*)(Bp + ((k0s + 1) * 8 + ct) * 512);
#pragma unroll
        for (int ct = 0; ct < 8; ++ct) {
            acc[0][ct] = __builtin_amdgcn_mfma_f32_16x16x32_bf16(a0e, be[ct], acc[0][ct], 0, 0, 0);
            acc[1][ct] = __builtin_amdgcn_mfma_f32_16x16x32_bf16(a1e, be[ct], acc[1][ct], 0, 0, 0);
        }
        a0e = *(const s8v*)(A0 + (k0s + 2) * 32);
        a1e = *(const s8v*)(A1 + (k0s + 2) * 32);
#pragma unroll
        for (int ct = 0; ct < 8; ++ct)
            be[ct] = *(const s8v*)(Bp + ((k0s + 2) * 8 + ct) * 512);
#pragma unroll
        for (int ct = 0; ct < 8; ++ct) {
            acc[0][ct] = __builtin_amdgcn_mfma_f32_16x16x32_bf16(a0o, bo[ct], acc[0][ct], 0, 0, 0);
            acc[1][ct] = __builtin_amdgcn_mfma_f32_16x16x32_bf16(a1o, bo[ct], acc[1][ct], 0, 0, 0);
        }
    }

    __shared__ float sred[4][2][8][16];
    float cs[8], cq[8];
#pragma unroll
    for (int ct = 0; ct < 8; ++ct) { cs[ct] = 0.f; cq[ct] = 0.f; }

#pragma unroll
    for (int s = 0; s < 2; ++s)
#pragma unroll
        for (int ct = 0; ct < 8; ++ct) {
            int col = ct * 16 + lrow;
            float bv = bias[col];
#pragma unroll
            for (int j = 0; j < 4; ++j) {
                int row = r0 + s * 16 + kg * 4 + j;
                float v = acc[s][ct][j] + bv;
                O[(size_t)row * 128 + col] = f2b(v);
                cs[ct] += v; cq[ct] += v * v;
            }
        }
#pragma unroll
    for (int ct = 0; ct < 8; ++ct) {
        cs[ct] += __shfl_xor(cs[ct], 16); cs[ct] += __shfl_xor(cs[ct], 32);
        cq[ct] += __shfl_xor(cq[ct], 16); cq[ct] += __shfl_xor(cq[ct], 32);
    }
    if (lane < 16) {
#pragma unroll
        for (int ct = 0; ct < 8; ++ct) {
            sred[wave][0][ct][lane] = cs[ct];
            sred[wave][1][ct][lane] = cq[ct];
        }
    }
    __syncthreads();
    if (threadIdx.x < 128) {
        int ct = threadIdx.x >> 4, lr = threadIdx.x & 15;
        float S = 0.f, Q = 0.f;
#pragma unroll
        for (int w = 0; w < 4; ++w) { S += sred[w][0][ct][lr]; Q += sred[w][1][ct][lr]; }
        partials[blockIdx.x * 256 + threadIdx.x]       = S;
        partials[blockIdx.x * 256 + 128 + threadIdx.x] = Q;
    }
}

// weight prep into fragment order (see gemm_mfma_cat)
__global__ __launch_bounds__(256)
void wprep(const float* __restrict__ W, u16* __restrict__ Bf, int base)
{
    int idx = blockIdx.x * 256 + threadIdx.x;     // < 128*768
    int j    = idx & 7;
    int lane = (idx >> 3) & 63;
    int ct   = (idx >> 9) & 7;
    int k0s  = idx >> 12;
    int k    = k0s * 32 + (lane >> 4) * 8 + j;
    int col  = ct * 16 + (lane & 15);
    int slot = k >> 7, d = k & 127;
    int wk = slot - base; if (wk < 0) wk += 6;
    Bf[idx] = f2b(W[(size_t)wk * 16384 + d * 128 + col]);
}

__global__ __launch_bounds__(256)
void w6prep(const float* __restrict__ W, u16* __restrict__ W6t, int base)
{
    int idx = blockIdx.x * 256 + threadIdx.x;     // < 16*768
    if (idx >= 16 * 768) return;
    int c = idx / 768, kk = idx % 768;
    int slot = kk >> 7, d = kk & 127;
    int wk = slot - base; if (wk < 0) wk += 6;
    W6t[idx] = (c < 10) ? f2b(W[(size_t)wk * 1280 + d * 10 + c]) : (u16)0;
}

// layer-1 GEMM + fused stats. Block = 128 rows; T values staged in LDS.
__global__ __launch_bounds__(256)
void l1gemm(u16* __restrict__ O, const float* __restrict__ T0,
            const float* __restrict__ Tt, const float* __restrict__ W,
            const float* __restrict__ bias, float* __restrict__ partials)
{
    __shared__ float Ts[128][18];
    __shared__ float sh[2][128], sh2[2][128];
    int tid = threadIdx.x;
    int rbase = blockIdx.x * 128;
    for (int i = tid; i < 128 * 18; i += 256) {
        int r = i / 18, t = i % 18;
        int k = t / 3, j = t % 3;
        Ts[r][t] = (k == 0) ? T0[(size_t)(rbase + r) * 3 + j]
                            : Tt[(size_t)(k - 1) * N1 * 3 + (size_t)(rbase + r) * 3 + j];
    }
    __syncthreads();
    int c = tid & 127, h = tid >> 7;
    float w[18];
#pragma unroll
    for (int k = 0; k < 6; ++k)
#pragma unroll
        for (int j = 0; j < 3; ++j) w[k * 3 + j] = W[(size_t)k * 384 + j * 128 + c];
    float bv = bias[c];
    float S = 0.f, Q = 0.f;
    for (int i = 0; i < 64; ++i) {
        int r = h * 64 + i;
        float acc = bv;
#pragma unroll
        for (int t = 0; t < 18; ++t) acc += Ts[r][t] * w[t];
        O[(size_t)(rbase + r) * 128 + c] = f2b(acc);
        S += acc; Q += acc * acc;
    }
    sh[h][c] = S; sh2[h][c] = Q;
    __syncthreads();
    if (tid < 128) {
        partials[blockIdx.x * 256 + tid]       = sh[0][tid] + sh[1][tid];
        partials[blockIdx.x * 256 + 128 + tid] = sh2[0][tid] + sh2[1][tid];
    }
}

// layer-6 GEMM + bias + relu
__global__ __launch_bounds__(256)
void out10_cat(float* __restrict__ O10, const u16* __restrict__ cat,
               const u16* __restrict__ W6t, const float* __restrict__ bias)
{
    int col = threadIdx.x & 15;
    int row = blockIdx.x * 16 + (threadIdx.x >> 4);
    const u16* a = cat + (size_t)row * 768;
    const u16* w = W6t + (size_t)col * 768;
    float acc = 0.f;
#pragma unroll 4
    for (int k0 = 0; k0 < 768; k0 += 8) {
        s8v av = *(const s8v*)(a + k0);
        s8v wv = *(const s8v*)(w + k0);
#pragma unroll
        for (int j = 0; j < 8; ++j)
            acc += b2f((u16)av[j]) * b2f((u16)wv[j]);
    }
    if (col < 10)
        O10[(size_t)row * 10 + col] = fmaxf(acc + bias[col], 0.f);
}

// ---------------------------------------------------------------------------
// BN reduce stage 1: 64 blocks; block i sums records {i, i+64, ...}
// ---------------------------------------------------------------------------
__global__ __launch_bounds__(256)
void bn_reduce1(const float* __restrict__ partials, int nblk,
                float* __restrict__ part2)
{
    int tid = threadIdx.x;
    float S = 0.f;
#pragma unroll 4
    for (int b = blockIdx.x; b < nblk; b += 64)
        S += partials[(size_t)b * 256 + tid];
    part2[blockIdx.x * 256 + tid] = S;
}

// BN reduce stage 2: 1 block over fixed 64 records -> mean, invstd
__global__ __launch_bounds__(256)
void bn_finalize2(const float* __restrict__ part2, int N,
                  float* __restrict__ meanb, float* __restrict__ invstd)
{
    __shared__ float red[256];
    int tid = threadIdx.x;
    int c = tid & 127, h = tid >> 7;      // h: 0 -> sum, 1 -> sumsq... no: split records
    // thread (c,h) sums records h, h+2, ..., for both sum (offset c) and sumsq (offset 128+c)
    float S = 0.f, Q = 0.f;
#pragma unroll 8
    for (int b = h; b < 64; b += 2) {
        S += part2[b * 256 + c];
        Q += part2[b * 256 + 128 + c];
    }
    __shared__ float shS[2][128], shQ[2][128];
    shS[h][c] = S; shQ[h][c] = Q;
    (void)red;
    __syncthreads();
    if (tid < 128) {
        float Sa = shS[0][tid] + shS[1][tid];
        float Qa = shQ[0][tid] + shQ[1][tid];
        float inv_n = 1.f / (float)N;
        float mu = Sa * inv_n;
        float var = Qa * inv_n - mu * mu;
        meanb[tid] = mu;
        invstd[tid] = rsqrtf(var + 1e-5f);
    }
}

// BN + relu + store bf16 into cat slot (8 channels/thread)
__global__ __launch_bounds__(256)
void bn_apply_cat8(const u16* __restrict__ O, u16* __restrict__ cat, int slot,
                   const float* __restrict__ meanb, const float* __restrict__ invstd,
                   const float* __restrict__ g, const float* __restrict__ bt)
{
    int idx = blockIdx.x * 256 + threadIdx.x;    // over N*16
    int c8 = idx & 15;
    size_t row = idx >> 4;
    s8v v = *(const s8v*)(O + row * 128 + c8 * 8);
    s8v ov;
#pragma unroll
    for (int j = 0; j < 8; ++j) {
        int c = c8 * 8 + j;
        float val = (b2f((u16)v[j]) - meanb[c]) * invstd[c] * g[c] + bt[c];
        ov[j] = (short)f2b(fmaxf(val, 0.f));
    }
    *(s8v*)(cat + row * 768 + slot * 128 + c8 * 8) = ov;
}

// BN + relu + 2x2 max-pool fused (8 channels/thread)
__global__ __launch_bounds__(256)
void bn_apply_pool8(const u16* __restrict__ O, u16* __restrict__ cat, int outSlot,
                    int s, int Nout,
                    const float* __restrict__ meanb, const float* __restrict__ invstd,
                    const float* __restrict__ g, const float* __restrict__ bt)
{
    int idx = blockIdx.x * 256 + threadIdx.x;    // over Nout*16
    if (idx >= Nout * 16) return;
    int c8 = idx & 15;
    int n2 = idx >> 4;
    int h  = s >> 1;
    int x2 = n2 % h;
    int y2 = (n2 / h) % h;
    int gg = n2 / (h * h);
    int base = (gg * s + 2 * y2) * s + 2 * x2;
    s8v v0 = *(const s8v*)(O + (size_t)base * 128 + c8 * 8);
    s8v v1 = *(const s8v*)(O + (size_t)(base + 1) * 128 + c8 * 8);
    s8v v2 = *(const s8v*)(O + (size_t)(base + s) * 128 + c8 * 8);
    s8v v3 = *(const s8v*)(O + (size_t)(base + s + 1) * 128 + c8 * 8);
    s8v ov;
#pragma unroll
    for (int j = 0; j < 8; ++j) {
        int c = c8 * 8 + j;
        float sc = invstd[c] * g[c];
        float so = bt[c] - meanb[c] * sc;
        float m =          b2f((u16)v0[j]) * sc + so;
        m = fmaxf(m, b2f((u16)v1[j]) * sc + so);
        m = fmaxf(m, b2f((u16)v2[j]) * sc + so);
        m = fmaxf(m, b2f((u16)v3[j]) * sc + so);
        ov[j] = (short)f2b(fmaxf(m, 0.f));
    }
    *(s8v*)(cat + (size_t)n2 * 768 + outSlot * 128 + c8 * 8) = ov;
}

// fp32 spatial pool (for layer-6 D=10 output)
__global__ __launch_bounds__(256)
void pool_spatial(float* __restrict__ out, const float* __restrict__ in,
                  int s, int D, int Nout)
{
    int idx = blockIdx.x * 256 + threadIdx.x;
    if (idx >= Nout * D) return;
    int c  = idx % D;
    int n2 = idx / D;
    int h  = s >> 1;
    int x2 = n2 % h;
    int y2 = (n2 / h) % h;
    int g  = n2 / (h * h);
    int base = (g * s + 2 * y2) * s + 2 * x2;
    float m = in[(size_t)base * D + c];
    m = fmaxf(m, in[(size_t)(base + 1) * D + c]);
    m = fmaxf(m, in[(size_t)(base + s) * D + c]);
    m = fmaxf(m, in[(size_t)(base + s + 1) * D + c]);
    out[(size_t)n2 * D + c] = m;
}

__global__ __launch_bounds__(256)
void pool_orient(float* __restrict__ out, const float* __restrict__ in)
{
    int idx = blockIdx.x * 256 + threadIdx.x;
    if (idx >= 512 * 10) return;
    int c = idx % 10;
    int n = idx / 10;
    int x = n % 8, y = (n / 8) % 8, b = n / 64;
    float m = -INFINITY;
    for (int o = 0; o < L_OR; ++o)
        m = fmaxf(m, in[(size_t)((((b * L_OR + o) * 8 + y) * 8 + x)) * 10 + c]);
    out[idx] = m;
}

__global__ __launch_bounds__(128)
void global_pool_logsoftmax(const float* __restrict__ in, float* __restrict__ out)
{
    __shared__ float G[8][10];
    __shared__ float rowm[8], rowl[8];
    int t = threadIdx.x;
    if (t < 80) {
        int b = t / 10, c = t % 10;
        float m = -INFINITY;
        for (int p = 0; p < 64; ++p)
            m = fmaxf(m, in[(size_t)(b * 64 + p) * 10 + c]);
        G[b][c] = m;
    }
    __syncthreads();
    if (t < 8) {
        float m = -INFINITY;
        for (int c = 0; c < 10; ++c) m = fmaxf(m, G[t][c]);
        float s = 0.f;
        for (int c = 0; c < 10; ++c) s += expf(G[t][c] - m);
        rowm[t] = m; rowl[t] = logf(s);
    }
    __syncthreads();
    if (t < 80) {
        int b = t / 10, c = t % 10;
        out[t] = G[b][c] - rowm[b] - rowl[b];
    }
}

// ---------------------------------------------------------------------------
// Host-side orchestration
// ---------------------------------------------------------------------------
static void launch_lapb(u16* cat, int os, int is, int ts, const float* ea,
                        int S, int N, float alpha, hipStream_t st)
{
    dim3 grid(N / 16), block(256);
    if (S == 64)      hipLaunchKernelGGL(lap128b<64>, grid, block, 0, st, cat, os, is, ts, ea, alpha);
    else if (S == 32) hipLaunchKernelGGL(lap128b<32>, grid, block, 0, st, cat, os, is, ts, ea, alpha);
    else              hipLaunchKernelGGL(lap128b<16>, grid, block, 0, st, cat, os, is, ts, ea, alpha);
}

static void cheb_laps(u16* cat, int base, const float* ea, int S, int N, hipStream_t st)
{
    for (int k = 1; k < 6; ++k) {
        int os = (k + base) % 6;
        int is = (k - 1 + base) % 6;
        int ts = (k >= 2) ? (k - 2 + base) % 6 : -1;
        launch_lapb(cat, os, is, ts, ea, S, N, (k == 1) ? 1.f : 2.f, st);
    }
}

static void bn_reduce(float* part, float* part2, int nblk, int N,
                      float* meanb, float* invstd, hipStream_t st)
{
    hipLaunchKernelGGL(bn_reduce1, dim3(64), dim3(256), 0, st, part, nblk, part2);
    hipLaunchKernelGGL(bn_finalize2, dim3(1), dim3(256), 0, st, part2, N, meanb, invstd);
}

extern "C" void kernel_launch(void* const* d_in, const int* in_sizes, int n_in,
                              void* d_out, int out_size, void* d_ws, size_t ws_size,
                              hipStream_t stream)
{
    const float* x   = (const float*)d_in[0];
    const float* ea1 = (const float*)d_in[2];
    const float* ea2 = (const float*)d_in[4];
    const float* ea3 = (const float*)d_in[6];
    const float* W1  = (const float*)d_in[12];
    const float* b1  = (const float*)d_in[13];
    const float* W2  = (const float*)d_in[14];
    const float* b2  = (const float*)d_in[15];
    const float* W3  = (const float*)d_in[16];
    const float* b3  = (const float*)d_in[17];
    const float* W4  = (const float*)d_in[18];
    const float* b4  = (const float*)d_in[19];
    const float* W5  = (const float*)d_in[20];
    const float* b5  = (const float*)d_in[21];
    const float* W6  = (const float*)d_in[22];
    const float* b6  = (const float*)d_in[23];
    const float* g1  = (const float*)d_in[24];
    const float* be1 = (const float*)d_in[25];
    const float* g2  = (const float*)d_in[26];
    const float* be2 = (const float*)d_in[27];
    const float* g3  = (const float*)d_in[28];
    const float* be3 = (const float*)d_in[29];
    const float* g4  = (const float*)d_in[30];
    const float* be4 = (const float*)d_in[31];
    const float* g5  = (const float*)d_in[32];
    const float* be5 = (const float*)d_in[33];

    u16 *cat, *O, *Bt, *W6t;
    float *Tt, *O10, *p3, *p4, *part, *part2, *meanb, *invstd;
    if (hipGetSymbolAddress((void**)&cat, HIP_SYMBOL(g_cat)) != hipSuccess) return;
    if (hipGetSymbolAddress((void**)&O,   HIP_SYMBOL(g_O))   != hipSuccess) return;
    if (hipGetSymbolAddress((void**)&Tt,  HIP_SYMBOL(g_Tt))  != hipSuccess) return;
    if (hipGetSymbolAddress((void**)&Bt,  HIP_SYMBOL(g_Bt))  != hipSuccess) return;
    if (hipGetSymbolAddress((void**)&W6t, HIP_SYMBOL(g_W6t)) != hipSuccess) return;
    if (hipGetSymbolAddress((void**)&O10, HIP_SYMBOL(g_O10)) != hipSuccess) return;
    if (hipGetSymbolAddress((void**)&p3,  HIP_SYMBOL(g_p3))  != hipSuccess) return;
    if (hipGetSymbolAddress((void**)&p4,  HIP_SYMBOL(g_p4))  != hipSuccess) return;
    if (hipGetSymbolAddress((void**)&part,   HIP_SYMBOL(g_part))  != hipSuccess) return;
    if (hipGetSymbolAddress((void**)&part2,  HIP_SYMBOL(g_part2)) != hipSuccess) return;
    if (hipGetSymbolAddress((void**)&meanb,  HIP_SYMBOL(g_mean))  != hipSuccess) return;
    if (hipGetSymbolAddress((void**)&invstd, HIP_SYMBOL(g_inv))   != hipSuccess) return;

    dim3 blk(256);

    // ---------- Layer 1: cheb(x[N1,3], W1) -> O bf16 (+stats); BN -> cat slot0 ----------
    {
        float* t1 = Tt;
        float* t2 = Tt + (size_t)N1 * 3;
        float* t3 = Tt + (size_t)2 * N1 * 3;
        float* t4 = Tt + (size_t)3 * N1 * 3;
        float* t5 = Tt + (size_t)4 * N1 * 3;
        dim3 gl((N1 + 255) / 256);
        hipLaunchKernelGGL(lap3_kernel<64>, gl, blk, 0, stream, t1, x,  (const float*)nullptr, ea1, 1.f);
        hipLaunchKernelGGL(lap3_kernel<64>, gl, blk, 0, stream, t2, t1, x,  ea1, 2.f);
        hipLaunchKernelGGL(lap3_kernel<64>, gl, blk, 0, stream, t3, t2, t1, ea1, 2.f);
        hipLaunchKernelGGL(lap3_kernel<64>, gl, blk, 0, stream, t4, t3, t2, ea1, 2.f);
        hipLaunchKernelGGL(lap3_kernel<64>, gl, blk, 0, stream, t5, t4, t3, ea1, 2.f);
        hipLaunchKernelGGL(l1gemm, dim3(N1 / 128), blk, 0, stream, O, x, Tt, W1, b1, part);
    }
    bn_reduce(part, part2, N1 / 128, N1, meanb, invstd, stream);
    hipLaunchKernelGGL(bn_apply_cat8, dim3(N1 / 16), blk, 0, stream,
                       O, cat, 0, meanb, invstd, g1, be1);

    // ---------- Layer 2 (N1, base 0) ----------
    hipLaunchKernelGGL(wprep, dim3(384), blk, 0, stream, W2, Bt, 0);
    cheb_laps(cat, 0, ea1, 64, N1, stream);
    hipLaunchKernelGGL(gemm_mfma_cat, dim3(N1 / 128), blk, 0, stream, O, cat, Bt, b2, part);
    bn_reduce(part, part2, N1 / 128, N1, meanb, invstd, stream);
    hipLaunchKernelGGL(bn_apply_pool8, dim3(N2 / 16), blk, 0, stream,
                       O, cat, 5, 64, N2, meanb, invstd, g2, be2);

    // ---------- Layer 3 (N2, base 5) ----------
    hipLaunchKernelGGL(wprep, dim3(384), blk, 0, stream, W3, Bt, 5);
    cheb_laps(cat, 5, ea2, 32, N2, stream);
    hipLaunchKernelGGL(gemm_mfma_cat, dim3(N2 / 128), blk, 0, stream, O, cat, Bt, b3, part);
    bn_reduce(part, part2, N2 / 128, N2, meanb, invstd, stream);
    hipLaunchKernelGGL(bn_apply_cat8, dim3(N2 / 16), blk, 0, stream,
                       O, cat, 0, meanb, invstd, g3, be3);

    // ---------- Layer 4 (N2, base 0) ----------
    hipLaunchKernelGGL(wprep, dim3(384), blk, 0, stream, W4, Bt, 0);
    cheb_laps(cat, 0, ea2, 32, N2, stream);
    hipLaunchKernelGGL(gemm_mfma_cat, dim3(N2 / 128), blk, 0, stream, O, cat, Bt, b4, part);
    bn_reduce(part, part2, N2 / 128, N2, meanb, invstd, stream);
    hipLaunchKernelGGL(bn_apply_pool8, dim3(N3 / 16), blk, 0, stream,
                       O, cat, 5, 32, N3, meanb, invstd, g4, be4);

    // ---------- Layer 5 (N3, base 5) ----------
    hipLaunchKernelGGL(wprep, dim3(384), blk, 0, stream, W5, Bt, 5);
    cheb_laps(cat, 5, ea3, 16, N3, stream);
    hipLaunchKernelGGL(gemm_mfma_cat, dim3(N3 / 128), blk, 0, stream, O, cat, Bt, b5, part);
    bn_reduce(part, part2, N3 / 128, N3, meanb, invstd, stream);
    hipLaunchKernelGGL(bn_apply_cat8, dim3(N3 / 16), blk, 0, stream,
                       O, cat, 0, meanb, invstd, g5, be5);

    // ---------- Layer 6 (N3, base 0, out 10, relu fused) ----------
    hipLaunchKernelGGL(w6prep, dim3(48), blk, 0, stream, W6, W6t, 0);
    cheb_laps(cat, 0, ea3, 16, N3, stream);
    hipLaunchKernelGGL(out10_cat, dim3(N3 / 16), blk, 0, stream, O10, cat, W6t, b6);

    // pool3: 16 -> 8 (D=10)
    hipLaunchKernelGGL(pool_spatial, dim3((3072 * 10 + 255) / 256), blk, 0, stream,
                       p3, O10, 16, 10, 3072);
    hipLaunchKernelGGL(pool_orient, dim3((512 * 10 + 255) / 256), blk, 0, stream, p4, p3);
    hipLaunchKernelGGL(global_pool_logsoftmax, dim3(1), dim3(128), 0, stream,
                       p4, (float*)d_out);
}

// Round 7
// 836.323 us; speedup vs baseline: 2.8886x; 1.0415x over previous
//
#include <hip/hip_runtime.h>
#include <math.h>

#define L_OR 6
#define N_BL 48   // B*L = 8*6

typedef unsigned short u16;
typedef __attribute__((ext_vector_type(8))) short s8v;   // 8 x bf16 (16B)
typedef __attribute__((ext_vector_type(4))) float f4v;

#define N1 196608
#define N2 49152
#define N3 12288

// ---- static device workspace (BSS, allocated at module load) ----
__device__ u16   g_cat[(size_t)N1 * 768 + 1024];  // 302 MB: 6 T-slots bf16 (+prefetch pad)
__device__ u16   g_O[(size_t)N1 * 128];           // 50 MB: GEMM output bf16
__device__ float g_Tt[5 * (size_t)N1 * 3];        // layer-1 T1..T5 fp32
__device__ u16   g_Bt[128 * 768 + 4096];          // fragment-ordered bf16 weights (+8KB pad)
__device__ u16   g_W6t[16 * 768];                 // layer-6 weights (padded cols)
__device__ float g_O10[(size_t)N3 * 10];
__device__ float g_p3[3072 * 10];
__device__ float g_p4[512 * 10];
__device__ float g_part[1536 * 256];              // per-block BN partials
__device__ float g_part2[64 * 256];               // stage-2 BN partials
__device__ float g_mean[128];
__device__ float g_inv[128];

__device__ __forceinline__ float b2f(u16 v) {
    return __uint_as_float(((unsigned)v) << 16);
}
__device__ __forceinline__ u16 f2b(float f) {
    unsigned u = __float_as_uint(f);
    return (u16)((u + 0x7FFFu + ((u >> 16) & 1u)) >> 16);   // RNE
}

// ---------------------------------------------------------------------------
// bf16 Laplacian on cat buffer: cat[:,outSlot] = alpha*L(cat[:,inSlot]) - cat[:,tppSlot]
// 16 lanes per node, 8 channels (16B) per lane.
// ---------------------------------------------------------------------------
template<int S>
__global__ __launch_bounds__(256)
void lap128b(u16* __restrict__ cat, int outSlot, int inSlot, int tppSlot,
             const float* __restrict__ ea, float alpha)
{
    int node = blockIdx.x * 16 + (threadIdx.x >> 4);
    int c8   = threadIdx.x & 15;          // 8 channels per lane

    const int x = node % S;
    const int y = (node / S) % S;
    const int g = node / (S * S);
    const int o = g % L_OR;
    const int b = g / L_OR;
    const int szx = N_BL * S * (S - 1);

    float a[8] = {0.f, 0.f, 0.f, 0.f, 0.f, 0.f, 0.f, 0.f};
    const int chOff = inSlot * 128 + c8 * 8;

    auto gather = [&](int src, float w) {
        s8v v = *(const s8v*)(cat + (size_t)src * 768 + chOff);
#pragma unroll
        for (int j = 0; j < 8; ++j) a[j] += w * b2f((u16)v[j]);
    };

    const int basex = (g * S + y) * (S - 1);
    if (x > 0)     gather(node - 1, ea[basex + x - 1]);
    if (x < S - 1) gather(node + 1, ea[szx + basex + x]);
    if (y > 0)     gather(node - S, ea[2 * szx + (g * (S - 1) + y - 1) * S + x]);
    if (y < S - 1) gather(node + S, ea[3 * szx + (g * (S - 1) + y) * S + x]);
    {   int op = (o == 0) ? L_OR - 1 : o - 1;
        int sp = ((b * L_OR + op) * S + y) * S + x;
        gather(sp, ea[4 * szx + sp]);
    }
    {   int on = (o == L_OR - 1) ? 0 : o + 1;
        int sn = ((b * L_OR + on) * S + y) * S + x;
        gather(sn, ea[4 * szx + N_BL * S * S + node]);
    }

    float r[8];
#pragma unroll
    for (int j = 0; j < 8; ++j) r[j] = alpha * a[j];
    if (tppSlot >= 0) {
        s8v t = *(const s8v*)(cat + (size_t)node * 768 + tppSlot * 128 + c8 * 8);
#pragma unroll
        for (int j = 0; j < 8; ++j) r[j] -= b2f((u16)t[j]);
    }
    s8v ov;
#pragma unroll
    for (int j = 0; j < 8; ++j) ov[j] = (short)f2b(r[j]);
    *(s8v*)(cat + (size_t)node * 768 + outSlot * 128 + c8 * 8) = ov;
}

// fp32 laplacian for layer 1 (D=3)
template<int S>
__global__ __launch_bounds__(256)
void lap3_kernel(float* __restrict__ out, const float* __restrict__ in,
                 const float* __restrict__ tpp, const float* __restrict__ ea,
                 float alpha)
{
    const int NN = N_BL * S * S;
    int n = blockIdx.x * 256 + threadIdx.x;
    if (n >= NN) return;
    const int x = n % S, y = (n / S) % S, g = n / (S * S);
    const int o = g % L_OR, b = g / L_OR;
    const int szx = N_BL * S * (S - 1);

    float a0 = 0.f, a1 = 0.f, a2 = 0.f;
    auto gather = [&](int src, float w) {
        a0 += w * in[src * 3 + 0];
        a1 += w * in[src * 3 + 1];
        a2 += w * in[src * 3 + 2];
    };
    const int basex = (g * S + y) * (S - 1);
    if (x > 0)     gather(n - 1, ea[basex + x - 1]);
    if (x < S - 1) gather(n + 1, ea[szx + basex + x]);
    if (y > 0)     gather(n - S, ea[2 * szx + (g * (S - 1) + y - 1) * S + x]);
    if (y < S - 1) gather(n + S, ea[3 * szx + (g * (S - 1) + y) * S + x]);
    { int op = (o == 0) ? L_OR - 1 : o - 1; int sp = ((b * L_OR + op) * S + y) * S + x;
      gather(sp, ea[4 * szx + sp]); }
    { int on = (o == L_OR - 1) ? 0 : o + 1; int sn = ((b * L_OR + on) * S + y) * S + x;
      gather(sn, ea[4 * szx + N_BL * S * S + n]); }

    float r0 = alpha * a0, r1 = alpha * a1, r2 = alpha * a2;
    if (tpp) { r0 -= tpp[n * 3 + 0]; r1 -= tpp[n * 3 + 1]; r2 -= tpp[n * 3 + 2]; }
    out[n * 3 + 0] = r0; out[n * 3 + 1] = r1; out[n * 3 + 2] = r2;
}

// ---------------------------------------------------------------------------
// MFMA GEMM + fused BN-stats.  O[N,128](bf16) = cat[N,768](bf16) @ W + bias.
// B staged per-phase (8KB) in double-buffered LDS, shared by 4 waves.
// A: depth-1 register prefetch. 2 barriers/phase (read-drain, write-publish).
// ---------------------------------------------------------------------------
__global__ __launch_bounds__(256)
void gemm_mfma_cat(u16* __restrict__ O, const u16* __restrict__ A,
                   const u16* __restrict__ Bf, const float* __restrict__ bias,
                   float* __restrict__ partials)
{
    __shared__ u16 Bs[2][4096];               // 2 phases x 8KB
    const int tid  = threadIdx.x;
    const int wave = tid >> 6;
    const int lane = tid & 63;
    const int lrow = lane & 15;
    const int kg   = lane >> 4;
    const int r0   = blockIdx.x * 128 + wave * 32;

    const u16* A0 = A + (size_t)(r0 + lrow) * 768 + kg * 8;
    const u16* A1 = A0 + (size_t)16 * 768;

    f4v acc[2][8] = {};

    // prologue: stage phase 0, load A phase 0
    {
        s8v s0 = *(const s8v*)(Bf + tid * 8);
        s8v s1 = *(const s8v*)(Bf + 2048 + tid * 8);
        *(s8v*)&Bs[0][tid * 8] = s0;
        *(s8v*)&Bs[0][2048 + tid * 8] = s1;
    }
    s8v a0 = *(const s8v*)(A0);
    s8v a1 = *(const s8v*)(A1);
    __syncthreads();

#pragma unroll 1
    for (int p = 0; p < 24; ++p) {
        const int cur = p & 1, nxt = cur ^ 1;
        // issue next-phase loads (in flight during this phase's MFMAs;
        // last iter reads the 8KB pad of g_Bt / row-pad of A — harmless)
        const u16* src = Bf + (p + 1) * 4096;
        s8v nb0 = *(const s8v*)(src + tid * 8);
        s8v nb1 = *(const s8v*)(src + 2048 + tid * 8);
        s8v a0n = *(const s8v*)(A0 + (p + 1) * 32);
        s8v a1n = *(const s8v*)(A1 + (p + 1) * 32);
        // compute phase p from LDS
#pragma unroll
        for (int ct = 0; ct < 8; ++ct) {
            s8v b = *(const s8v*)&Bs[cur][(ct * 64 + lane) * 8];
            acc[0][ct] = __builtin_amdgcn_mfma_f32_16x16x32_bf16(a0, b, acc[0][ct], 0, 0, 0);
            acc[1][ct] = __builtin_amdgcn_mfma_f32_16x16x32_bf16(a1, b, acc[1][ct], 0, 0, 0);
        }
        __syncthreads();                      // everyone done reading Bs[nxt] (phase p-1)
        *(s8v*)&Bs[nxt][tid * 8] = nb0;
        *(s8v*)&Bs[nxt][2048 + tid * 8] = nb1;
        __syncthreads();                      // Bs[nxt] published
        a0 = a0n; a1 = a1n;
    }

    __shared__ float sred[4][2][8][16];
    float cs[8], cq[8];
#pragma unroll
    for (int ct = 0; ct < 8; ++ct) { cs[ct] = 0.f; cq[ct] = 0.f; }

#pragma unroll
    for (int s = 0; s < 2; ++s)
#pragma unroll
        for (int ct = 0; ct < 8; ++ct) {
            int col = ct * 16 + lrow;
            float bv = bias[col];
#pragma unroll
            for (int j = 0; j < 4; ++j) {
                int row = r0 + s * 16 + kg * 4 + j;
                float v = acc[s][ct][j] + bv;
                O[(size_t)row * 128 + col] = f2b(v);
                cs[ct] += v; cq[ct] += v * v;
            }
        }
#pragma unroll
    for (int ct = 0; ct < 8; ++ct) {
        cs[ct] += __shfl_xor(cs[ct], 16); cs[ct] += __shfl_xor(cs[ct], 32);
        cq[ct] += __shfl_xor(cq[ct], 16); cq[ct] += __shfl_xor(cq[ct], 32);
    }
    if (lane < 16) {
#pragma unroll
        for (int ct = 0; ct < 8; ++ct) {
            sred[wave][0][ct][lane] = cs[ct];
            sred[wave][1][ct][lane] = cq[ct];
        }
    }
    __syncthreads();
    if (threadIdx.x < 128) {
        int ct = threadIdx.x >> 4, lr = threadIdx.x & 15;
        float S = 0.f, Q = 0.f;
#pragma unroll
        for (int w = 0; w < 4; ++w) { S += sred[w][0][ct][lr]; Q += sred[w][1][ct][lr]; }
        partials[blockIdx.x * 256 + threadIdx.x]       = S;
        partials[blockIdx.x * 256 + 128 + threadIdx.x] = Q;
    }
}

// weight prep into fragment order (see gemm_mfma_cat)
__global__ __launch_bounds__(256)
void wprep(const float* __restrict__ W, u16* __restrict__ Bf, int base)
{
    int idx = blockIdx.x * 256 + threadIdx.x;     // < 128*768
    int j    = idx & 7;
    int lane = (idx >> 3) & 63;
    int ct   = (idx >> 9) & 7;
    int k0s  = idx >> 12;
    int k    = k0s * 32 + (lane >> 4) * 8 + j;
    int col  = ct * 16 + (lane & 15);
    int slot = k >> 7, d = k & 127;
    int wk = slot - base; if (wk < 0) wk += 6;
    Bf[idx] = f2b(W[(size_t)wk * 16384 + d * 128 + col]);
}

__global__ __launch_bounds__(256)
void w6prep(const float* __restrict__ W, u16* __restrict__ W6t, int base)
{
    int idx = blockIdx.x * 256 + threadIdx.x;     // < 16*768
    if (idx >= 16 * 768) return;
    int c = idx / 768, kk = idx % 768;
    int slot = kk >> 7, d = kk & 127;
    int wk = slot - base; if (wk < 0) wk += 6;
    W6t[idx] = (c < 10) ? f2b(W[(size_t)wk * 1280 + d * 10 + c]) : (u16)0;
}

// layer-1 GEMM + fused stats. Block = 128 rows; T values staged in LDS.
__global__ __launch_bounds__(256)
void l1gemm(u16* __restrict__ O, const float* __restrict__ T0,
            const float* __restrict__ Tt, const float* __restrict__ W,
            const float* __restrict__ bias, float* __restrict__ partials)
{
    __shared__ float Ts[128][18];
    __shared__ float sh[2][128], sh2[2][128];
    int tid = threadIdx.x;
    int rbase = blockIdx.x * 128;
    for (int i = tid; i < 128 * 18; i += 256) {
        int r = i / 18, t = i % 18;
        int k = t / 3, j = t % 3;
        Ts[r][t] = (k == 0) ? T0[(size_t)(rbase + r) * 3 + j]
                            : Tt[(size_t)(k - 1) * N1 * 3 + (size_t)(rbase + r) * 3 + j];
    }
    __syncthreads();
    int c = tid & 127, h = tid >> 7;
    float w[18];
#pragma unroll
    for (int k = 0; k < 6; ++k)
#pragma unroll
        for (int j = 0; j < 3; ++j) w[k * 3 + j] = W[(size_t)k * 384 + j * 128 + c];
    float bv = bias[c];
    float S = 0.f, Q = 0.f;
    for (int i = 0; i < 64; ++i) {
        int r = h * 64 + i;
        float acc = bv;
#pragma unroll
        for (int t = 0; t < 18; ++t) acc += Ts[r][t] * w[t];
        O[(size_t)(rbase + r) * 128 + c] = f2b(acc);
        S += acc; Q += acc * acc;
    }
    sh[h][c] = S; sh2[h][c] = Q;
    __syncthreads();
    if (tid < 128) {
        partials[blockIdx.x * 256 + tid]       = sh[0][tid] + sh[1][tid];
        partials[blockIdx.x * 256 + 128 + tid] = sh2[0][tid] + sh2[1][tid];
    }
}

// layer-6 GEMM + bias + relu
__global__ __launch_bounds__(256)
void out10_cat(float* __restrict__ O10, const u16* __restrict__ cat,
               const u16* __restrict__ W6t, const float* __restrict__ bias)
{
    int col = threadIdx.x & 15;
    int row = blockIdx.x * 16 + (threadIdx.x >> 4);
    const u16* a = cat + (size_t)row * 768;
    const u16* w = W6t + (size_t)col * 768;
    float acc = 0.f;
#pragma unroll 4
    for (int k0 = 0; k0 < 768; k0 += 8) {
        s8v av = *(const s8v*)(a + k0);
        s8v wv = *(const s8v*)(w + k0);
#pragma unroll
        for (int j = 0; j < 8; ++j)
            acc += b2f((u16)av[j]) * b2f((u16)wv[j]);
    }
    if (col < 10)
        O10[(size_t)row * 10 + col] = fmaxf(acc + bias[col], 0.f);
}

// ---------------------------------------------------------------------------
// BN reduce stage 1: 64 blocks; block i sums records {i, i+64, ...}
// ---------------------------------------------------------------------------
__global__ __launch_bounds__(256)
void bn_reduce1(const float* __restrict__ partials, int nblk,
                float* __restrict__ part2)
{
    int tid = threadIdx.x;
    float S = 0.f;
#pragma unroll 4
    for (int b = blockIdx.x; b < nblk; b += 64)
        S += partials[(size_t)b * 256 + tid];
    part2[blockIdx.x * 256 + tid] = S;
}

// BN reduce stage 2: 1 block over fixed 64 records -> mean, invstd
__global__ __launch_bounds__(256)
void bn_finalize2(const float* __restrict__ part2, int N,
                  float* __restrict__ meanb, float* __restrict__ invstd)
{
    int tid = threadIdx.x;
    int c = tid & 127, h = tid >> 7;
    float S = 0.f, Q = 0.f;
#pragma unroll 8
    for (int b = h; b < 64; b += 2) {
        S += part2[b * 256 + c];
        Q += part2[b * 256 + 128 + c];
    }
    __shared__ float shS[2][128], shQ[2][128];
    shS[h][c] = S; shQ[h][c] = Q;
    __syncthreads();
    if (tid < 128) {
        float Sa = shS[0][tid] + shS[1][tid];
        float Qa = shQ[0][tid] + shQ[1][tid];
        float inv_n = 1.f / (float)N;
        float mu = Sa * inv_n;
        float var = Qa * inv_n - mu * mu;
        meanb[tid] = mu;
        invstd[tid] = rsqrtf(var + 1e-5f);
    }
}

// BN + relu + store bf16 into cat slot (8 channels/thread)
__global__ __launch_bounds__(256)
void bn_apply_cat8(const u16* __restrict__ O, u16* __restrict__ cat, int slot,
                   const float* __restrict__ meanb, const float* __restrict__ invstd,
                   const float* __restrict__ g, const float* __restrict__ bt)
{
    int idx = blockIdx.x * 256 + threadIdx.x;    // over N*16
    int c8 = idx & 15;
    size_t row = idx >> 4;
    s8v v = *(const s8v*)(O + row * 128 + c8 * 8);
    s8v ov;
#pragma unroll
    for (int j = 0; j < 8; ++j) {
        int c = c8 * 8 + j;
        float val = (b2f((u16)v[j]) - meanb[c]) * invstd[c] * g[c] + bt[c];
        ov[j] = (short)f2b(fmaxf(val, 0.f));
    }
    *(s8v*)(cat + row * 768 + slot * 128 + c8 * 8) = ov;
}

// BN + relu + 2x2 max-pool fused (8 channels/thread)
__global__ __launch_bounds__(256)
void bn_apply_pool8(const u16* __restrict__ O, u16* __restrict__ cat, int outSlot,
                    int s, int Nout,
                    const float* __restrict__ meanb, const float* __restrict__ invstd,
                    const float* __restrict__ g, const float* __restrict__ bt)
{
    int idx = blockIdx.x * 256 + threadIdx.x;    // over Nout*16
    if (idx >= Nout * 16) return;
    int c8 = idx & 15;
    int n2 = idx >> 4;
    int h  = s >> 1;
    int x2 = n2 % h;
    int y2 = (n2 / h) % h;
    int gg = n2 / (h * h);
    int base = (gg * s + 2 * y2) * s + 2 * x2;
    s8v v0 = *(const s8v*)(O + (size_t)base * 128 + c8 * 8);
    s8v v1 = *(const s8v*)(O + (size_t)(base + 1) * 128 + c8 * 8);
    s8v v2 = *(const s8v*)(O + (size_t)(base + s) * 128 + c8 * 8);
    s8v v3 = *(const s8v*)(O + (size_t)(base + s + 1) * 128 + c8 * 8);
    s8v ov;
#pragma unroll
    for (int j = 0; j < 8; ++j) {
        int c = c8 * 8 + j;
        float sc = invstd[c] * g[c];
        float so = bt[c] - meanb[c] * sc;
        float m =          b2f((u16)v0[j]) * sc + so;
        m = fmaxf(m, b2f((u16)v1[j]) * sc + so);
        m = fmaxf(m, b2f((u16)v2[j]) * sc + so);
        m = fmaxf(m, b2f((u16)v3[j]) * sc + so);
        ov[j] = (short)f2b(fmaxf(m, 0.f));
    }
    *(s8v*)(cat + (size_t)n2 * 768 + outSlot * 128 + c8 * 8) = ov;
}

// fp32 spatial pool (for layer-6 D=10 output)
__global__ __launch_bounds__(256)
void pool_spatial(float* __restrict__ out, const float* __restrict__ in,
                  int s, int D, int Nout)
{
    int idx = blockIdx.x * 256 + threadIdx.x;
    if (idx >= Nout * D) return;
    int c  = idx % D;
    int n2 = idx / D;
    int h  = s >> 1;
    int x2 = n2 % h;
    int y2 = (n2 / h) % h;
    int g  = n2 / (h * h);
    int base = (g * s + 2 * y2) * s + 2 * x2;
    float m = in[(size_t)base * D + c];
    m = fmaxf(m, in[(size_t)(base + 1) * D + c]);
    m = fmaxf(m, in[(size_t)(base + s) * D + c]);
    m = fmaxf(m, in[(size_t)(base + s + 1) * D + c]);
    out[(size_t)n2 * D + c] = m;
}

__global__ __launch_bounds__(256)
void pool_orient(float* __restrict__ out, const float* __restrict__ in)
{
    int idx = blockIdx.x * 256 + threadIdx.x;
    if (idx >= 512 * 10) return;
    int c = idx % 10;
    int n = idx / 10;
    int x = n % 8, y = (n / 8) % 8, b = n / 64;
    float m = -INFINITY;
    for (int o = 0; o < L_OR; ++o)
        m = fmaxf(m, in[(size_t)((((b * L_OR + o) * 8 + y) * 8 + x)) * 10 + c]);
    out[idx] = m;
}

__global__ __launch_bounds__(128)
void global_pool_logsoftmax(const float* __restrict__ in, float* __restrict__ out)
{
    __shared__ float G[8][10];
    __shared__ float rowm[8], rowl[8];
    int t = threadIdx.x;
    if (t < 80) {
        int b = t / 10, c = t % 10;
        float m = -INFINITY;
        for (int p = 0; p < 64; ++p)
            m = fmaxf(m, in[(size_t)(b * 64 + p) * 10 + c]);
        G[b][c] = m;
    }
    __syncthreads();
    if (t < 8) {
        float m = -INFINITY;
        for (int c = 0; c < 10; ++c) m = fmaxf(m, G[t][c]);
        float s = 0.f;
        for (int c = 0; c < 10; ++c) s += expf(G[t][c] - m);
        rowm[t] = m; rowl[t] = logf(s);
    }
    __syncthreads();
    if (t < 80) {
        int b = t / 10, c = t % 10;
        out[t] = G[b][c] - rowm[b] - rowl[b];
    }
}

// ---------------------------------------------------------------------------
// Host-side orchestration
// ---------------------------------------------------------------------------
static void launch_lapb(u16* cat, int os, int is, int ts, const float* ea,
                        int S, int N, float alpha, hipStream_t st)
{
    dim3 grid(N / 16), block(256);
    if (S == 64)      hipLaunchKernelGGL(lap128b<64>, grid, block, 0, st, cat, os, is, ts, ea, alpha);
    else if (S == 32) hipLaunchKernelGGL(lap128b<32>, grid, block, 0, st, cat, os, is, ts, ea, alpha);
    else              hipLaunchKernelGGL(lap128b<16>, grid, block, 0, st, cat, os, is, ts, ea, alpha);
}

static void cheb_laps(u16* cat, int base, const float* ea, int S, int N, hipStream_t st)
{
    for (int k = 1; k < 6; ++k) {
        int os = (k + base) % 6;
        int is = (k - 1 + base) % 6;
        int ts = (k >= 2) ? (k - 2 + base) % 6 : -1;
        launch_lapb(cat, os, is, ts, ea, S, N, (k == 1) ? 1.f : 2.f, st);
    }
}

static void bn_reduce(float* part, float* part2, int nblk, int N,
                      float* meanb, float* invstd, hipStream_t st)
{
    hipLaunchKernelGGL(bn_reduce1, dim3(64), dim3(256), 0, st, part, nblk, part2);
    hipLaunchKernelGGL(bn_finalize2, dim3(1), dim3(256), 0, st, part2, N, meanb, invstd);
}

extern "C" void kernel_launch(void* const* d_in, const int* in_sizes, int n_in,
                              void* d_out, int out_size, void* d_ws, size_t ws_size,
                              hipStream_t stream)
{
    const float* x   = (const float*)d_in[0];
    const float* ea1 = (const float*)d_in[2];
    const float* ea2 = (const float*)d_in[4];
    const float* ea3 = (const float*)d_in[6];
    const float* W1  = (const float*)d_in[12];
    const float* b1  = (const float*)d_in[13];
    const float* W2  = (const float*)d_in[14];
    const float* b2  = (const float*)d_in[15];
    const float* W3  = (const float*)d_in[16];
    const float* b3  = (const float*)d_in[17];
    const float* W4  = (const float*)d_in[18];
    const float* b4  = (const float*)d_in[19];
    const float* W5  = (const float*)d_in[20];
    const float* b5  = (const float*)d_in[21];
    const float* W6  = (const float*)d_in[22];
    const float* b6  = (const float*)d_in[23];
    const float* g1  = (const float*)d_in[24];
    const float* be1 = (const float*)d_in[25];
    const float* g2  = (const float*)d_in[26];
    const float* be2 = (const float*)d_in[27];
    const float* g3  = (const float*)d_in[28];
    const float* be3 = (const float*)d_in[29];
    const float* g4  = (const float*)d_in[30];
    const float* be4 = (const float*)d_in[31];
    const float* g5  = (const float*)d_in[32];
    const float* be5 = (const float*)d_in[33];

    u16 *cat, *O, *Bt, *W6t;
    float *Tt, *O10, *p3, *p4, *part, *part2, *meanb, *invstd;
    if (hipGetSymbolAddress((void**)&cat, HIP_SYMBOL(g_cat)) != hipSuccess) return;
    if (hipGetSymbolAddress((void**)&O,   HIP_SYMBOL(g_O))   != hipSuccess) return;
    if (hipGetSymbolAddress((void**)&Tt,  HIP_SYMBOL(g_Tt))  != hipSuccess) return;
    if (hipGetSymbolAddress((void**)&Bt,  HIP_SYMBOL(g_Bt))  != hipSuccess) return;
    if (hipGetSymbolAddress((void**)&W6t, HIP_SYMBOL(g_W6t)) != hipSuccess) return;
    if (hipGetSymbolAddress((void**)&O10, HIP_SYMBOL(g_O10)) != hipSuccess) return;
    if (hipGetSymbolAddress((void**)&p3,  HIP_SYMBOL(g_p3))  != hipSuccess) return;
    if (hipGetSymbolAddress((void**)&p4,  HIP_SYMBOL(g_p4))  != hipSuccess) return;
    if (hipGetSymbolAddress((void**)&part,   HIP_SYMBOL(g_part))  != hipSuccess) return;
    if (hipGetSymbolAddress((void**)&part2,  HIP_SYMBOL(g_part2)) != hipSuccess) return;
    if (hipGetSymbolAddress((void**)&meanb,  HIP_SYMBOL(g_mean))  != hipSuccess) return;
    if (hipGetSymbolAddress((void**)&invstd, HIP_SYMBOL(g_inv))   != hipSuccess) return;

    dim3 blk(256);

    // ---------- Layer 1: cheb(x[N1,3], W1) -> O bf16 (+stats); BN -> cat slot0 ----------
    {
        float* t1 = Tt;
        float* t2 = Tt + (size_t)N1 * 3;
        float* t3 = Tt + (size_t)2 * N1 * 3;
        float* t4 = Tt + (size_t)3 * N1 * 3;
        float* t5 = Tt + (size_t)4 * N1 * 3;
        dim3 gl((N1 + 255) / 256);
        hipLaunchKernelGGL(lap3_kernel<64>, gl, blk, 0, stream, t1, x,  (const float*)nullptr, ea1, 1.f);
        hipLaunchKernelGGL(lap3_kernel<64>, gl, blk, 0, stream, t2, t1, x,  ea1, 2.f);
        hipLaunchKernelGGL(lap3_kernel<64>, gl, blk, 0, stream, t3, t2, t1, ea1, 2.f);
        hipLaunchKernelGGL(lap3_kernel<64>, gl, blk, 0, stream, t4, t3, t2, ea1, 2.f);
        hipLaunchKernelGGL(lap3_kernel<64>, gl, blk, 0, stream, t5, t4, t3, ea1, 2.f);
        hipLaunchKernelGGL(l1gemm, dim3(N1 / 128), blk, 0, stream, O, x, Tt, W1, b1, part);
    }
    bn_reduce(part, part2, N1 / 128, N1, meanb, invstd, stream);
    hipLaunchKernelGGL(bn_apply_cat8, dim3(N1 / 16), blk, 0, stream,
                       O, cat, 0, meanb, invstd, g1, be1);

    // ---------- Layer 2 (N1, base 0) ----------
    hipLaunchKernelGGL(wprep, dim3(384), blk, 0, stream, W2, Bt, 0);
    cheb_laps(cat, 0, ea1, 64, N1, stream);
    hipLaunchKernelGGL(gemm_mfma_cat, dim3(N1 / 128), blk, 0, stream, O, cat, Bt, b2, part);
    bn_reduce(part, part2, N1 / 128, N1, meanb, invstd, stream);
    hipLaunchKernelGGL(bn_apply_pool8, dim3(N2 / 16), blk, 0, stream,
                       O, cat, 5, 64, N2, meanb, invstd, g2, be2);

    // ---------- Layer 3 (N2, base 5) ----------
    hipLaunchKernelGGL(wprep, dim3(384), blk, 0, stream, W3, Bt, 5);
    cheb_laps(cat, 5, ea2, 32, N2, stream);
    hipLaunchKernelGGL(gemm_mfma_cat, dim3(N2 / 128), blk, 0, stream, O, cat, Bt, b3, part);
    bn_reduce(part, part2, N2 / 128, N2, meanb, invstd, stream);
    hipLaunchKernelGGL(bn_apply_cat8, dim3(N2 / 16), blk, 0, stream,
                       O, cat, 0, meanb, invstd, g3, be3);

    // ---------- Layer 4 (N2, base 0) ----------
    hipLaunchKernelGGL(wprep, dim3(384), blk, 0, stream, W4, Bt, 0);
    cheb_laps(cat, 0, ea2, 32, N2, stream);
    hipLaunchKernelGGL(gemm_mfma_cat, dim3(N2 / 128), blk, 0, stream, O, cat, Bt, b4, part);
    bn_reduce(part, part2, N2 / 128, N2, meanb, invstd, stream);
    hipLaunchKernelGGL(bn_apply_pool8, dim3(N3 / 16), blk, 0, stream,
                       O, cat, 5, 32, N3, meanb, invstd, g4, be4);

    // ---------- Layer 5 (N3, base 5) ----------
    hipLaunchKernelGGL(wprep, dim3(384), blk, 0, stream, W5, Bt, 5);
    cheb_laps(cat, 5, ea3, 16, N3, stream);
    hipLaunchKernelGGL(gemm_mfma_cat, dim3(N3 / 128), blk, 0, stream, O, cat, Bt, b5, part);
    bn_reduce(part, part2, N3 / 128, N3, meanb, invstd, stream);
    hipLaunchKernelGGL(bn_apply_cat8, dim3(N3 / 16), blk, 0, stream,
                       O, cat, 0, meanb, invstd, g5, be5);

    // ---------- Layer 6 (N3, base 0, out 10, relu fused) ----------
    hipLaunchKernelGGL(w6prep, dim3(48), blk, 0, stream, W6, W6t, 0);
    cheb_laps(cat, 0, ea3, 16, N3, stream);
    hipLaunchKernelGGL(out10_cat, dim3(N3 / 16), blk, 0, stream, O10, cat, W6t, b6);

    // pool3: 16 -> 8 (D=10)
    hipLaunchKernelGGL(pool_spatial, dim3((3072 * 10 + 255) / 256), blk, 0, stream,
                       p3, O10, 16, 10, 3072);
    hipLaunchKernelGGL(pool_orient, dim3((512 * 10 + 255) / 256), blk, 0, stream, p4, p3);
    hipLaunchKernelGGL(global_pool_logsoftmax, dim3(1), dim3(128), 0, stream,
                       p4, (float*)d_out);
}

// Round 8
// 795.072 us; speedup vs baseline: 3.0385x; 1.0519x over previous
//
#include <hip/hip_runtime.h>
#include <math.h>

#define L_OR 6
#define N_BL 48   // B*L = 8*6

typedef unsigned short u16;
typedef __attribute__((ext_vector_type(8))) short s8v;   // 8 x bf16 (16B)
typedef __attribute__((ext_vector_type(4))) float f4v;

#define N1 196608
#define N2 49152
#define N3 12288

// ---- static device workspace (BSS, allocated at module load) ----
__device__ u16   g_cat[(size_t)N1 * 768 + 1024];  // 302 MB: 6 T-slots bf16 (+pad)
__device__ u16   g_O[(size_t)N1 * 128];           // 50 MB: GEMM output bf16
__device__ float g_Tt[5 * (size_t)N1 * 3];        // layer-1 T1..T5 fp32
__device__ u16   g_Bt[128 * 768 + 8192];          // fragment-ordered bf16 weights (+16KB pad)
__device__ u16   g_W6t[16 * 768];                 // layer-6 weights (padded cols)
__device__ float g_wt1[(size_t)N1 * 8];           // edge-weight tables per scale
__device__ float g_wt2[(size_t)N2 * 8];
__device__ float g_wt3[(size_t)N3 * 8];
__device__ float g_O10[(size_t)N3 * 10];
__device__ float g_p3[3072 * 10];
__device__ float g_p4[512 * 10];
__device__ float g_part[1536 * 256];              // per-block BN partials
__device__ float g_part2[64 * 256];               // stage-2 BN partials
__device__ float g_mean[128];
__device__ float g_inv[128];

__device__ __forceinline__ float b2f(u16 v) {
    return __uint_as_float(((unsigned)v) << 16);
}
__device__ __forceinline__ u16 f2b(float f) {
    unsigned u = __float_as_uint(f);
    return (u16)((u + 0x7FFFu + ((u >> 16) & 1u)) >> 16);   // RNE
}

// ---------------------------------------------------------------------------
// Edge-weight table prep (once per scale): wtab[n][0..5] = weights
// [xm,xp,ym,yp,om,op]; [6],[7] = ring source offsets (as int bits).
// ---------------------------------------------------------------------------
template<int S>
__global__ __launch_bounds__(256)
void eaprep(float* __restrict__ wtab, const float* __restrict__ ea)
{
    const int NN = N_BL * S * S;
    int n = blockIdx.x * 256 + threadIdx.x;
    if (n >= NN) return;
    int x = n % S, y = (n / S) % S, g = n / (S * S);
    int o = g % L_OR, b = g / L_OR;
    const int szx = N_BL * S * (S - 1);
    const int basex = (g * S + y) * (S - 1);
    float wxm = (x > 0)     ? ea[basex + x - 1] : 0.f;
    float wxp = (x < S - 1) ? ea[szx + basex + x] : 0.f;
    float wym = (y > 0)     ? ea[2 * szx + (g * (S - 1) + y - 1) * S + x] : 0.f;
    float wyp = (y < S - 1) ? ea[3 * szx + (g * (S - 1) + y) * S + x] : 0.f;
    int op_ = (o == 0) ? L_OR - 1 : o - 1;
    int on_ = (o == L_OR - 1) ? 0 : o + 1;
    int sp = ((b * L_OR + op_) * S + y) * S + x;
    int sn = ((b * L_OR + on_) * S + y) * S + x;
    float wom = ea[4 * szx + sp];
    float wop = ea[4 * szx + N_BL * S * S + n];
    float* w = wtab + (size_t)n * 8;
    w[0] = wxm; w[1] = wxp; w[2] = wym; w[3] = wyp; w[4] = wom; w[5] = wop;
    ((int*)w)[6] = sp - n;
    ((int*)w)[7] = sn - n;
}

// ---------------------------------------------------------------------------
// bf16 Laplacian on cat: cat[:,outSlot] = alpha*L(cat[:,inSlot]) - cat[:,tppSlot]
// 16 lanes/node, 8 channels (16B)/lane. Weights from wtab (broadcast loads).
// ---------------------------------------------------------------------------
template<int S>
__global__ __launch_bounds__(256)
void lap128b(u16* __restrict__ cat, int outSlot, int inSlot, int tppSlot,
             const float* __restrict__ wtab, float alpha)
{
    const int NN = N_BL * S * S;
    int node = blockIdx.x * 16 + (threadIdx.x >> 4);
    int c8   = threadIdx.x & 15;

    float4 wa = *(const float4*)(wtab + (size_t)node * 8);
    float4 wb = *(const float4*)(wtab + (size_t)node * 8 + 4);
    int dsp = __float_as_int(wb.z);
    int dsn = __float_as_int(wb.w);

    // clamped static-neighbor indices (weight is 0 wherever clamped)
    int sxm = (node > 0)      ? node - 1 : 0;
    int sxp = (node < NN - 1) ? node + 1 : node;
    int sym = (node >= S)     ? node - S : node;
    int syp = (node < NN - S) ? node + S : node;

    const int chOff = inSlot * 128 + c8 * 8;
    float a[8] = {0.f, 0.f, 0.f, 0.f, 0.f, 0.f, 0.f, 0.f};
    auto gather = [&](int src, float w) {
        s8v v = *(const s8v*)(cat + (size_t)src * 768 + chOff);
#pragma unroll
        for (int j = 0; j < 8; ++j) a[j] += w * b2f((u16)v[j]);
    };
    gather(sxm, wa.x);
    gather(sxp, wa.y);
    gather(sym, wa.z);
    gather(syp, wa.w);
    gather(node + dsp, wb.x);
    gather(node + dsn, wb.y);

    float r[8];
#pragma unroll
    for (int j = 0; j < 8; ++j) r[j] = alpha * a[j];
    if (tppSlot >= 0) {
        s8v t = *(const s8v*)(cat + (size_t)node * 768 + tppSlot * 128 + c8 * 8);
#pragma unroll
        for (int j = 0; j < 8; ++j) r[j] -= b2f((u16)t[j]);
    }
    uint4 ov;
    asm("v_cvt_pk_bf16_f32 %0, %1, %2" : "=v"(ov.x) : "v"(r[0]), "v"(r[1]));
    asm("v_cvt_pk_bf16_f32 %0, %1, %2" : "=v"(ov.y) : "v"(r[2]), "v"(r[3]));
    asm("v_cvt_pk_bf16_f32 %0, %1, %2" : "=v"(ov.z) : "v"(r[4]), "v"(r[5]));
    asm("v_cvt_pk_bf16_f32 %0, %1, %2" : "=v"(ov.w) : "v"(r[6]), "v"(r[7]));
    *(uint4*)(cat + (size_t)node * 768 + outSlot * 128 + c8 * 8) = ov;
}

// fp32 laplacian for layer 1 (D=3), wtab-based
template<int S>
__global__ __launch_bounds__(256)
void lap3_kernel(float* __restrict__ out, const float* __restrict__ in,
                 const float* __restrict__ tpp, const float* __restrict__ wtab,
                 float alpha)
{
    const int NN = N_BL * S * S;
    int n = blockIdx.x * 256 + threadIdx.x;
    if (n >= NN) return;
    float4 wa = *(const float4*)(wtab + (size_t)n * 8);
    float4 wb = *(const float4*)(wtab + (size_t)n * 8 + 4);
    int dsp = __float_as_int(wb.z);
    int dsn = __float_as_int(wb.w);
    int sxm = (n > 0)      ? n - 1 : 0;
    int sxp = (n < NN - 1) ? n + 1 : n;
    int sym = (n >= S)     ? n - S : n;
    int syp = (n < NN - S) ? n + S : n;

    float a0 = 0.f, a1 = 0.f, a2 = 0.f;
    auto gather = [&](int src, float w) {
        a0 += w * in[src * 3 + 0];
        a1 += w * in[src * 3 + 1];
        a2 += w * in[src * 3 + 2];
    };
    gather(sxm, wa.x); gather(sxp, wa.y); gather(sym, wa.z); gather(syp, wa.w);
    gather(n + dsp, wb.x); gather(n + dsn, wb.y);

    float r0 = alpha * a0, r1 = alpha * a1, r2 = alpha * a2;
    if (tpp) { r0 -= tpp[n * 3 + 0]; r1 -= tpp[n * 3 + 1]; r2 -= tpp[n * 3 + 2]; }
    out[n * 3 + 0] = r0; out[n * 3 + 1] = r1; out[n * 3 + 2] = r2;
}

// ---------------------------------------------------------------------------
// MFMA GEMM + fused BN-stats.  O[N,128](bf16) = cat[N,768](bf16) @ W + bias.
// B staged 16KB/phase in double-buffered LDS (2 k-subphases per barrier pair).
// ---------------------------------------------------------------------------
__global__ __launch_bounds__(256)
void gemm_mfma_cat(u16* __restrict__ O, const u16* __restrict__ A,
                   const u16* __restrict__ Bf, const float* __restrict__ bias,
                   float* __restrict__ partials)
{
    __shared__ u16 Bs[2][8192];               // 2 x 16KB
    const int tid  = threadIdx.x;
    const int wave = tid >> 6;
    const int lane = tid & 63;
    const int lrow = lane & 15;
    const int kg   = lane >> 4;
    const int r0   = blockIdx.x * 128 + wave * 32;

    const u16* A0 = A + (size_t)(r0 + lrow) * 768 + kg * 8;
    const u16* A1 = A0 + (size_t)16 * 768;

    f4v acc[2][8] = {};

    // prologue: stage phase 0 (16KB), load A for both subphases
#pragma unroll
    for (int i = 0; i < 4; ++i)
        *(s8v*)&Bs[0][i * 2048 + tid * 8] = *(const s8v*)(Bf + i * 2048 + tid * 8);
    s8v a00 = *(const s8v*)(A0);
    s8v a10 = *(const s8v*)(A1);
    s8v a01 = *(const s8v*)(A0 + 32);
    s8v a11 = *(const s8v*)(A1 + 32);
    __syncthreads();

#pragma unroll 1
    for (int p = 0; p < 12; ++p) {
        const int cur = p & 1, nxt = cur ^ 1;
        // issue next-phase loads (cover under this phase's 32 MFMAs;
        // last iter reads pads — harmless)
        const u16* src = Bf + (p + 1) * 8192;
        s8v nb0 = *(const s8v*)(src + tid * 8);
        s8v nb1 = *(const s8v*)(src + 2048 + tid * 8);
        s8v nb2 = *(const s8v*)(src + 4096 + tid * 8);
        s8v nb3 = *(const s8v*)(src + 6144 + tid * 8);
        s8v na00 = *(const s8v*)(A0 + (p + 1) * 64);
        s8v na10 = *(const s8v*)(A1 + (p + 1) * 64);
        s8v na01 = *(const s8v*)(A0 + (p + 1) * 64 + 32);
        s8v na11 = *(const s8v*)(A1 + (p + 1) * 64 + 32);
        // subphase 0
#pragma unroll
        for (int ct = 0; ct < 8; ++ct) {
            s8v b = *(const s8v*)&Bs[cur][(ct * 64 + lane) * 8];
            acc[0][ct] = __builtin_amdgcn_mfma_f32_16x16x32_bf16(a00, b, acc[0][ct], 0, 0, 0);
            acc[1][ct] = __builtin_amdgcn_mfma_f32_16x16x32_bf16(a10, b, acc[1][ct], 0, 0, 0);
        }
        // subphase 1
#pragma unroll
        for (int ct = 0; ct < 8; ++ct) {
            s8v b = *(const s8v*)&Bs[cur][4096 + (ct * 64 + lane) * 8];
            acc[0][ct] = __builtin_amdgcn_mfma_f32_16x16x32_bf16(a01, b, acc[0][ct], 0, 0, 0);
            acc[1][ct] = __builtin_amdgcn_mfma_f32_16x16x32_bf16(a11, b, acc[1][ct], 0, 0, 0);
        }
        __syncthreads();                      // readers of Bs[nxt] done
        *(s8v*)&Bs[nxt][tid * 8]        = nb0;
        *(s8v*)&Bs[nxt][2048 + tid * 8] = nb1;
        *(s8v*)&Bs[nxt][4096 + tid * 8] = nb2;
        *(s8v*)&Bs[nxt][6144 + tid * 8] = nb3;
        __syncthreads();                      // Bs[nxt] published
        a00 = na00; a10 = na10; a01 = na01; a11 = na11;
    }

    __shared__ float sred[4][2][8][16];
    float cs[8], cq[8];
#pragma unroll
    for (int ct = 0; ct < 8; ++ct) { cs[ct] = 0.f; cq[ct] = 0.f; }

#pragma unroll
    for (int s = 0; s < 2; ++s)
#pragma unroll
        for (int ct = 0; ct < 8; ++ct) {
            int col = ct * 16 + lrow;
            float bv = bias[col];
#pragma unroll
            for (int j = 0; j < 4; ++j) {
                int row = r0 + s * 16 + kg * 4 + j;
                float v = acc[s][ct][j] + bv;
                O[(size_t)row * 128 + col] = f2b(v);
                cs[ct] += v; cq[ct] += v * v;
            }
        }
#pragma unroll
    for (int ct = 0; ct < 8; ++ct) {
        cs[ct] += __shfl_xor(cs[ct], 16); cs[ct] += __shfl_xor(cs[ct], 32);
        cq[ct] += __shfl_xor(cq[ct], 16); cq[ct] += __shfl_xor(cq[ct], 32);
    }
    if (lane < 16) {
#pragma unroll
        for (int ct = 0; ct < 8; ++ct) {
            sred[wave][0][ct][lane] = cs[ct];
            sred[wave][1][ct][lane] = cq[ct];
        }
    }
    __syncthreads();
    if (threadIdx.x < 128) {
        int ct = threadIdx.x >> 4, lr = threadIdx.x & 15;
        float S = 0.f, Q = 0.f;
#pragma unroll
        for (int w = 0; w < 4; ++w) { S += sred[w][0][ct][lr]; Q += sred[w][1][ct][lr]; }
        partials[blockIdx.x * 256 + threadIdx.x]       = S;
        partials[blockIdx.x * 256 + 128 + threadIdx.x] = Q;
    }
}

// weight prep into fragment order (see gemm_mfma_cat)
__global__ __launch_bounds__(256)
void wprep(const float* __restrict__ W, u16* __restrict__ Bf, int base)
{
    int idx = blockIdx.x * 256 + threadIdx.x;     // < 128*768
    int j    = idx & 7;
    int lane = (idx >> 3) & 63;
    int ct   = (idx >> 9) & 7;
    int k0s  = idx >> 12;
    int k    = k0s * 32 + (lane >> 4) * 8 + j;
    int col  = ct * 16 + (lane & 15);
    int slot = k >> 7, d = k & 127;
    int wk = slot - base; if (wk < 0) wk += 6;
    Bf[idx] = f2b(W[(size_t)wk * 16384 + d * 128 + col]);
}

__global__ __launch_bounds__(256)
void w6prep(const float* __restrict__ W, u16* __restrict__ W6t, int base)
{
    int idx = blockIdx.x * 256 + threadIdx.x;     // < 16*768
    if (idx >= 16 * 768) return;
    int c = idx / 768, kk = idx % 768;
    int slot = kk >> 7, d = kk & 127;
    int wk = slot - base; if (wk < 0) wk += 6;
    W6t[idx] = (c < 10) ? f2b(W[(size_t)wk * 1280 + d * 10 + c]) : (u16)0;
}

// layer-1 GEMM + fused stats. Block = 128 rows; T values staged in LDS.
__global__ __launch_bounds__(256)
void l1gemm(u16* __restrict__ O, const float* __restrict__ T0,
            const float* __restrict__ Tt, const float* __restrict__ W,
            const float* __restrict__ bias, float* __restrict__ partials)
{
    __shared__ float Ts[128][18];
    __shared__ float sh[2][128], sh2[2][128];
    int tid = threadIdx.x;
    int rbase = blockIdx.x * 128;
    for (int i = tid; i < 128 * 18; i += 256) {
        int r = i / 18, t = i % 18;
        int k = t / 3, j = t % 3;
        Ts[r][t] = (k == 0) ? T0[(size_t)(rbase + r) * 3 + j]
                            : Tt[(size_t)(k - 1) * N1 * 3 + (size_t)(rbase + r) * 3 + j];
    }
    __syncthreads();
    int c = tid & 127, h = tid >> 7;
    float w[18];
#pragma unroll
    for (int k = 0; k < 6; ++k)
#pragma unroll
        for (int j = 0; j < 3; ++j) w[k * 3 + j] = W[(size_t)k * 384 + j * 128 + c];
    float bv = bias[c];
    float S = 0.f, Q = 0.f;
    for (int i = 0; i < 64; ++i) {
        int r = h * 64 + i;
        float acc = bv;
#pragma unroll
        for (int t = 0; t < 18; ++t) acc += Ts[r][t] * w[t];
        O[(size_t)(rbase + r) * 128 + c] = f2b(acc);
        S += acc; Q += acc * acc;
    }
    sh[h][c] = S; sh2[h][c] = Q;
    __syncthreads();
    if (tid < 128) {
        partials[blockIdx.x * 256 + tid]       = sh[0][tid] + sh[1][tid];
        partials[blockIdx.x * 256 + 128 + tid] = sh2[0][tid] + sh2[1][tid];
    }
}

// layer-6 GEMM + bias + relu
__global__ __launch_bounds__(256)
void out10_cat(float* __restrict__ O10, const u16* __restrict__ cat,
               const u16* __restrict__ W6t, const float* __restrict__ bias)
{
    int col = threadIdx.x & 15;
    int row = blockIdx.x * 16 + (threadIdx.x >> 4);
    const u16* a = cat + (size_t)row * 768;
    const u16* w = W6t + (size_t)col * 768;
    float acc = 0.f;
#pragma unroll 4
    for (int k0 = 0; k0 < 768; k0 += 8) {
        s8v av = *(const s8v*)(a + k0);
        s8v wv = *(const s8v*)(w + k0);
#pragma unroll
        for (int j = 0; j < 8; ++j)
            acc += b2f((u16)av[j]) * b2f((u16)wv[j]);
    }
    if (col < 10)
        O10[(size_t)row * 10 + col] = fmaxf(acc + bias[col], 0.f);
}

// BN reduce stage 1: 64 blocks; block i sums records {i, i+64, ...}
__global__ __launch_bounds__(256)
void bn_reduce1(const float* __restrict__ partials, int nblk,
                float* __restrict__ part2)
{
    int tid = threadIdx.x;
    float S = 0.f;
#pragma unroll 4
    for (int b = blockIdx.x; b < nblk; b += 64)
        S += partials[(size_t)b * 256 + tid];
    part2[blockIdx.x * 256 + tid] = S;
}

// BN reduce stage 2: 1 block over fixed 64 records -> mean, invstd
__global__ __launch_bounds__(256)
void bn_finalize2(const float* __restrict__ part2, int N,
                  float* __restrict__ meanb, float* __restrict__ invstd)
{
    int tid = threadIdx.x;
    int c = tid & 127, h = tid >> 7;
    float S = 0.f, Q = 0.f;
#pragma unroll 8
    for (int b = h; b < 64; b += 2) {
        S += part2[b * 256 + c];
        Q += part2[b * 256 + 128 + c];
    }
    __shared__ float shS[2][128], shQ[2][128];
    shS[h][c] = S; shQ[h][c] = Q;
    __syncthreads();
    if (tid < 128) {
        float Sa = shS[0][tid] + shS[1][tid];
        float Qa = shQ[0][tid] + shQ[1][tid];
        float inv_n = 1.f / (float)N;
        float mu = Sa * inv_n;
        float var = Qa * inv_n - mu * mu;
        meanb[tid] = mu;
        invstd[tid] = rsqrtf(var + 1e-5f);
    }
}

// BN + relu + store bf16 into cat slot (8 channels/thread)
__global__ __launch_bounds__(256)
void bn_apply_cat8(const u16* __restrict__ O, u16* __restrict__ cat, int slot,
                   const float* __restrict__ meanb, const float* __restrict__ invstd,
                   const float* __restrict__ g, const float* __restrict__ bt)
{
    int idx = blockIdx.x * 256 + threadIdx.x;    // over N*16
    int c8 = idx & 15;
    size_t row = idx >> 4;
    s8v v = *(const s8v*)(O + row * 128 + c8 * 8);
    s8v ov;
#pragma unroll
    for (int j = 0; j < 8; ++j) {
        int c = c8 * 8 + j;
        float val = (b2f((u16)v[j]) - meanb[c]) * invstd[c] * g[c] + bt[c];
        ov[j] = (short)f2b(fmaxf(val, 0.f));
    }
    *(s8v*)(cat + row * 768 + slot * 128 + c8 * 8) = ov;
}

// BN + relu + 2x2 max-pool fused (8 channels/thread)
__global__ __launch_bounds__(256)
void bn_apply_pool8(const u16* __restrict__ O, u16* __restrict__ cat, int outSlot,
                    int s, int Nout,
                    const float* __restrict__ meanb, const float* __restrict__ invstd,
                    const float* __restrict__ g, const float* __restrict__ bt)
{
    int idx = blockIdx.x * 256 + threadIdx.x;    // over Nout*16
    if (idx >= Nout * 16) return;
    int c8 = idx & 15;
    int n2 = idx >> 4;
    int h  = s >> 1;
    int x2 = n2 % h;
    int y2 = (n2 / h) % h;
    int gg = n2 / (h * h);
    int base = (gg * s + 2 * y2) * s + 2 * x2;
    s8v v0 = *(const s8v*)(O + (size_t)base * 128 + c8 * 8);
    s8v v1 = *(const s8v*)(O + (size_t)(base + 1) * 128 + c8 * 8);
    s8v v2 = *(const s8v*)(O + (size_t)(base + s) * 128 + c8 * 8);
    s8v v3 = *(const s8v*)(O + (size_t)(base + s + 1) * 128 + c8 * 8);
    s8v ov;
#pragma unroll
    for (int j = 0; j < 8; ++j) {
        int c = c8 * 8 + j;
        float sc = invstd[c] * g[c];
        float so = bt[c] - meanb[c] * sc;
        float m =          b2f((u16)v0[j]) * sc + so;
        m = fmaxf(m, b2f((u16)v1[j]) * sc + so);
        m = fmaxf(m, b2f((u16)v2[j]) * sc + so);
        m = fmaxf(m, b2f((u16)v3[j]) * sc + so);
        ov[j] = (short)f2b(fmaxf(m, 0.f));
    }
    *(s8v*)(cat + (size_t)n2 * 768 + outSlot * 128 + c8 * 8) = ov;
}

// fp32 spatial pool (for layer-6 D=10 output)
__global__ __launch_bounds__(256)
void pool_spatial(float* __restrict__ out, const float* __restrict__ in,
                  int s, int D, int Nout)
{
    int idx = blockIdx.x * 256 + threadIdx.x;
    if (idx >= Nout * D) return;
    int c  = idx % D;
    int n2 = idx / D;
    int h  = s >> 1;
    int x2 = n2 % h;
    int y2 = (n2 / h) % h;
    int g  = n2 / (h * h);
    int base = (g * s + 2 * y2) * s + 2 * x2;
    float m = in[(size_t)base * D + c];
    m = fmaxf(m, in[(size_t)(base + 1) * D + c]);
    m = fmaxf(m, in[(size_t)(base + s) * D + c]);
    m = fmaxf(m, in[(size_t)(base + s + 1) * D + c]);
    out[(size_t)n2 * D + c] = m;
}

__global__ __launch_bounds__(256)
void pool_orient(float* __restrict__ out, const float* __restrict__ in)
{
    int idx = blockIdx.x * 256 + threadIdx.x;
    if (idx >= 512 * 10) return;
    int c = idx % 10;
    int n = idx / 10;
    int x = n % 8, y = (n / 8) % 8, b = n / 64;
    float m = -INFINITY;
    for (int o = 0; o < L_OR; ++o)
        m = fmaxf(m, in[(size_t)((((b * L_OR + o) * 8 + y) * 8 + x)) * 10 + c]);
    out[idx] = m;
}

__global__ __launch_bounds__(128)
void global_pool_logsoftmax(const float* __restrict__ in, float* __restrict__ out)
{
    __shared__ float G[8][10];
    __shared__ float rowm[8], rowl[8];
    int t = threadIdx.x;
    if (t < 80) {
        int b = t / 10, c = t % 10;
        float m = -INFINITY;
        for (int p = 0; p < 64; ++p)
            m = fmaxf(m, in[(size_t)(b * 64 + p) * 10 + c]);
        G[b][c] = m;
    }
    __syncthreads();
    if (t < 8) {
        float m = -INFINITY;
        for (int c = 0; c < 10; ++c) m = fmaxf(m, G[t][c]);
        float s = 0.f;
        for (int c = 0; c < 10; ++c) s += expf(G[t][c] - m);
        rowm[t] = m; rowl[t] = logf(s);
    }
    __syncthreads();
    if (t < 80) {
        int b = t / 10, c = t % 10;
        out[t] = G[b][c] - rowm[b] - rowl[b];
    }
}

// ---------------------------------------------------------------------------
// Host-side orchestration
// ---------------------------------------------------------------------------
static void launch_lapb(u16* cat, int os, int is, int ts, const float* wtab,
                        int S, int N, float alpha, hipStream_t st)
{
    dim3 grid(N / 16), block(256);
    if (S == 64)      hipLaunchKernelGGL(lap128b<64>, grid, block, 0, st, cat, os, is, ts, wtab, alpha);
    else if (S == 32) hipLaunchKernelGGL(lap128b<32>, grid, block, 0, st, cat, os, is, ts, wtab, alpha);
    else              hipLaunchKernelGGL(lap128b<16>, grid, block, 0, st, cat, os, is, ts, wtab, alpha);
}

static void cheb_laps(u16* cat, int base, const float* wtab, int S, int N, hipStream_t st)
{
    for (int k = 1; k < 6; ++k) {
        int os = (k + base) % 6;
        int is = (k - 1 + base) % 6;
        int ts = (k >= 2) ? (k - 2 + base) % 6 : -1;
        launch_lapb(cat, os, is, ts, wtab, S, N, (k == 1) ? 1.f : 2.f, st);
    }
}

static void bn_reduce(float* part, float* part2, int nblk, int N,
                      float* meanb, float* invstd, hipStream_t st)
{
    hipLaunchKernelGGL(bn_reduce1, dim3(64), dim3(256), 0, st, part, nblk, part2);
    hipLaunchKernelGGL(bn_finalize2, dim3(1), dim3(256), 0, st, part2, N, meanb, invstd);
}

extern "C" void kernel_launch(void* const* d_in, const int* in_sizes, int n_in,
                              void* d_out, int out_size, void* d_ws, size_t ws_size,
                              hipStream_t stream)
{
    const float* x   = (const float*)d_in[0];
    const float* ea1 = (const float*)d_in[2];
    const float* ea2 = (const float*)d_in[4];
    const float* ea3 = (const float*)d_in[6];
    const float* W1  = (const float*)d_in[12];
    const float* b1  = (const float*)d_in[13];
    const float* W2  = (const float*)d_in[14];
    const float* b2  = (const float*)d_in[15];
    const float* W3  = (const float*)d_in[16];
    const float* b3  = (const float*)d_in[17];
    const float* W4  = (const float*)d_in[18];
    const float* b4  = (const float*)d_in[19];
    const float* W5  = (const float*)d_in[20];
    const float* b5  = (const float*)d_in[21];
    const float* W6  = (const float*)d_in[22];
    const float* b6  = (const float*)d_in[23];
    const float* g1  = (const float*)d_in[24];
    const float* be1 = (const float*)d_in[25];
    const float* g2  = (const float*)d_in[26];
    const float* be2 = (const float*)d_in[27];
    const float* g3  = (const float*)d_in[28];
    const float* be3 = (const float*)d_in[29];
    const float* g4  = (const float*)d_in[30];
    const float* be4 = (const float*)d_in[31];
    const float* g5  = (const float*)d_in[32];
    const float* be5 = (const float*)d_in[33];

    u16 *cat, *O, *Bt, *W6t;
    float *Tt, *O10, *p3, *p4, *part, *part2, *meanb, *invstd, *wt1, *wt2, *wt3;
    if (hipGetSymbolAddress((void**)&cat, HIP_SYMBOL(g_cat)) != hipSuccess) return;
    if (hipGetSymbolAddress((void**)&O,   HIP_SYMBOL(g_O))   != hipSuccess) return;
    if (hipGetSymbolAddress((void**)&Tt,  HIP_SYMBOL(g_Tt))  != hipSuccess) return;
    if (hipGetSymbolAddress((void**)&Bt,  HIP_SYMBOL(g_Bt))  != hipSuccess) return;
    if (hipGetSymbolAddress((void**)&W6t, HIP_SYMBOL(g_W6t)) != hipSuccess) return;
    if (hipGetSymbolAddress((void**)&O10, HIP_SYMBOL(g_O10)) != hipSuccess) return;
    if (hipGetSymbolAddress((void**)&p3,  HIP_SYMBOL(g_p3))  != hipSuccess) return;
    if (hipGetSymbolAddress((void**)&p4,  HIP_SYMBOL(g_p4))  != hipSuccess) return;
    if (hipGetSymbolAddress((void**)&part,   HIP_SYMBOL(g_part))  != hipSuccess) return;
    if (hipGetSymbolAddress((void**)&part2,  HIP_SYMBOL(g_part2)) != hipSuccess) return;
    if (hipGetSymbolAddress((void**)&meanb,  HIP_SYMBOL(g_mean))  != hipSuccess) return;
    if (hipGetSymbolAddress((void**)&invstd, HIP_SYMBOL(g_inv))   != hipSuccess) return;
    if (hipGetSymbolAddress((void**)&wt1, HIP_SYMBOL(g_wt1)) != hipSuccess) return;
    if (hipGetSymbolAddress((void**)&wt2, HIP_SYMBOL(g_wt2)) != hipSuccess) return;
    if (hipGetSymbolAddress((void**)&wt3, HIP_SYMBOL(g_wt3)) != hipSuccess) return;

    dim3 blk(256);

    // ---------- edge-weight tables (once per call) ----------
    hipLaunchKernelGGL(eaprep<64>, dim3(N1 / 256), blk, 0, stream, wt1, ea1);
    hipLaunchKernelGGL(eaprep<32>, dim3(N2 / 256), blk, 0, stream, wt2, ea2);
    hipLaunchKernelGGL(eaprep<16>, dim3(N3 / 256), blk, 0, stream, wt3, ea3);

    // ---------- Layer 1: cheb(x[N1,3], W1) -> O bf16 (+stats); BN -> cat slot0 ----------
    {
        float* t1 = Tt;
        float* t2 = Tt + (size_t)N1 * 3;
        float* t3 = Tt + (size_t)2 * N1 * 3;
        float* t4 = Tt + (size_t)3 * N1 * 3;
        float* t5 = Tt + (size_t)4 * N1 * 3;
        dim3 gl((N1 + 255) / 256);
        hipLaunchKernelGGL(lap3_kernel<64>, gl, blk, 0, stream, t1, x,  (const float*)nullptr, wt1, 1.f);
        hipLaunchKernelGGL(lap3_kernel<64>, gl, blk, 0, stream, t2, t1, x,  wt1, 2.f);
        hipLaunchKernelGGL(lap3_kernel<64>, gl, blk, 0, stream, t3, t2, t1, wt1, 2.f);
        hipLaunchKernelGGL(lap3_kernel<64>, gl, blk, 0, stream, t4, t3, t2, wt1, 2.f);
        hipLaunchKernelGGL(lap3_kernel<64>, gl, blk, 0, stream, t5, t4, t3, wt1, 2.f);
        hipLaunchKernelGGL(l1gemm, dim3(N1 / 128), blk, 0, stream, O, x, Tt, W1, b1, part);
    }
    bn_reduce(part, part2, N1 / 128, N1, meanb, invstd, stream);
    hipLaunchKernelGGL(bn_apply_cat8, dim3(N1 / 16), blk, 0, stream,
                       O, cat, 0, meanb, invstd, g1, be1);

    // ---------- Layer 2 (N1, base 0) ----------
    hipLaunchKernelGGL(wprep, dim3(384), blk, 0, stream, W2, Bt, 0);
    cheb_laps(cat, 0, wt1, 64, N1, stream);
    hipLaunchKernelGGL(gemm_mfma_cat, dim3(N1 / 128), blk, 0, stream, O, cat, Bt, b2, part);
    bn_reduce(part, part2, N1 / 128, N1, meanb, invstd, stream);
    hipLaunchKernelGGL(bn_apply_pool8, dim3(N2 / 16), blk, 0, stream,
                       O, cat, 5, 64, N2, meanb, invstd, g2, be2);

    // ---------- Layer 3 (N2, base 5) ----------
    hipLaunchKernelGGL(wprep, dim3(384), blk, 0, stream, W3, Bt, 5);
    cheb_laps(cat, 5, wt2, 32, N2, stream);
    hipLaunchKernelGGL(gemm_mfma_cat, dim3(N2 / 128), blk, 0, stream, O, cat, Bt, b3, part);
    bn_reduce(part, part2, N2 / 128, N2, meanb, invstd, stream);
    hipLaunchKernelGGL(bn_apply_cat8, dim3(N2 / 16), blk, 0, stream,
                       O, cat, 0, meanb, invstd, g3, be3);

    // ---------- Layer 4 (N2, base 0) ----------
    hipLaunchKernelGGL(wprep, dim3(384), blk, 0, stream, W4, Bt, 0);
    cheb_laps(cat, 0, wt2, 32, N2, stream);
    hipLaunchKernelGGL(gemm_mfma_cat, dim3(N2 / 128), blk, 0, stream, O, cat, Bt, b4, part);
    bn_reduce(part, part2, N2 / 128, N2, meanb, invstd, stream);
    hipLaunchKernelGGL(bn_apply_pool8, dim3(N3 / 16), blk, 0, stream,
                       O, cat, 5, 32, N3, meanb, invstd, g4, be4);

    // ---------- Layer 5 (N3, base 5) ----------
    hipLaunchKernelGGL(wprep, dim3(384), blk, 0, stream, W5, Bt, 5);
    cheb_laps(cat, 5, wt3, 16, N3, stream);
    hipLaunchKernelGGL(gemm_mfma_cat, dim3(N3 / 128), blk, 0, stream, O, cat, Bt, b5, part);
    bn_reduce(part, part2, N3 / 128, N3, meanb, invstd, stream);
    hipLaunchKernelGGL(bn_apply_cat8, dim3(N3 / 16), blk, 0, stream,
                       O, cat, 0, meanb, invstd, g5, be5);

    // ---------- Layer 6 (N3, base 0, out 10, relu fused) ----------
    hipLaunchKernelGGL(w6prep, dim3(48), blk, 0, stream, W6, W6t, 0);
    cheb_laps(cat, 0, wt3, 16, N3, stream);
    hipLaunchKernelGGL(out10_cat, dim3(N3 / 16), blk, 0, stream, O10, cat, W6t, b6);

    // pool3: 16 -> 8 (D=10)
    hipLaunchKernelGGL(pool_spatial, dim3((3072 * 10 + 255) / 256), blk, 0, stream,
                       p3, O10, 16, 10, 3072);
    hipLaunchKernelGGL(pool_orient, dim3((512 * 10 + 255) / 256), blk, 0, stream, p4, p3);
    hipLaunchKernelGGL(global_pool_logsoftmax, dim3(1), dim3(128), 0, stream,
                       p4, (float*)d_out);
}

// Round 9
// 760.486 us; speedup vs baseline: 3.1767x; 1.0455x over previous
//
#include <hip/hip_runtime.h>
#include <math.h>

#define L_OR 6
#define N_BL 48   // B*L = 8*6

typedef unsigned short u16;
typedef __attribute__((ext_vector_type(8))) short s8v;   // 8 x bf16 (16B)
typedef __attribute__((ext_vector_type(4))) float f4v;

#define N1 196608
#define N2 49152
#define N3 12288
#define LSTRIDE 114688   // u16 stride per layer in g_Bt (96K data + 16K pad)

// ---- static device workspace (BSS, allocated at module load) ----
__device__ u16   g_cat[(size_t)N1 * 768 + 1024];  // 302 MB: 6 T-slots bf16 (+pad)
__device__ u16   g_O[(size_t)N1 * 128];           // 50 MB: GEMM output bf16
__device__ float g_Tt[5 * (size_t)N1 * 3];        // layer-1 T1..T5 fp32
__device__ u16   g_Bt[4 * LSTRIDE];               // fragment-ordered weights, W2..W5
__device__ u16   g_W6t[16 * 768];                 // layer-6 weights (padded cols)
__device__ float g_wt1[(size_t)N1 * 8];           // edge-weight tables per scale
__device__ float g_wt2[(size_t)N2 * 8];
__device__ float g_wt3[(size_t)N3 * 8];
__device__ float g_O10[(size_t)N3 * 10];
__device__ float g_part[1536 * 256];              // per-block BN partials
__device__ float g_part2[64 * 256];               // stage-2 BN partials
__device__ float g_gsc[128];                      // BN combined scale
__device__ float g_gso[128];                      // BN combined offset

__device__ __forceinline__ float b2f(u16 v) {
    return __uint_as_float(((unsigned)v) << 16);
}
__device__ __forceinline__ u16 f2b(float f) {
    unsigned u = __float_as_uint(f);
    return (u16)((u + 0x7FFFu + ((u >> 16) & 1u)) >> 16);   // RNE
}

// ---------------------------------------------------------------------------
// Edge-weight tables, all three scales in one launch.
// wtab[n][0..5] = weights [xm,xp,ym,yp,om,op]; [6],[7] = ring offsets (int bits)
// ---------------------------------------------------------------------------
__global__ __launch_bounds__(256)
void eaprep_all(float* __restrict__ wt1, float* __restrict__ wt2,
                float* __restrict__ wt3, const float* __restrict__ ea1,
                const float* __restrict__ ea2, const float* __restrict__ ea3)
{
    int idx = blockIdx.x * 256 + threadIdx.x;
    int S, n; float* wtab; const float* ea;
    if (idx < N1)            { S = 64; wtab = wt1; ea = ea1; n = idx; }
    else if (idx < N1 + N2)  { S = 32; wtab = wt2; ea = ea2; n = idx - N1; }
    else if (idx < N1 + N2 + N3) { S = 16; wtab = wt3; ea = ea3; n = idx - N1 - N2; }
    else return;
    int x = n % S, y = (n / S) % S, g = n / (S * S);
    int o = g % L_OR, b = g / L_OR;
    const int szx = N_BL * S * (S - 1);
    const int basex = (g * S + y) * (S - 1);
    float wxm = (x > 0)     ? ea[basex + x - 1] : 0.f;
    float wxp = (x < S - 1) ? ea[szx + basex + x] : 0.f;
    float wym = (y > 0)     ? ea[2 * szx + (g * (S - 1) + y - 1) * S + x] : 0.f;
    float wyp = (y < S - 1) ? ea[3 * szx + (g * (S - 1) + y) * S + x] : 0.f;
    int op_ = (o == 0) ? L_OR - 1 : o - 1;
    int on_ = (o == L_OR - 1) ? 0 : o + 1;
    int sp = ((b * L_OR + op_) * S + y) * S + x;
    int sn = ((b * L_OR + on_) * S + y) * S + x;
    float wom = ea[4 * szx + sp];
    float wop = ea[4 * szx + N_BL * S * S + n];
    float* w = wtab + (size_t)n * 8;
    w[0] = wxm; w[1] = wxp; w[2] = wym; w[3] = wyp; w[4] = wom; w[5] = wop;
    ((int*)w)[6] = sp - n;
    ((int*)w)[7] = sn - n;
}

// ---------------------------------------------------------------------------
// bf16 Laplacian on cat: cat[:,outSlot] = alpha*L(cat[:,inSlot]) - cat[:,tppSlot]
// ---------------------------------------------------------------------------
template<int S>
__global__ __launch_bounds__(256)
void lap128b(u16* __restrict__ cat, int outSlot, int inSlot, int tppSlot,
             const float* __restrict__ wtab, float alpha)
{
    const int NN = N_BL * S * S;
    int node = blockIdx.x * 16 + (threadIdx.x >> 4);
    int c8   = threadIdx.x & 15;

    float4 wa = *(const float4*)(wtab + (size_t)node * 8);
    float4 wb = *(const float4*)(wtab + (size_t)node * 8 + 4);
    int dsp = __float_as_int(wb.z);
    int dsn = __float_as_int(wb.w);
    int sxm = (node > 0)      ? node - 1 : 0;
    int sxp = (node < NN - 1) ? node + 1 : node;
    int sym = (node >= S)     ? node - S : node;
    int syp = (node < NN - S) ? node + S : node;

    const int chOff = inSlot * 128 + c8 * 8;
    float a[8] = {0.f, 0.f, 0.f, 0.f, 0.f, 0.f, 0.f, 0.f};
    auto gather = [&](int src, float w) {
        s8v v = *(const s8v*)(cat + (size_t)src * 768 + chOff);
#pragma unroll
        for (int j = 0; j < 8; ++j) a[j] += w * b2f((u16)v[j]);
    };
    gather(sxm, wa.x); gather(sxp, wa.y); gather(sym, wa.z); gather(syp, wa.w);
    gather(node + dsp, wb.x); gather(node + dsn, wb.y);

    float r[8];
#pragma unroll
    for (int j = 0; j < 8; ++j) r[j] = alpha * a[j];
    if (tppSlot >= 0) {
        s8v t = *(const s8v*)(cat + (size_t)node * 768 + tppSlot * 128 + c8 * 8);
#pragma unroll
        for (int j = 0; j < 8; ++j) r[j] -= b2f((u16)t[j]);
    }
    uint4 ov;
    asm("v_cvt_pk_bf16_f32 %0, %1, %2" : "=v"(ov.x) : "v"(r[0]), "v"(r[1]));
    asm("v_cvt_pk_bf16_f32 %0, %1, %2" : "=v"(ov.y) : "v"(r[2]), "v"(r[3]));
    asm("v_cvt_pk_bf16_f32 %0, %1, %2" : "=v"(ov.z) : "v"(r[4]), "v"(r[5]));
    asm("v_cvt_pk_bf16_f32 %0, %1, %2" : "=v"(ov.w) : "v"(r[6]), "v"(r[7]));
    *(uint4*)(cat + (size_t)node * 768 + outSlot * 128 + c8 * 8) = ov;
}

// ---------------------------------------------------------------------------
// Fused BN+ReLU + first lap: h = max(O*sc+so,0);  writes T0=h and T1=L(h).
// ---------------------------------------------------------------------------
template<int S>
__global__ __launch_bounds__(256)
void lap1bn(u16* __restrict__ cat, const u16* __restrict__ O,
            int t0Slot, int t1Slot, const float* __restrict__ wtab,
            const float* __restrict__ gsc, const float* __restrict__ gso)
{
    const int NN = N_BL * S * S;
    int node = blockIdx.x * 16 + (threadIdx.x >> 4);
    int c8   = threadIdx.x & 15;

    float4 wa = *(const float4*)(wtab + (size_t)node * 8);
    float4 wb = *(const float4*)(wtab + (size_t)node * 8 + 4);
    int dsp = __float_as_int(wb.z);
    int dsn = __float_as_int(wb.w);
    int sxm = (node > 0)      ? node - 1 : 0;
    int sxp = (node < NN - 1) ? node + 1 : node;
    int sym = (node >= S)     ? node - S : node;
    int syp = (node < NN - S) ? node + S : node;

    float sc[8], so[8];
    {
        float4 s0 = *(const float4*)(gsc + c8 * 8);
        float4 s1 = *(const float4*)(gsc + c8 * 8 + 4);
        float4 o0 = *(const float4*)(gso + c8 * 8);
        float4 o1 = *(const float4*)(gso + c8 * 8 + 4);
        sc[0]=s0.x; sc[1]=s0.y; sc[2]=s0.z; sc[3]=s0.w;
        sc[4]=s1.x; sc[5]=s1.y; sc[6]=s1.z; sc[7]=s1.w;
        so[0]=o0.x; so[1]=o0.y; so[2]=o0.z; so[3]=o0.w;
        so[4]=o1.x; so[5]=o1.y; so[6]=o1.z; so[7]=o1.w;
    }

    float a[8] = {0.f, 0.f, 0.f, 0.f, 0.f, 0.f, 0.f, 0.f};
    auto gatherbn = [&](int src, float w) {
        s8v v = *(const s8v*)(O + (size_t)src * 128 + c8 * 8);
#pragma unroll
        for (int j = 0; j < 8; ++j)
            a[j] += w * fmaxf(b2f((u16)v[j]) * sc[j] + so[j], 0.f);
    };
    gatherbn(sxm, wa.x); gatherbn(sxp, wa.y); gatherbn(sym, wa.z); gatherbn(syp, wa.w);
    gatherbn(node + dsp, wb.x); gatherbn(node + dsn, wb.y);

    // own node -> T0 = h(node)
    float t0[8];
    {
        s8v v = *(const s8v*)(O + (size_t)node * 128 + c8 * 8);
#pragma unroll
        for (int j = 0; j < 8; ++j)
            t0[j] = fmaxf(b2f((u16)v[j]) * sc[j] + so[j], 0.f);
    }
    uint4 o0v, o1v;
    asm("v_cvt_pk_bf16_f32 %0, %1, %2" : "=v"(o0v.x) : "v"(t0[0]), "v"(t0[1]));
    asm("v_cvt_pk_bf16_f32 %0, %1, %2" : "=v"(o0v.y) : "v"(t0[2]), "v"(t0[3]));
    asm("v_cvt_pk_bf16_f32 %0, %1, %2" : "=v"(o0v.z) : "v"(t0[4]), "v"(t0[5]));
    asm("v_cvt_pk_bf16_f32 %0, %1, %2" : "=v"(o0v.w) : "v"(t0[6]), "v"(t0[7]));
    asm("v_cvt_pk_bf16_f32 %0, %1, %2" : "=v"(o1v.x) : "v"(a[0]), "v"(a[1]));
    asm("v_cvt_pk_bf16_f32 %0, %1, %2" : "=v"(o1v.y) : "v"(a[2]), "v"(a[3]));
    asm("v_cvt_pk_bf16_f32 %0, %1, %2" : "=v"(o1v.z) : "v"(a[4]), "v"(a[5]));
    asm("v_cvt_pk_bf16_f32 %0, %1, %2" : "=v"(o1v.w) : "v"(a[6]), "v"(a[7]));
    *(uint4*)(cat + (size_t)node * 768 + t0Slot * 128 + c8 * 8) = o0v;
    *(uint4*)(cat + (size_t)node * 768 + t1Slot * 128 + c8 * 8) = o1v;
}

// fp32 laplacian for layer 1 (D=3), wtab-based
template<int S>
__global__ __launch_bounds__(256)
void lap3_kernel(float* __restrict__ out, const float* __restrict__ in,
                 const float* __restrict__ tpp, const float* __restrict__ wtab,
                 float alpha)
{
    const int NN = N_BL * S * S;
    int n = blockIdx.x * 256 + threadIdx.x;
    if (n >= NN) return;
    float4 wa = *(const float4*)(wtab + (size_t)n * 8);
    float4 wb = *(const float4*)(wtab + (size_t)n * 8 + 4);
    int dsp = __float_as_int(wb.z);
    int dsn = __float_as_int(wb.w);
    int sxm = (n > 0)      ? n - 1 : 0;
    int sxp = (n < NN - 1) ? n + 1 : n;
    int sym = (n >= S)     ? n - S : n;
    int syp = (n < NN - S) ? n + S : n;

    float a0 = 0.f, a1 = 0.f, a2 = 0.f;
    auto gather = [&](int src, float w) {
        a0 += w * in[src * 3 + 0];
        a1 += w * in[src * 3 + 1];
        a2 += w * in[src * 3 + 2];
    };
    gather(sxm, wa.x); gather(sxp, wa.y); gather(sym, wa.z); gather(syp, wa.w);
    gather(n + dsp, wb.x); gather(n + dsn, wb.y);

    float r0 = alpha * a0, r1 = alpha * a1, r2 = alpha * a2;
    if (tpp) { r0 -= tpp[n * 3 + 0]; r1 -= tpp[n * 3 + 1]; r2 -= tpp[n * 3 + 2]; }
    out[n * 3 + 0] = r0; out[n * 3 + 1] = r1; out[n * 3 + 2] = r2;
}

// ---------------------------------------------------------------------------
// MFMA GEMM + fused BN-stats.  O[N,128](bf16) = cat[N,768](bf16) @ W + bias.
// B: depth-2 register pipeline -> double-buffered 16KB LDS phases.
// ---------------------------------------------------------------------------
__global__ __launch_bounds__(256)
void gemm_mfma_cat(u16* __restrict__ O, const u16* __restrict__ A,
                   const u16* __restrict__ Bf, const float* __restrict__ bias,
                   float* __restrict__ partials)
{
    __shared__ u16 Bs[2][8192];               // 2 x 16KB
    const int tid  = threadIdx.x;
    const int wave = tid >> 6;
    const int lane = tid & 63;
    const int lrow = lane & 15;
    const int kg   = lane >> 4;
    const int r0   = blockIdx.x * 128 + wave * 32;

    const u16* A0 = A + (size_t)(r0 + lrow) * 768 + kg * 8;
    const u16* A1 = A0 + (size_t)16 * 768;

    f4v acc[2][8] = {};

#define COMPUTE(BUF, A00, A10, A01, A11)                                        \
    {                                                                           \
        _Pragma("unroll")                                                       \
        for (int ct = 0; ct < 8; ++ct) {                                        \
            s8v b = *(const s8v*)&Bs[BUF][(ct * 64 + lane) * 8];                \
            acc[0][ct] = __builtin_amdgcn_mfma_f32_16x16x32_bf16(A00, b, acc[0][ct], 0, 0, 0); \
            acc[1][ct] = __builtin_amdgcn_mfma_f32_16x16x32_bf16(A10, b, acc[1][ct], 0, 0, 0); \
        }                                                                       \
        _Pragma("unroll")                                                       \
        for (int ct = 0; ct < 8; ++ct) {                                        \
            s8v b = *(const s8v*)&Bs[BUF][4096 + (ct * 64 + lane) * 8];         \
            acc[0][ct] = __builtin_amdgcn_mfma_f32_16x16x32_bf16(A01, b, acc[0][ct], 0, 0, 0); \
            acc[1][ct] = __builtin_amdgcn_mfma_f32_16x16x32_bf16(A11, b, acc[1][ct], 0, 0, 0); \
        }                                                                       \
    }

    // prologue: phase0 -> Bs[0]; phase1 -> regs X; A for phase0
#pragma unroll
    for (int i = 0; i < 4; ++i)
        *(s8v*)&Bs[0][i * 2048 + tid * 8] = *(const s8v*)(Bf + i * 2048 + tid * 8);
    s8v rX0 = *(const s8v*)(Bf + 8192 + tid * 8);
    s8v rX1 = *(const s8v*)(Bf + 8192 + 2048 + tid * 8);
    s8v rX2 = *(const s8v*)(Bf + 8192 + 4096 + tid * 8);
    s8v rX3 = *(const s8v*)(Bf + 8192 + 6144 + tid * 8);
    s8v a00 = *(const s8v*)(A0);
    s8v a10 = *(const s8v*)(A1);
    s8v a01 = *(const s8v*)(A0 + 32);
    s8v a11 = *(const s8v*)(A1 + 32);
    s8v rY0, rY1, rY2, rY3;
    __syncthreads();

#pragma unroll 1
    for (int q = 0; q < 6; ++q) {
        {   // even body: p = 2q; compute Bs[0]; publish phase p+1 (X) -> Bs[1]
            const int p = 2 * q;
            const u16* src = Bf + (p + 2) * 8192;
            rY0 = *(const s8v*)(src + tid * 8);
            rY1 = *(const s8v*)(src + 2048 + tid * 8);
            rY2 = *(const s8v*)(src + 4096 + tid * 8);
            rY3 = *(const s8v*)(src + 6144 + tid * 8);
            s8v na00 = *(const s8v*)(A0 + (p + 1) * 64);
            s8v na10 = *(const s8v*)(A1 + (p + 1) * 64);
            s8v na01 = *(const s8v*)(A0 + (p + 1) * 64 + 32);
            s8v na11 = *(const s8v*)(A1 + (p + 1) * 64 + 32);
            COMPUTE(0, a00, a10, a01, a11);
            __syncthreads();
            *(s8v*)&Bs[1][tid * 8]        = rX0;
            *(s8v*)&Bs[1][2048 + tid * 8] = rX1;
            *(s8v*)&Bs[1][4096 + tid * 8] = rX2;
            *(s8v*)&Bs[1][6144 + tid * 8] = rX3;
            __syncthreads();
            a00 = na00; a10 = na10; a01 = na01; a11 = na11;
        }
        {   // odd body: p = 2q+1; compute Bs[1]; publish phase p+1 (Y) -> Bs[0]
            const int p = 2 * q + 1;
            const u16* src = Bf + (p + 2) * 8192;
            rX0 = *(const s8v*)(src + tid * 8);
            rX1 = *(const s8v*)(src + 2048 + tid * 8);
            rX2 = *(const s8v*)(src + 4096 + tid * 8);
            rX3 = *(const s8v*)(src + 6144 + tid * 8);
            s8v na00 = *(const s8v*)(A0 + (p + 1) * 64);
            s8v na10 = *(const s8v*)(A1 + (p + 1) * 64);
            s8v na01 = *(const s8v*)(A0 + (p + 1) * 64 + 32);
            s8v na11 = *(const s8v*)(A1 + (p + 1) * 64 + 32);
            COMPUTE(1, a00, a10, a01, a11);
            __syncthreads();
            *(s8v*)&Bs[0][tid * 8]        = rY0;
            *(s8v*)&Bs[0][2048 + tid * 8] = rY1;
            *(s8v*)&Bs[0][4096 + tid * 8] = rY2;
            *(s8v*)&Bs[0][6144 + tid * 8] = rY3;
            __syncthreads();
            a00 = na00; a10 = na10; a01 = na01; a11 = na11;
        }
    }
#undef COMPUTE

    __shared__ float sred[4][2][8][16];
    float cs[8], cq[8];
#pragma unroll
    for (int ct = 0; ct < 8; ++ct) { cs[ct] = 0.f; cq[ct] = 0.f; }

#pragma unroll
    for (int s = 0; s < 2; ++s)
#pragma unroll
        for (int ct = 0; ct < 8; ++ct) {
            int col = ct * 16 + lrow;
            float bv = bias[col];
#pragma unroll
            for (int j = 0; j < 4; ++j) {
                int row = r0 + s * 16 + kg * 4 + j;
                float v = acc[s][ct][j] + bv;
                O[(size_t)row * 128 + col] = f2b(v);
                cs[ct] += v; cq[ct] += v * v;
            }
        }
#pragma unroll
    for (int ct = 0; ct < 8; ++ct) {
        cs[ct] += __shfl_xor(cs[ct], 16); cs[ct] += __shfl_xor(cs[ct], 32);
        cq[ct] += __shfl_xor(cq[ct], 16); cq[ct] += __shfl_xor(cq[ct], 32);
    }
    if (lane < 16) {
#pragma unroll
        for (int ct = 0; ct < 8; ++ct) {
            sred[wave][0][ct][lane] = cs[ct];
            sred[wave][1][ct][lane] = cq[ct];
        }
    }
    __syncthreads();
    if (threadIdx.x < 128) {
        int ct = threadIdx.x >> 4, lr = threadIdx.x & 15;
        float S = 0.f, Q = 0.f;
#pragma unroll
        for (int w = 0; w < 4; ++w) { S += sred[w][0][ct][lr]; Q += sred[w][1][ct][lr]; }
        partials[blockIdx.x * 256 + threadIdx.x]       = S;
        partials[blockIdx.x * 256 + 128 + threadIdx.x] = Q;
    }
}

// all four 128x128-layer weights in one launch; blockIdx.y = layer (W2..W5)
__global__ __launch_bounds__(256)
void wprep_all(const float* __restrict__ W2, const float* __restrict__ W3,
               const float* __restrict__ W4, const float* __restrict__ W5,
               u16* __restrict__ Bf)
{
    int l = blockIdx.y;
    const float* W = (l == 0) ? W2 : (l == 1) ? W3 : (l == 2) ? W4 : W5;
    int base = (l & 1) ? 5 : 0;
    int idx = blockIdx.x * 256 + threadIdx.x;     // < 128*768
    int j    = idx & 7;
    int lane = (idx >> 3) & 63;
    int ct   = (idx >> 9) & 7;
    int k0s  = idx >> 12;
    int k    = k0s * 32 + (lane >> 4) * 8 + j;
    int col  = ct * 16 + (lane & 15);
    int slot = k >> 7, d = k & 127;
    int wk = slot - base; if (wk < 0) wk += 6;
    Bf[(size_t)l * LSTRIDE + idx] = f2b(W[(size_t)wk * 16384 + d * 128 + col]);
}

__global__ __launch_bounds__(256)
void w6prep(const float* __restrict__ W, u16* __restrict__ W6t, int base)
{
    int idx = blockIdx.x * 256 + threadIdx.x;     // < 16*768
    if (idx >= 16 * 768) return;
    int c = idx / 768, kk = idx % 768;
    int slot = kk >> 7, d = kk & 127;
    int wk = slot - base; if (wk < 0) wk += 6;
    W6t[idx] = (c < 10) ? f2b(W[(size_t)wk * 1280 + d * 10 + c]) : (u16)0;
}

// layer-1 GEMM + fused stats. Block = 128 rows; T values staged in LDS.
__global__ __launch_bounds__(256)
void l1gemm(u16* __restrict__ O, const float* __restrict__ T0,
            const float* __restrict__ Tt, const float* __restrict__ W,
            const float* __restrict__ bias, float* __restrict__ partials)
{
    __shared__ float Ts[128][18];
    __shared__ float sh[2][128], sh2[2][128];
    int tid = threadIdx.x;
    int rbase = blockIdx.x * 128;
    for (int i = tid; i < 128 * 18; i += 256) {
        int r = i / 18, t = i % 18;
        int k = t / 3, j = t % 3;
        Ts[r][t] = (k == 0) ? T0[(size_t)(rbase + r) * 3 + j]
                            : Tt[(size_t)(k - 1) * N1 * 3 + (size_t)(rbase + r) * 3 + j];
    }
    __syncthreads();
    int c = tid & 127, h = tid >> 7;
    float w[18];
#pragma unroll
    for (int k = 0; k < 6; ++k)
#pragma unroll
        for (int j = 0; j < 3; ++j) w[k * 3 + j] = W[(size_t)k * 384 + j * 128 + c];
    float bv = bias[c];
    float S = 0.f, Q = 0.f;
    for (int i = 0; i < 64; ++i) {
        int r = h * 64 + i;
        float acc = bv;
#pragma unroll
        for (int t = 0; t < 18; ++t) acc += Ts[r][t] * w[t];
        O[(size_t)(rbase + r) * 128 + c] = f2b(acc);
        S += acc; Q += acc * acc;
    }
    sh[h][c] = S; sh2[h][c] = Q;
    __syncthreads();
    if (tid < 128) {
        partials[blockIdx.x * 256 + tid]       = sh[0][tid] + sh[1][tid];
        partials[blockIdx.x * 256 + 128 + tid] = sh2[0][tid] + sh2[1][tid];
    }
}

// layer-6 GEMM + bias + relu
__global__ __launch_bounds__(256)
void out10_cat(float* __restrict__ O10, const u16* __restrict__ cat,
               const u16* __restrict__ W6t, const float* __restrict__ bias)
{
    int col = threadIdx.x & 15;
    int row = blockIdx.x * 16 + (threadIdx.x >> 4);
    const u16* a = cat + (size_t)row * 768;
    const u16* w = W6t + (size_t)col * 768;
    float acc = 0.f;
#pragma unroll 4
    for (int k0 = 0; k0 < 768; k0 += 8) {
        s8v av = *(const s8v*)(a + k0);
        s8v wv = *(const s8v*)(w + k0);
#pragma unroll
        for (int j = 0; j < 8; ++j)
            acc += b2f((u16)av[j]) * b2f((u16)wv[j]);
    }
    if (col < 10)
        O10[(size_t)row * 10 + col] = fmaxf(acc + bias[col], 0.f);
}

// BN reduce stage 1: 64 blocks; block i sums records {i, i+64, ...}
__global__ __launch_bounds__(256)
void bn_reduce1(const float* __restrict__ partials, int nblk,
                float* __restrict__ part2)
{
    int tid = threadIdx.x;
    float S = 0.f;
#pragma unroll 4
    for (int b = blockIdx.x; b < nblk; b += 64)
        S += partials[(size_t)b * 256 + tid];
    part2[blockIdx.x * 256 + tid] = S;
}

// BN reduce stage 2: -> combined scale gsc = invstd*gamma, gso = beta - mean*gsc
__global__ __launch_bounds__(256)
void bn_finalize2(const float* __restrict__ part2, int N,
                  const float* __restrict__ g, const float* __restrict__ bt,
                  float* __restrict__ gsc, float* __restrict__ gso)
{
    int tid = threadIdx.x;
    int c = tid & 127, h = tid >> 7;
    float S = 0.f, Q = 0.f;
#pragma unroll 8
    for (int b = h; b < 64; b += 2) {
        S += part2[b * 256 + c];
        Q += part2[b * 256 + 128 + c];
    }
    __shared__ float shS[2][128], shQ[2][128];
    shS[h][c] = S; shQ[h][c] = Q;
    __syncthreads();
    if (tid < 128) {
        float Sa = shS[0][tid] + shS[1][tid];
        float Qa = shQ[0][tid] + shQ[1][tid];
        float inv_n = 1.f / (float)N;
        float mu = Sa * inv_n;
        float var = Qa * inv_n - mu * mu;
        float is = rsqrtf(var + 1e-5f);
        float sc = is * g[tid];
        gsc[tid] = sc;
        gso[tid] = bt[tid] - mu * sc;
    }
}

// BN + relu + 2x2 max-pool fused (8 channels/thread) using gsc/gso
__global__ __launch_bounds__(256)
void bn_apply_pool8(const u16* __restrict__ O, u16* __restrict__ cat, int outSlot,
                    int s, int Nout,
                    const float* __restrict__ gsc, const float* __restrict__ gso)
{
    int idx = blockIdx.x * 256 + threadIdx.x;    // over Nout*16
    if (idx >= Nout * 16) return;
    int c8 = idx & 15;
    int n2 = idx >> 4;
    int h  = s >> 1;
    int x2 = n2 % h;
    int y2 = (n2 / h) % h;
    int gg = n2 / (h * h);
    int base = (gg * s + 2 * y2) * s + 2 * x2;
    s8v v0 = *(const s8v*)(O + (size_t)base * 128 + c8 * 8);
    s8v v1 = *(const s8v*)(O + (size_t)(base + 1) * 128 + c8 * 8);
    s8v v2 = *(const s8v*)(O + (size_t)(base + s) * 128 + c8 * 8);
    s8v v3 = *(const s8v*)(O + (size_t)(base + s + 1) * 128 + c8 * 8);
    s8v ov;
#pragma unroll
    for (int j = 0; j < 8; ++j) {
        int c = c8 * 8 + j;
        float sc = gsc[c], so = gso[c];
        float m =          b2f((u16)v0[j]) * sc + so;
        m = fmaxf(m, b2f((u16)v1[j]) * sc + so);
        m = fmaxf(m, b2f((u16)v2[j]) * sc + so);
        m = fmaxf(m, b2f((u16)v3[j]) * sc + so);
        ov[j] = (short)f2b(fmaxf(m, 0.f));
    }
    *(s8v*)(cat + (size_t)n2 * 768 + outSlot * 128 + c8 * 8) = ov;
}

// fused tail: pool3(16->8) + orientation pool + global max + log_softmax
__global__ __launch_bounds__(512)
void tail_fused(const float* __restrict__ O10, float* __restrict__ out)
{
    __shared__ float p4[512][10];
    __shared__ float G[8][10];
    __shared__ float rowm[8], rowl[8];
    int t = threadIdx.x;
    for (int i = t; i < 5120; i += 512) {
        int c = i % 10, n = i / 10;
        int x = n & 7, y = (n >> 3) & 7, b = n >> 6;
        float m = -INFINITY;
        for (int o = 0; o < L_OR; ++o) {
            int base = ((b * L_OR + o) * 16 + 2 * y) * 16 + 2 * x;
            m = fmaxf(m, O10[(size_t)base * 10 + c]);
            m = fmaxf(m, O10[(size_t)(base + 1) * 10 + c]);
            m = fmaxf(m, O10[(size_t)(base + 16) * 10 + c]);
            m = fmaxf(m, O10[(size_t)(base + 17) * 10 + c]);
        }
        p4[n][c] = m;
    }
    __syncthreads();
    if (t < 80) {
        int b = t / 10, c = t % 10;
        float m = -INFINITY;
        for (int p = 0; p < 64; ++p) m = fmaxf(m, p4[b * 64 + p][c]);
        G[b][c] = m;
    }
    __syncthreads();
    if (t < 8) {
        float m = -INFINITY;
        for (int c = 0; c < 10; ++c) m = fmaxf(m, G[t][c]);
        float s = 0.f;
        for (int c = 0; c < 10; ++c) s += expf(G[t][c] - m);
        rowm[t] = m; rowl[t] = logf(s);
    }
    __syncthreads();
    if (t < 80) {
        int b = t / 10, c = t % 10;
        out[t] = G[b][c] - rowm[b] - rowl[b];
    }
}

// ---------------------------------------------------------------------------
// Host-side orchestration
// ---------------------------------------------------------------------------
static void launch_lapb(u16* cat, int os, int is, int ts, const float* wtab,
                        int S, int N, float alpha, hipStream_t st)
{
    dim3 grid(N / 16), block(256);
    if (S == 64)      hipLaunchKernelGGL(lap128b<64>, grid, block, 0, st, cat, os, is, ts, wtab, alpha);
    else if (S == 32) hipLaunchKernelGGL(lap128b<32>, grid, block, 0, st, cat, os, is, ts, wtab, alpha);
    else              hipLaunchKernelGGL(lap128b<16>, grid, block, 0, st, cat, os, is, ts, wtab, alpha);
}

// base-5 full lap chain (k=1..5), used after pooled input in slot 5
static void cheb_laps_b5(u16* cat, const float* wtab, int S, int N, hipStream_t st)
{
    for (int k = 1; k < 6; ++k) {
        int os = (k + 5) % 6;
        int is = (k - 1 + 5) % 6;
        int ts = (k >= 2) ? (k - 2 + 5) % 6 : -1;
        launch_lapb(cat, os, is, ts, wtab, S, N, (k == 1) ? 1.f : 2.f, st);
    }
}

// base-0 laps k=2..5 (T0,T1 already written by lap1bn)
static void cheb_laps_2to5(u16* cat, const float* wtab, int S, int N, hipStream_t st)
{
    for (int k = 2; k < 6; ++k)
        launch_lapb(cat, k, k - 1, k - 2, wtab, S, N, 2.f, st);
}

static void launch_lap1bn(u16* cat, const u16* O, const float* wtab,
                          const float* gsc, const float* gso,
                          int S, int N, hipStream_t st)
{
    dim3 grid(N / 16), block(256);
    if (S == 64)      hipLaunchKernelGGL(lap1bn<64>, grid, block, 0, st, cat, O, 0, 1, wtab, gsc, gso);
    else if (S == 32) hipLaunchKernelGGL(lap1bn<32>, grid, block, 0, st, cat, O, 0, 1, wtab, gsc, gso);
    else              hipLaunchKernelGGL(lap1bn<16>, grid, block, 0, st, cat, O, 0, 1, wtab, gsc, gso);
}

static void bn_reduce(float* part, float* part2, int nblk, int N,
                      const float* g, const float* bt,
                      float* gsc, float* gso, hipStream_t st)
{
    hipLaunchKernelGGL(bn_reduce1, dim3(64), dim3(256), 0, st, part, nblk, part2);
    hipLaunchKernelGGL(bn_finalize2, dim3(1), dim3(256), 0, st, part2, N, g, bt, gsc, gso);
}

extern "C" void kernel_launch(void* const* d_in, const int* in_sizes, int n_in,
                              void* d_out, int out_size, void* d_ws, size_t ws_size,
                              hipStream_t stream)
{
    const float* x   = (const float*)d_in[0];
    const float* ea1 = (const float*)d_in[2];
    const float* ea2 = (const float*)d_in[4];
    const float* ea3 = (const float*)d_in[6];
    const float* W1  = (const float*)d_in[12];
    const float* b1  = (const float*)d_in[13];
    const float* W2  = (const float*)d_in[14];
    const float* b2  = (const float*)d_in[15];
    const float* W3  = (const float*)d_in[16];
    const float* b3  = (const float*)d_in[17];
    const float* W4  = (const float*)d_in[18];
    const float* b4  = (const float*)d_in[19];
    const float* W5  = (const float*)d_in[20];
    const float* b5  = (const float*)d_in[21];
    const float* W6  = (const float*)d_in[22];
    const float* b6  = (const float*)d_in[23];
    const float* g1  = (const float*)d_in[24];
    const float* be1 = (const float*)d_in[25];
    const float* g2  = (const float*)d_in[26];
    const float* be2 = (const float*)d_in[27];
    const float* g3  = (const float*)d_in[28];
    const float* be3 = (const float*)d_in[29];
    const float* g4  = (const float*)d_in[30];
    const float* be4 = (const float*)d_in[31];
    const float* g5  = (const float*)d_in[32];
    const float* be5 = (const float*)d_in[33];

    u16 *cat, *O, *Bt, *W6t;
    float *Tt, *O10, *part, *part2, *gsc, *gso, *wt1, *wt2, *wt3;
    if (hipGetSymbolAddress((void**)&cat, HIP_SYMBOL(g_cat)) != hipSuccess) return;
    if (hipGetSymbolAddress((void**)&O,   HIP_SYMBOL(g_O))   != hipSuccess) return;
    if (hipGetSymbolAddress((void**)&Tt,  HIP_SYMBOL(g_Tt))  != hipSuccess) return;
    if (hipGetSymbolAddress((void**)&Bt,  HIP_SYMBOL(g_Bt))  != hipSuccess) return;
    if (hipGetSymbolAddress((void**)&W6t, HIP_SYMBOL(g_W6t)) != hipSuccess) return;
    if (hipGetSymbolAddress((void**)&O10, HIP_SYMBOL(g_O10)) != hipSuccess) return;
    if (hipGetSymbolAddress((void**)&part,  HIP_SYMBOL(g_part))  != hipSuccess) return;
    if (hipGetSymbolAddress((void**)&part2, HIP_SYMBOL(g_part2)) != hipSuccess) return;
    if (hipGetSymbolAddress((void**)&gsc, HIP_SYMBOL(g_gsc)) != hipSuccess) return;
    if (hipGetSymbolAddress((void**)&gso, HIP_SYMBOL(g_gso)) != hipSuccess) return;
    if (hipGetSymbolAddress((void**)&wt1, HIP_SYMBOL(g_wt1)) != hipSuccess) return;
    if (hipGetSymbolAddress((void**)&wt2, HIP_SYMBOL(g_wt2)) != hipSuccess) return;
    if (hipGetSymbolAddress((void**)&wt3, HIP_SYMBOL(g_wt3)) != hipSuccess) return;

    dim3 blk(256);

    // ---------- prep ----------
    hipLaunchKernelGGL(eaprep_all, dim3((N1 + N2 + N3) / 256), blk, 0, stream,
                       wt1, wt2, wt3, ea1, ea2, ea3);
    hipLaunchKernelGGL(wprep_all, dim3(384, 4), blk, 0, stream, W2, W3, W4, W5, Bt);
    hipLaunchKernelGGL(w6prep, dim3(48), blk, 0, stream, W6, W6t, 0);

    // ---------- Layer 1: cheb(x[N1,3], W1) -> O bf16 (+stats) ----------
    {
        float* t1 = Tt;
        float* t2 = Tt + (size_t)N1 * 3;
        float* t3 = Tt + (size_t)2 * N1 * 3;
        float* t4 = Tt + (size_t)3 * N1 * 3;
        float* t5 = Tt + (size_t)4 * N1 * 3;
        dim3 gl((N1 + 255) / 256);
        hipLaunchKernelGGL(lap3_kernel<64>, gl, blk, 0, stream, t1, x,  (const float*)nullptr, wt1, 1.f);
        hipLaunchKernelGGL(lap3_kernel<64>, gl, blk, 0, stream, t2, t1, x,  wt1, 2.f);
        hipLaunchKernelGGL(lap3_kernel<64>, gl, blk, 0, stream, t3, t2, t1, wt1, 2.f);
        hipLaunchKernelGGL(lap3_kernel<64>, gl, blk, 0, stream, t4, t3, t2, wt1, 2.f);
        hipLaunchKernelGGL(lap3_kernel<64>, gl, blk, 0, stream, t5, t4, t3, wt1, 2.f);
        hipLaunchKernelGGL(l1gemm, dim3(N1 / 128), blk, 0, stream, O, x, Tt, W1, b1, part);
    }
    bn_reduce(part, part2, N1 / 128, N1, g1, be1, gsc, gso, stream);

    // ---------- Layer 2 (N1): fused BN-lap, laps, GEMM ----------
    launch_lap1bn(cat, O, wt1, gsc, gso, 64, N1, stream);
    cheb_laps_2to5(cat, wt1, 64, N1, stream);
    hipLaunchKernelGGL(gemm_mfma_cat, dim3(N1 / 128), blk, 0, stream, O, cat, Bt, b2, part);
    bn_reduce(part, part2, N1 / 128, N1, g2, be2, gsc, gso, stream);
    hipLaunchKernelGGL(bn_apply_pool8, dim3(N2 / 16), blk, 0, stream,
                       O, cat, 5, 64, N2, gsc, gso);

    // ---------- Layer 3 (N2, base 5) ----------
    cheb_laps_b5(cat, wt2, 32, N2, stream);
    hipLaunchKernelGGL(gemm_mfma_cat, dim3(N2 / 128), blk, 0, stream, O, cat, Bt + 1 * LSTRIDE, b3, part);
    bn_reduce(part, part2, N2 / 128, N2, g3, be3, gsc, gso, stream);

    // ---------- Layer 4 (N2, base 0) ----------
    launch_lap1bn(cat, O, wt2, gsc, gso, 32, N2, stream);
    cheb_laps_2to5(cat, wt2, 32, N2, stream);
    hipLaunchKernelGGL(gemm_mfma_cat, dim3(N2 / 128), blk, 0, stream, O, cat, Bt + 2 * LSTRIDE, b4, part);
    bn_reduce(part, part2, N2 / 128, N2, g4, be4, gsc, gso, stream);
    hipLaunchKernelGGL(bn_apply_pool8, dim3(N3 / 16), blk, 0, stream,
                       O, cat, 5, 32, N3, gsc, gso);

    // ---------- Layer 5 (N3, base 5) ----------
    cheb_laps_b5(cat, wt3, 16, N3, stream);
    hipLaunchKernelGGL(gemm_mfma_cat, dim3(N3 / 128), blk, 0, stream, O, cat, Bt + 3 * LSTRIDE, b5, part);
    bn_reduce(part, part2, N3 / 128, N3, g5, be5, gsc, gso, stream);

    // ---------- Layer 6 (N3, base 0, out 10, relu fused) ----------
    launch_lap1bn(cat, O, wt3, gsc, gso, 16, N3, stream);
    cheb_laps_2to5(cat, wt3, 16, N3, stream);
    hipLaunchKernelGGL(out10_cat, dim3(N3 / 16), blk, 0, stream, O10, cat, W6t, b6);

    // ---------- fused tail ----------
    hipLaunchKernelGGL(tail_fused, dim3(1), dim3(512), 0, stream, O10, (float*)d_out);
}